// Round 10
// baseline (850.170 us; speedup 1.0000x reference)
//
#include <hip/hip_runtime.h>
#include <hip/hip_bf16.h>
#include <math.h>

#define DIMC 64
#define C3 192
#define NHEADS 6
#define DH 32
#define WSZ 8
#define SHIFTV 4
#define HIDC 128
#define FULLR 256
#define HALFR 128

typedef __attribute__((ext_vector_type(8))) short bf16x8;
typedef __attribute__((ext_vector_type(4))) float f32x4;

__device__ __forceinline__ float gelu_f(float x){
    return 0.5f * x * (1.0f + erff(x * 0.70710678118654752440f));
}
__device__ __forceinline__ unsigned short f2bf(float f){
    union { float f; unsigned u; } v; v.f = f;
    unsigned r = (v.u + 0x7FFF + ((v.u >> 16) & 1)) >> 16;
    return (unsigned short)r;
}
__device__ __forceinline__ float bf2f(unsigned short h){
    union { unsigned u; float f; } v; v.u = ((unsigned)h) << 16;
    return v.f;
}

// ---------------- DWT: ll fp32 (plane), high bf16 (window-token-major), + fused gap partial sums
__global__ __launch_bounds__(256) void k_dwt(const float* __restrict__ x, float* __restrict__ ll,
                                             unsigned short* __restrict__ high, float* __restrict__ gap,
                                             int nb, int b0){
    __shared__ float red[256];
    int idx = blockIdx.x * 256 + threadIdx.x;
    int total = nb << 19;
    if (idx >= total) return;
    int w4 = idx & 63;
    int h  = (idx >> 6) & 127;
    int c  = (idx >> 13) & 63;
    int b  = idx >> 19;
    const float* xp = x + (((size_t)(b0 + b) * DIMC + c) * FULLR + 2*h) * FULLR + 4*w4;
    float4 r0 = *(const float4*)xp;
    float4 r1 = *(const float4*)(xp + FULLR);
    size_t lbase = (((size_t)b*64 + c) << 14) + h*128 + w4*2;
    float x1a = 0.5f*r0.x, x3a = 0.5f*r0.y, x2a = 0.5f*r1.x, x4a = 0.5f*r1.y;
    float x1b = 0.5f*r0.z, x3b = 0.5f*r0.w, x2b = 0.5f*r1.z, x4b = 0.5f*r1.w;
    float2 v;
    v.x = x1a + x2a + x3a + x4a;           v.y = x1b + x2b + x3b + x4b;
    *(float2*)&ll[lbase] = v;
    int hs = (h + SHIFTV) & 127;  int wh = hs >> 3; int rr = hs & 7;
    int ws = (2*w4 + SHIFTV) & 127; int ww = ws >> 3; int cc = ws & 7;
    size_t wbase = ((size_t)(b*256 + wh*16 + ww)) * 12288 + rr*8 + cc;
    unsigned u;
    u = (unsigned)f2bf(-x1a - x2a + x3a + x4a) | ((unsigned)f2bf(-x1b - x2b + x3b + x4b) << 16);
    *(unsigned*)&high[wbase + (size_t)c*64] = u;
    u = (unsigned)f2bf(-x1a + x2a - x3a + x4a) | ((unsigned)f2bf(-x1b + x2b - x3b + x4b) << 16);
    *(unsigned*)&high[wbase + (size_t)(64 + c)*64] = u;
    u = (unsigned)f2bf( x1a - x2a - x3a + x4a) | ((unsigned)f2bf( x1b - x2b - x3b + x4b) << 16);
    *(unsigned*)&high[wbase + (size_t)(128 + c)*64] = u;
    // fused gap partial: block covers fixed (b,c)
    red[threadIdx.x] = v.x + v.y;
    __syncthreads();
    for (int st = 128; st > 0; st >>= 1){
        if (threadIdx.x < st) red[threadIdx.x] += red[threadIdx.x + st];
        __syncthreads();
    }
    if (threadIdx.x == 0) atomicAdd(&gap[b*64 + c], red[0]);
}

// ---------------- gate MLP (gap holds SUM; fold 1/16384)
__global__ __launch_bounds__(256) void k_gate(const float* __restrict__ gap, const float* __restrict__ w1,
                                              const float* __restrict__ w2, float* __restrict__ gate){
    int b = blockIdx.x;
    __shared__ float hid[48];
    __shared__ float g[64];
    if (threadIdx.x < 64) g[threadIdx.x] = gap[b*64 + threadIdx.x] * (1.0f/16384.0f);
    __syncthreads();
    if (threadIdx.x < 48){
        float s = 0.f;
        for (int c = 0; c < 64; c++) s += g[c] * w1[threadIdx.x*64 + c];
        hid[threadIdx.x] = gelu_f(s);
    }
    __syncthreads();
    if (threadIdx.x < C3){
        float s = 0.f;
        for (int j = 0; j < 48; j++) s += hid[j] * w2[threadIdx.x*48 + j];
        gate[b*C3 + threadIdx.x] = 1.0f / (1.0f + expf(-s));
    }
}

// ---------------- weights -> bf16, rel bias table, gap zero
__global__ __launch_bounds__(256) void k_cvt(const float* __restrict__ wq, const float* __restrict__ wp,
    const float* __restrict__ rel_table, const int* __restrict__ rel_idx, const float* __restrict__ wo,
    const float* __restrict__ wi,
    unsigned short* __restrict__ wqb, unsigned short* __restrict__ wpb, float* __restrict__ bias6,
    unsigned short* __restrict__ wob, unsigned short* __restrict__ wib, float* __restrict__ gap){
    int idx = blockIdx.x*256 + threadIdx.x;
    if (idx < 576*192) wqb[idx] = f2bf(wq[idx]);
    if (idx < 192*192) wpb[idx] = f2bf(wp[idx]);
    if (idx < 64*128)  wob[idx] = f2bf(wo[idx]);
    if (idx < 256*64)  wib[idx] = f2bf(wi[idx]);
    if (idx < 256)     gap[idx] = 0.f;
    if (idx < 6*64*64){
        int h = idx >> 12; int ij = idx & 4095;
        bias6[idx] = rel_table[rel_idx[ij]*NHEADS + h];
    }
}

// ---------------- merged spectral kernel + circulant (bf16): one block per channel
__global__ __launch_bounds__(256) void k_kcirc(const float* __restrict__ wr, const float* __restrict__ wi,
                                               unsigned short* __restrict__ circ){
    __shared__ float ksl[64];
    int ch = blockIdx.x;
    int tid = threadIdx.x;
    if (tid < 64){
        int r = tid >> 3, c = tid & 7;
        float s = 0.f;
        for (int u = 0; u < 8; u++){
            for (int v = 0; v < 8; v++){
                float re, im;
                if (v <= 4){ re = wr[ch*40 + u*5 + v]; im = wi[ch*40 + u*5 + v]; }
                else { int u2 = (8-u)&7; int v2 = 8-v; re = wr[ch*40 + u2*5 + v2]; im = -wi[ch*40 + u2*5 + v2]; }
                float ang = (float)(u*r + v*c) * 0.78539816339744831f;
                float cs, sn; __sincosf(ang, &sn, &cs);
                s += re * cs - im * sn;
            }
        }
        ksl[tid] = s * (1.0f/64.0f);
    }
    __syncthreads();
    for (int idx = tid; idx < 4096; idx += 256){
        int o = idx >> 6, i = idx & 63;
        int dr = ((o >> 3) - (i >> 3)) & 7;
        int dc = ((o & 7) - (i & 7)) & 7;
        circ[(size_t)ch*4096 + idx] = f2bf(ksl[dr*8 + dc]);
    }
}

// ---------------- fused shifted-window MHSA via MFMA, in-place, LDS-overlaid (28.2 KB)
__global__ __launch_bounds__(256, 4) void k_attn(unsigned short* __restrict__ high,
    const unsigned short* __restrict__ wqb, const unsigned short* __restrict__ wpb,
    const float* __restrict__ bqkv, const float* __restrict__ bproj,
    const float* __restrict__ bias6, const float* __restrict__ lnw, const float* __restrict__ lnb,
    const float* __restrict__ gate, const float* __restrict__ gm_p, const float* __restrict__ gc_p)
{
    __shared__ __align__(16) char smem[28160];
    // phase 1 overlay
    unsigned short* xb = (unsigned short*)smem;          // [64][200]
    float* st_s  = (float*)(smem + 25600);               // [4][64]
    float* st_ss = (float*)(smem + 26624);               // [4][64]
    float* mu_s  = (float*)(smem + 27648);               // [64]
    float* rs_s  = (float*)(smem + 27904);               // [64]
    // phase 2 overlay (xb dead)
    unsigned short* qs  = (unsigned short*)smem;          // [64][40]
    unsigned short* ks2 = (unsigned short*)(smem + 5120); // [64][40]
    unsigned short* vt  = (unsigned short*)(smem + 10240);// [32][72]
    unsigned short* ps  = (unsigned short*)(smem + 14848);// [64][72]

    int tid = threadIdx.x;
    int lane = tid & 63;
    int wv = tid >> 6;
    int lrow = lane & 15;
    int lkg  = lane >> 4;
    int blk = blockIdx.x;
    int b  = blk >> 8;
    size_t wbase = (size_t)blk * 12288;
    const float scale = 0.17677669529663687f;
    float gm = gm_p[0], gc = gc_p[0];

    // ---- stage + LN stats (token = lane, wave owns 48 channels)
    int t = lane, part = wv;
    float vals[48];
    {
        float s = 0.f, ss = 0.f;
        #pragma unroll
        for (int i = 0; i < 48; i++){
            float v = bf2f(high[wbase + (size_t)(part*48 + i)*64 + t]);
            vals[i] = v; s += v; ss += v*v;
        }
        st_s[part*64 + t] = s; st_ss[part*64 + t] = ss;
    }
    __syncthreads();
    if (tid < 64){
        float s = st_s[tid]+st_s[64+tid]+st_s[128+tid]+st_s[192+tid];
        float ss = st_ss[tid]+st_ss[64+tid]+st_ss[128+tid]+st_ss[192+tid];
        float mu = s*(1.f/C3);
        float var = ss*(1.f/C3) - mu*mu;
        mu_s[tid] = mu; rs_s[tid] = rsqrtf(var + 1e-6f);
    }
    __syncthreads();
    {
        float mu = mu_s[t], rs = rs_s[t];
        #pragma unroll
        for (int i8 = 0; i8 < 6; i8++){
            bf16x8 pk;
            #pragma unroll
            for (int jj = 0; jj < 8; jj++){
                int c = part*48 + i8*8 + jj;
                float nv = (vals[i8*8+jj] - mu) * rs * lnw[c] + lnb[c];
                pk[jj] = (short)f2bf(nv);
            }
            *(bf16x8*)&xb[t*200 + part*48 + i8*8] = pk;
        }
    }
    __syncthreads();

    // ---- A-row into registers: thread's QKV A-operand is fixed token row wv*16+lrow
    bf16x8 areg[6];
    #pragma unroll
    for (int ksU = 0; ksU < 6; ksU++)
        areg[ksU] = *(const bf16x8*)&xb[(wv*16 + lrow)*200 + ksU*32 + lkg*8];
    __syncthreads();   // xb dead; qs/ks2/vt/ps may now overwrite it

    f32x4 pacc[3][4];
    #pragma unroll
    for (int mt3 = 0; mt3 < 3; mt3++)
        #pragma unroll
        for (int nt = 0; nt < 4; nt++) pacc[mt3][nt] = (f32x4){0.f,0.f,0.f,0.f};

    for (int h = 0; h < NHEADS; h++){
        f32x4 acc[6];
        #pragma unroll
        for (int nt = 0; nt < 6; nt++) acc[nt] = (f32x4){0.f,0.f,0.f,0.f};
        #pragma unroll
        for (int ksU = 0; ksU < 6; ksU++){
            int c0 = ksU*32 + lkg*8;
            bf16x8 a = areg[ksU];
            #pragma unroll
            for (int nt = 0; nt < 6; nt++){
                int which = nt >> 1;
                int gr = which*C3 + h*32 + (nt&1)*16 + lrow;
                bf16x8 bb = *(const bf16x8*)&wqb[(size_t)gr*C3 + c0];
                acc[nt] = __builtin_amdgcn_mfma_f32_16x16x32_bf16(a, bb, acc[nt], 0, 0, 0);
            }
        }
        #pragma unroll
        for (int nt = 0; nt < 6; nt++){
            int which = nt >> 1;
            int d = (nt&1)*16 + lrow;
            float bias = bqkv[which*C3 + h*32 + d];
            #pragma unroll
            for (int r = 0; r < 4; r++){
                int row = wv*16 + lkg*4 + r;
                float v = acc[nt][r] + bias;
                if (which == 0)      qs[row*40 + d]  = f2bf(v * scale);
                else if (which == 1) ks2[row*40 + d] = f2bf(v);
                else                 vt[d*72 + row]  = f2bf(v);
            }
        }
        __syncthreads();

        // scores + softmax (no max-subtraction: |s| small, exp range-safe)
        f32x4 sacc[4];
        {
            bf16x8 a = *(const bf16x8*)&qs[(wv*16 + lrow)*40 + lkg*8];
            #pragma unroll
            for (int nt = 0; nt < 4; nt++){
                bf16x8 bb = *(const bf16x8*)&ks2[(nt*16 + lrow)*40 + lkg*8];
                f32x4 z = (f32x4){0.f,0.f,0.f,0.f};
                sacc[nt] = __builtin_amdgcn_mfma_f32_16x16x32_bf16(a, bb, z, 0, 0, 0);
            }
        }
        {
            #pragma unroll
            for (int r = 0; r < 4; r++){
                int i = wv*16 + lkg*4 + r;
                float pv[4];
                float s = 0.f;
                #pragma unroll
                for (int nt = 0; nt < 4; nt++){
                    pv[nt] = __expf(sacc[nt][r] + bias6[h*4096 + i*64 + nt*16 + lrow]);
                    s += pv[nt];
                }
                s += __shfl_xor(s, 1); s += __shfl_xor(s, 2);
                s += __shfl_xor(s, 4); s += __shfl_xor(s, 8);
                float inv = 1.0f / s;
                #pragma unroll
                for (int nt = 0; nt < 4; nt++) ps[i*72 + nt*16 + lrow] = f2bf(pv[nt] * inv);
            }
        }
        __syncthreads();

        f32x4 oacc[2];
        #pragma unroll
        for (int nt = 0; nt < 2; nt++) oacc[nt] = (f32x4){0.f,0.f,0.f,0.f};
        #pragma unroll
        for (int kst = 0; kst < 2; kst++){
            bf16x8 a = *(const bf16x8*)&ps[(wv*16 + lrow)*72 + kst*32 + lkg*8];
            #pragma unroll
            for (int nt = 0; nt < 2; nt++){
                bf16x8 bb = *(const bf16x8*)&vt[(nt*16 + lrow)*72 + kst*32 + lkg*8];
                oacc[nt] = __builtin_amdgcn_mfma_f32_16x16x32_bf16(a, bb, oacc[nt], 0, 0, 0);
            }
        }
        #pragma unroll
        for (int nt = 0; nt < 2; nt++)
            #pragma unroll
            for (int r = 0; r < 4; r++)
                qs[(wv*16 + lkg*4 + r)*40 + nt*16 + lrow] = f2bf(oacc[nt][r]);
        __syncthreads();

        #pragma unroll
        for (int mt3 = 0; mt3 < 3; mt3++){
            int o = wv*48 + mt3*16 + lrow;
            bf16x8 a = *(const bf16x8*)&wpb[(size_t)o*C3 + h*32 + lkg*8];
            #pragma unroll
            for (int nt = 0; nt < 4; nt++){
                bf16x8 bb = *(const bf16x8*)&qs[(nt*16 + lrow)*40 + lkg*8];
                pacc[mt3][nt] = __builtin_amdgcn_mfma_f32_16x16x32_bf16(a, bb, pacc[mt3][nt], 0, 0, 0);
            }
        }
        __syncthreads();
    }

    #pragma unroll
    for (int mt3 = 0; mt3 < 3; mt3++){
        #pragma unroll
        for (int r = 0; r < 4; r++){
            int o = wv*48 + mt3*16 + lkg*4 + r;
            float bias = bproj[o];
            float gf = 1.0f + gc * (gate[b*C3 + o] - 0.5f) * 2.0f;
            #pragma unroll
            for (int nt = 0; nt < 4; nt++){
                int token = nt*16 + lrow;
                size_t gi = wbase + (size_t)o*64 + token;
                float orig = bf2f(high[gi]);
                high[gi] = f2bf((orig + gm*(pacc[mt3][nt][r] + bias)) * gf);
            }
        }
    }
}

// ---------------- aux depthwise 3x3 + gelu
__global__ __launch_bounds__(256) void k_dwc_aux(const float* __restrict__ ll, const float* __restrict__ dw,
                                                 float* __restrict__ tmp, int nb){
    int idx = blockIdx.x*256 + threadIdx.x;
    int total = nb << 17;
    if (idx >= total) return;
    int c0 = (idx & 31) * 4;
    int h  = (idx >> 5) & 127;
    int ch = (idx >> 12) & 63;
    int b  = idx >> 18;
    const float* wd = dw + ch*9;
    const float* plane = ll + (((size_t)b*64 + ch) << 14);
    float acc[4] = {0.f, 0.f, 0.f, 0.f};
    #pragma unroll
    for (int dy = 0; dy < 3; dy++){
        int y = h + dy - 1;
        if (y < 0 || y > 127) continue;
        const float* rp = plane + y*128;
        float4 v = *(const float4*)(rp + c0);
        float l = (c0 > 0)   ? rp[c0 - 1] : 0.f;
        float rg = (c0 < 124) ? rp[c0 + 4] : 0.f;
        float w0 = wd[dy*3+0], w1 = wd[dy*3+1], w2 = wd[dy*3+2];
        acc[0] += w0*l   + w1*v.x + w2*v.y;
        acc[1] += w0*v.x + w1*v.y + w2*v.z;
        acc[2] += w0*v.y + w1*v.z + w2*v.w;
        acc[3] += w0*v.z + w1*v.w + w2*rg;
    }
    float4 o;
    o.x = gelu_f(acc[0]); o.y = gelu_f(acc[1]); o.z = gelu_f(acc[2]); o.w = gelu_f(acc[3]);
    *(float4*)&tmp[(((size_t)b*64 + ch) << 14) + h*128 + c0] = o;
}

// ---------------- aux pointwise, LDS-tiled
__global__ __launch_bounds__(256) void k_aux_pw(const float* __restrict__ ll, const float* __restrict__ tmp,
                                                const float* __restrict__ pw, const float* __restrict__ ga_p,
                                                float* __restrict__ rll, int nb){
    __shared__ float tl[64][65];
    int tid = threadIdx.x;
    int blk = blockIdx.x;
    int b = blk >> 8;
    int pix0 = (blk & 255) * 64;
    for (int idx = tid; idx < 4096; idx += 256){
        int c = idx >> 6, px = idx & 63;
        tl[c][px] = tmp[((size_t)(b*64 + c) << 14) + pix0 + px];
    }
    __syncthreads();
    int px = tid & 63, cq = tid >> 6;
    float ga = ga_p[0];
    for (int og = 0; og < 2; og++){
        int ob = cq*16 + og*8;
        float acc[8] = {0,0,0,0,0,0,0,0};
        for (int c = 0; c < 64; c++){
            float v = tl[c][px];
            #pragma unroll
            for (int j = 0; j < 8; j++) acc[j] += v * pw[(ob+j)*64 + c];
        }
        #pragma unroll
        for (int j = 0; j < 8; j++){
            size_t gi = ((size_t)(b*64 + ob + j) << 14) + pix0 + px;
            rll[gi] = ll[gi] + ga * acc[j];
        }
    }
}

// ---------------- IWT + (iwt - x) @ attn_out_w.T + x -> y1 (bf16)
__global__ __launch_bounds__(256) void k_iwt_proj(const float* __restrict__ rll,
    const unsigned short* __restrict__ high,
    const float* __restrict__ x, const float* __restrict__ wao,
    unsigned short* __restrict__ y1b, int nb, int b0){
    __shared__ float wt[64][65];
    __shared__ float dbuf[64][65];
    __shared__ float xt[64][65];
    int tid = threadIdx.x;
    for (int idx = tid; idx < 4096; idx += 256){
        int o = idx >> 6, i = idx & 63;
        wt[i][o] = wao[o*64 + i];
    }
    int blk = blockIdx.x;
    int seg = blk & 3;
    int ph  = (blk >> 2) & 255;
    int b   = blk >> 10;
    int pw0 = seg * 64;
    int h2 = ph >> 1, p = ph & 1;
    size_t xbase = ((size_t)(b0 + b) * DIMC) * 65536;
    int px = tid & 63;
    int ci = tid >> 6;
    int pwv = pw0 + px;
    int w2 = pwv >> 1, q = pwv & 1;
    float shl = q ? 1.f : -1.f;
    float slh = p ? 1.f : -1.f;
    float shh = (p == q) ? 1.f : -1.f;
    int hs = (h2 + SHIFTV) & 127; int wh = hs >> 3; int rr = hs & 7;
    int ws = (w2 + SHIFTV) & 127; int ww = ws >> 3; int cc = ws & 7;
    size_t wbase = ((size_t)(b*256 + wh*16 + ww)) * 12288 + rr*8 + cc;
    for (int i = ci; i < 64; i += 4){
        float llv = rll[(((size_t)b*64 + i)*128 + h2)*128 + w2];
        float hl = bf2f(high[wbase + (size_t)i*64]);
        float lh = bf2f(high[wbase + (size_t)(64 + i)*64]);
        float hh = bf2f(high[wbase + (size_t)(128 + i)*64]);
        float iw = 0.5f * (llv + shl*hl + slh*lh + shh*hh);
        float xv = x[xbase + (size_t)i*65536 + (size_t)ph*256 + pwv];
        xt[i][px] = xv;
        dbuf[i][px] = iw - xv;
    }
    __syncthreads();
    for (int o = ci; o < 64; o += 4){
        float s0=0.f,s1=0.f,s2=0.f,s3=0.f;
        for (int i = 0; i < 64; i += 4){
            s0 += dbuf[i+0][px] * wt[i+0][o];
            s1 += dbuf[i+1][px] * wt[i+1][o];
            s2 += dbuf[i+2][px] * wt[i+2][o];
            s3 += dbuf[i+3][px] * wt[i+3][o];
        }
        y1b[(((size_t)(b*64 + o)) << 16) + (size_t)ph*256 + pwv] =
            f2bf(xt[o][px] + (s0+s1)+(s2+s3));
    }
}

// ---------------- FFN part A: LN + conv1x1(64->256) via MFMA, bf16 in/out
__global__ __launch_bounds__(256) void k_ffn_a(const unsigned short* __restrict__ y1b,
    const float* __restrict__ lnw, const float* __restrict__ lnb,
    const unsigned short* __restrict__ wib, unsigned short* __restrict__ h, int nb)
{
    __shared__ float yl[64][72];
    __shared__ __align__(16) unsigned short xn[64][72];
    __shared__ __align__(16) unsigned short ho[128][72];
    __shared__ float mu_s[64], rs_s[64];
    int tid = threadIdx.x;
    int lane = tid & 63;
    int wv = tid >> 6;
    int lrow = lane & 15;
    int lkg  = lane >> 4;
    int blk = blockIdx.x;
    int b   = blk >> 10;
    int row = (blk >> 2) & 255;
    int q   = blk & 3;

    for (int idx = tid; idx < 512; idx += 256){
        int c = idx >> 3, p8 = idx & 7;
        bf16x8 v = *(const bf16x8*)&y1b[((size_t)(b*64 + c) << 16) + (size_t)row*256 + q*64 + p8*8];
        #pragma unroll
        for (int j = 0; j < 8; j++) yl[c][p8*8 + j] = bf2f((unsigned short)v[j]);
    }
    __syncthreads();
    if (tid < 64){
        float s = 0.f, ss = 0.f;
        for (int c = 0; c < 64; c++){ float v = yl[c][tid]; s += v; ss += v*v; }
        float mu = s * (1.f/64.f), var = ss * (1.f/64.f) - mu*mu;
        mu_s[tid] = mu; rs_s[tid] = rsqrtf(var + 1e-6f);
    }
    __syncthreads();
    for (int idx = tid; idx < 4096; idx += 256){
        int px = idx & 63, c = idx >> 6;
        xn[px][c] = f2bf((yl[c][px] - mu_s[px]) * rs_s[px] * lnw[c] + lnb[c]);
    }
    __syncthreads();

    for (int hh = 0; hh < 2; hh++){
        int oc0 = hh*128;
        f32x4 acc[8];
        #pragma unroll
        for (int nt = 0; nt < 8; nt++) acc[nt] = (f32x4){0.f,0.f,0.f,0.f};
        #pragma unroll
        for (int kst = 0; kst < 2; kst++){
            bf16x8 a = *(const bf16x8*)&xn[wv*16 + lrow][kst*32 + lkg*8];
            #pragma unroll
            for (int nt = 0; nt < 8; nt++){
                bf16x8 bb = *(const bf16x8*)&wib[(size_t)(oc0 + nt*16 + lrow)*64 + kst*32 + lkg*8];
                acc[nt] = __builtin_amdgcn_mfma_f32_16x16x32_bf16(a, bb, acc[nt], 0, 0, 0);
            }
        }
        #pragma unroll
        for (int nt = 0; nt < 8; nt++)
            #pragma unroll
            for (int r = 0; r < 4; r++)
                ho[nt*16 + lrow][wv*16 + lkg*4 + r] = f2bf(acc[nt][r]);
        __syncthreads();
        for (int idx = tid; idx < 1024; idx += 256){
            int oc = idx >> 3, p8 = idx & 7;
            bf16x8 v = *(const bf16x8*)&ho[oc][p8*8];
            *(bf16x8*)&h[(size_t)(b*256 + oc0 + oc)*65536 + (size_t)row*256 + q*64 + p8*8] = v;
        }
        __syncthreads();
    }
}

// ---------------- FFN part B: depthwise 3x3 (8 px/thread, vectorized) -> patch-major hd
__global__ __launch_bounds__(256) void k_ffn_b(const unsigned short* __restrict__ h,
    const float* __restrict__ w_dw, unsigned short* __restrict__ hd, int nb)
{
    int chunk = blockIdx.x*256 + threadIdx.x;
    int total = nb*256*8192;
    if (chunk >= total) return;
    int c0  = (chunk & 31) * 8;
    int r   = (chunk >> 5) & 255;
    int bch = chunk >> 13;
    int ch  = bch & 255;
    const unsigned short* hp = h + ((size_t)bch << 16);
    const float* wd = w_dw + ch*9;
    float acc[8] = {0,0,0,0,0,0,0,0};
    #pragma unroll
    for (int dy = 0; dy < 3; dy++){
        int y = r + dy - 1;
        if (y < 0 || y > 255) continue;
        const unsigned short* rp = hp + y*256;
        bf16x8 v = *(const bf16x8*)&rp[c0];
        float vf[8];
        #pragma unroll
        for (int j = 0; j < 8; j++) vf[j] = bf2f((unsigned short)v[j]);
        float l  = (c0 > 0)   ? bf2f(rp[c0 - 1]) : 0.f;
        float rg = (c0 < 248) ? bf2f(rp[c0 + 8]) : 0.f;
        float w0 = wd[dy*3+0], w1 = wd[dy*3+1], w2 = wd[dy*3+2];
        acc[0] += w0*l + w1*vf[0] + w2*vf[1];
        #pragma unroll
        for (int j = 1; j < 7; j++) acc[j] += w0*vf[j-1] + w1*vf[j] + w2*vf[j+1];
        acc[7] += w0*vf[6] + w1*vf[7] + w2*rg;
    }
    bf16x8 o;
    #pragma unroll
    for (int j = 0; j < 8; j++) o[j] = (short)f2bf(acc[j]);
    int patch = (r >> 3)*32 + (c0 >> 3);
    *(bf16x8*)&hd[((size_t)bch << 16) + (size_t)patch*64 + (r & 7)*8] = o;
}

// ---------------- FFN spectral conv via MFMA circulant GEMM + gelu*gate -> m (bf16)
__global__ __launch_bounds__(256) void k_conv(const unsigned short* __restrict__ hdu,
    const unsigned short* __restrict__ circ, unsigned short* __restrict__ mbuf)
{
    int tid = threadIdx.x;
    int lane = tid & 63;
    int wv = tid >> 6;
    int lrow = lane & 15;
    int lkg  = lane >> 4;
    int blk = blockIdx.x;
    int b   = blk >> 7;
    int chc = (blk >> 5) & 3;
    int pc  = blk & 31;
    int pbase  = pc*32 + (wv >> 1)*16;
    int chbase = chc*32 + (wv & 1)*16;

    for (int c16 = 0; c16 < 16; c16++){
        int ch = chbase + c16;
        const unsigned short* Ab = hdu + (((size_t)(b*256 + ch)) << 16);
        const unsigned short* Bb = circ + (size_t)ch*4096;
        f32x4 acc[4];
        #pragma unroll
        for (int nt = 0; nt < 4; nt++) acc[nt] = (f32x4){0.f,0.f,0.f,0.f};
        #pragma unroll
        for (int kst = 0; kst < 2; kst++){
            bf16x8 a = *(const bf16x8*)&Ab[(size_t)(pbase + lrow)*64 + kst*32 + lkg*8];
            #pragma unroll
            for (int nt = 0; nt < 4; nt++){
                bf16x8 bb = *(const bf16x8*)&Bb[(size_t)(nt*16 + lrow)*64 + kst*32 + lkg*8];
                acc[nt] = __builtin_amdgcn_mfma_f32_16x16x32_bf16(a, bb, acc[nt], 0, 0, 0);
            }
        }
        const unsigned short* Gb = hdu + (((size_t)(b*256 + 128 + ch)) << 16);
        unsigned short* Mb = mbuf + (((size_t)(b*128 + ch)) << 16);
        #pragma unroll
        for (int nt = 0; nt < 4; nt++){
            #pragma unroll
            for (int r = 0; r < 4; r++){
                int patch = pbase + lkg*4 + r;
                int px = nt*16 + lrow;
                float g = bf2f(Gb[(size_t)patch*64 + px]);
                Mb[(size_t)patch*64 + px] = f2bf(gelu_f(acc[nt][r]) * g);
            }
        }
    }
}

// ---------------- FFN out-projection via MFMA: out = y1 + m @ w_out.T
__global__ __launch_bounds__(256) void k_out(const unsigned short* __restrict__ y1b,
    const unsigned short* __restrict__ mbuf, const unsigned short* __restrict__ wob,
    float* __restrict__ out, int b0)
{
    __shared__ __align__(16) unsigned short mlds[2][64][136];
    int tid = threadIdx.x;
    int lane = tid & 63;
    int wv = tid >> 6;
    int lrow = lane & 15;
    int lkg  = lane >> 4;
    int blk = blockIdx.x;
    int b  = blk >> 9;
    int pp = blk & 511;

    for (int it = 0; it < 8; it++){
        int chunk = tid + it*256;
        int ch = chunk >> 4;
        int p = (chunk >> 3) & 1;
        int px8 = chunk & 7;
        bf16x8 v = *(const bf16x8*)&mbuf[(((size_t)(b*128 + ch)) << 16) + (size_t)(2*pp + p)*64 + px8*8];
        #pragma unroll
        for (int j = 0; j < 8; j++) mlds[p][px8*8 + j][ch] = (unsigned short)v[j];
    }
    __syncthreads();

    int p = wv >> 1;
    int ochalf = wv & 1;
    f32x4 acc[2][4];
    #pragma unroll
    for (int mt = 0; mt < 2; mt++)
        #pragma unroll
        for (int nt = 0; nt < 4; nt++) acc[mt][nt] = (f32x4){0.f,0.f,0.f,0.f};
    #pragma unroll
    for (int kst = 0; kst < 4; kst++){
        bf16x8 a0 = *(const bf16x8*)&wob[(size_t)(ochalf*32 + 0  + lrow)*128 + kst*32 + lkg*8];
        bf16x8 a1 = *(const bf16x8*)&wob[(size_t)(ochalf*32 + 16 + lrow)*128 + kst*32 + lkg*8];
        #pragma unroll
        for (int nt = 0; nt < 4; nt++){
            bf16x8 bb = *(const bf16x8*)&mlds[p][nt*16 + lrow][kst*32 + lkg*8];
            acc[0][nt] = __builtin_amdgcn_mfma_f32_16x16x32_bf16(a0, bb, acc[0][nt], 0, 0, 0);
            acc[1][nt] = __builtin_amdgcn_mfma_f32_16x16x32_bf16(a1, bb, acc[1][nt], 0, 0, 0);
        }
    }
    int patchIdx = 2*pp + p;
    int Rb = (patchIdx >> 5) * 8, Cb = (patchIdx & 31) * 8;
    #pragma unroll
    for (int mt = 0; mt < 2; mt++){
        #pragma unroll
        for (int nt = 0; nt < 4; nt++){
            #pragma unroll
            for (int r = 0; r < 4; r++){
                int oc = ochalf*32 + mt*16 + lkg*4 + r;
                int px = nt*16 + lrow;
                int R = Rb + (px >> 3), C = Cb + (px & 7);
                size_t li = (((size_t)(b*64 + oc)) << 16) + (size_t)R*256 + C;
                size_t go = (((size_t)((b0 + b)*64 + oc)) << 16) + (size_t)R*256 + C;
                out[go] = bf2f(y1b[li]) + acc[mt][nt][r];
            }
        }
    }
}

extern "C" void kernel_launch(void* const* d_in, const int* in_sizes, int n_in,
                              void* d_out, int out_size, void* d_ws, size_t ws_size,
                              hipStream_t stream){
    const float* x        = (const float*)d_in[0];
    const float* ln_w     = (const float*)d_in[1];
    const float* ln_b     = (const float*)d_in[2];
    const float* lnh_w    = (const float*)d_in[3];
    const float* lnh_b    = (const float*)d_in[4];
    const float* w_qkv    = (const float*)d_in[5];
    const float* b_qkv    = (const float*)d_in[6];
    const float* w_proj   = (const float*)d_in[7];
    const float* b_proj   = (const float*)d_in[8];
    const float* rel_tab  = (const float*)d_in[9];
    const float* g_main   = (const float*)d_in[10];
    const float* g_aux    = (const float*)d_in[11];
    const float* g_cross  = (const float*)d_in[12];
    const float* aux_dw   = (const float*)d_in[13];
    const float* aux_pw   = (const float*)d_in[14];
    const float* cg_w1    = (const float*)d_in[15];
    const float* cg_w2    = (const float*)d_in[16];
    const float* attn_ow  = (const float*)d_in[17];
    const float* ffn_in_w = (const float*)d_in[18];
    const float* ffn_dw   = (const float*)d_in[19];
    const float* ffn_ow   = (const float*)d_in[20];
    const float* wb_re    = (const float*)d_in[21];
    const float* wb_im    = (const float*)d_in[22];
    const int*   rel_idx  = (const int*)d_in[23];
    float* out = (float*)d_out;
    (void)in_sizes; (void)n_in; (void)out_size;

    const size_t MBsz = (size_t)1 << 20;
    auto need = [&](int nb)->size_t { return (size_t)nb*72*MBsz + 2*MBsz; };
    int nbmax = 4;
    while (nbmax > 1 && need(nbmax) > ws_size) nbmax >>= 1;

    for (int b0 = 0; b0 < 4; b0 += nbmax){
        int nb = nbmax;
        char* p = (char*)d_ws;
        char* U = p;                      p += (size_t)nb*72*MBsz;
        float* gap  = (float*)p;          p += 4096;
        float* gate = (float*)p;          p += 4096;
        unsigned short* wqb = (unsigned short*)p; p += 576*192*2;
        unsigned short* wpb = (unsigned short*)p; p += 192*192*2;
        float* bias6 = (float*)p;         p += 6*64*64*4;
        unsigned short* circ = (unsigned short*)p; p += 128*4096*2;
        unsigned short* wob  = (unsigned short*)p; p += 64*128*2;
        unsigned short* wib  = (unsigned short*)p; p += 256*64*2;

        // phase-1 overlays (all inside hd's future region [0, nb*32MB))
        float* ll            = (float*)U;                                   // nb*4MB
        unsigned short* highb= (unsigned short*)(U + (size_t)nb*4*MBsz);    // nb*6MB
        float* tmp           = (float*)(U + (size_t)nb*10*MBsz);            // nb*4MB
        float* rll           = (float*)(U + (size_t)nb*14*MBsz);            // nb*4MB
        // phase-2
        unsigned short* hd   = (unsigned short*)U;                          // nb*32MB [0..32)
        unsigned short* h    = (unsigned short*)(U + (size_t)nb*32*MBsz);   // nb*32MB [32..64)
        unsigned short* y1b  = (unsigned short*)(U + (size_t)nb*64*MBsz);   // nb*8MB  [64..72)
        unsigned short* mbuf = (unsigned short*)(U + (size_t)nb*32*MBsz);   // nb*16MB overlays dead h

        k_kcirc<<<128, 256, 0, stream>>>(wb_re, wb_im, circ);
        k_cvt<<<432, 256, 0, stream>>>(w_qkv, w_proj, rel_tab, rel_idx, ffn_ow, ffn_in_w,
                                       wqb, wpb, bias6, wob, wib, gap);
        k_dwt<<<nb*2048, 256, 0, stream>>>(x, ll, highb, gap, nb, b0);
        k_gate<<<nb, 256, 0, stream>>>(gap, cg_w1, cg_w2, gate);
        k_attn<<<nb*256, 256, 0, stream>>>(highb, wqb, wpb, b_qkv, b_proj, bias6,
                                           lnh_w, lnh_b, gate, g_main, g_cross);
        k_dwc_aux<<<nb*512, 256, 0, stream>>>(ll, aux_dw, tmp, nb);
        k_aux_pw<<<nb*256, 256, 0, stream>>>(ll, tmp, aux_pw, g_aux, rll, nb);
        k_iwt_proj<<<nb*1024, 256, 0, stream>>>(rll, highb, x, attn_ow, y1b, nb, b0);
        k_ffn_a<<<nb*1024, 256, 0, stream>>>(y1b, ln_w, ln_b, wib, h, nb);
        k_ffn_b<<<nb*8192, 256, 0, stream>>>(h, ffn_dw, hd, nb);
        k_conv<<<nb*128, 256, 0, stream>>>(hd, circ, mbuf);
        k_out<<<nb*512, 256, 0, stream>>>(y1b, mbuf, wob, out, b0);
    }
}

// Round 11
// 841.122 us; speedup vs baseline: 1.0108x; 1.0108x over previous
//
#include <hip/hip_runtime.h>
#include <hip/hip_bf16.h>
#include <math.h>

#define DIMC 64
#define C3 192
#define NHEADS 6
#define DH 32
#define WSZ 8
#define SHIFTV 4
#define HIDC 128
#define FULLR 256
#define HALFR 128

typedef __attribute__((ext_vector_type(8))) short bf16x8;
typedef __attribute__((ext_vector_type(4))) float f32x4;

__device__ __forceinline__ float gelu_f(float x){
    return 0.5f * x * (1.0f + erff(x * 0.70710678118654752440f));
}
__device__ __forceinline__ unsigned short f2bf(float f){
    union { float f; unsigned u; } v; v.f = f;
    unsigned r = (v.u + 0x7FFF + ((v.u >> 16) & 1)) >> 16;
    return (unsigned short)r;
}
__device__ __forceinline__ float bf2f(unsigned short h){
    union { unsigned u; float f; } v; v.u = ((unsigned)h) << 16;
    return v.f;
}

// ---------------- DWT: ll fp32 (plane), high bf16 (window-token-major), + fused gap partial sums
__global__ __launch_bounds__(256) void k_dwt(const float* __restrict__ x, float* __restrict__ ll,
                                             unsigned short* __restrict__ high, float* __restrict__ gap,
                                             int nb, int b0){
    __shared__ float red[256];
    int idx = blockIdx.x * 256 + threadIdx.x;
    int total = nb << 19;
    if (idx >= total) return;
    int w4 = idx & 63;
    int h  = (idx >> 6) & 127;
    int c  = (idx >> 13) & 63;
    int b  = idx >> 19;
    const float* xp = x + (((size_t)(b0 + b) * DIMC + c) * FULLR + 2*h) * FULLR + 4*w4;
    float4 r0 = *(const float4*)xp;
    float4 r1 = *(const float4*)(xp + FULLR);
    size_t lbase = (((size_t)b*64 + c) << 14) + h*128 + w4*2;
    float x1a = 0.5f*r0.x, x3a = 0.5f*r0.y, x2a = 0.5f*r1.x, x4a = 0.5f*r1.y;
    float x1b = 0.5f*r0.z, x3b = 0.5f*r0.w, x2b = 0.5f*r1.z, x4b = 0.5f*r1.w;
    float2 v;
    v.x = x1a + x2a + x3a + x4a;           v.y = x1b + x2b + x3b + x4b;
    *(float2*)&ll[lbase] = v;
    int hs = (h + SHIFTV) & 127;  int wh = hs >> 3; int rr = hs & 7;
    int ws = (2*w4 + SHIFTV) & 127; int ww = ws >> 3; int cc = ws & 7;
    size_t wbase = ((size_t)(b*256 + wh*16 + ww)) * 12288 + rr*8 + cc;
    unsigned u;
    u = (unsigned)f2bf(-x1a - x2a + x3a + x4a) | ((unsigned)f2bf(-x1b - x2b + x3b + x4b) << 16);
    *(unsigned*)&high[wbase + (size_t)c*64] = u;
    u = (unsigned)f2bf(-x1a + x2a - x3a + x4a) | ((unsigned)f2bf(-x1b + x2b - x3b + x4b) << 16);
    *(unsigned*)&high[wbase + (size_t)(64 + c)*64] = u;
    u = (unsigned)f2bf( x1a - x2a - x3a + x4a) | ((unsigned)f2bf( x1b - x2b - x3b + x4b) << 16);
    *(unsigned*)&high[wbase + (size_t)(128 + c)*64] = u;
    red[threadIdx.x] = v.x + v.y;
    __syncthreads();
    for (int st = 128; st > 0; st >>= 1){
        if (threadIdx.x < st) red[threadIdx.x] += red[threadIdx.x + st];
        __syncthreads();
    }
    if (threadIdx.x == 0) atomicAdd(&gap[b*64 + c], red[0]);
}

// ---------------- gate MLP (gap holds SUM; fold 1/16384)
__global__ __launch_bounds__(256) void k_gate(const float* __restrict__ gap, const float* __restrict__ w1,
                                              const float* __restrict__ w2, float* __restrict__ gate){
    int b = blockIdx.x;
    __shared__ float hid[48];
    __shared__ float g[64];
    if (threadIdx.x < 64) g[threadIdx.x] = gap[b*64 + threadIdx.x] * (1.0f/16384.0f);
    __syncthreads();
    if (threadIdx.x < 48){
        float s = 0.f;
        for (int c = 0; c < 64; c++) s += g[c] * w1[threadIdx.x*64 + c];
        hid[threadIdx.x] = gelu_f(s);
    }
    __syncthreads();
    if (threadIdx.x < C3){
        float s = 0.f;
        for (int j = 0; j < 48; j++) s += hid[j] * w2[threadIdx.x*48 + j];
        gate[b*C3 + threadIdx.x] = 1.0f / (1.0f + expf(-s));
    }
}

// ---------------- weights -> bf16, rel bias table, gap zero
__global__ __launch_bounds__(256) void k_cvt(const float* __restrict__ wq, const float* __restrict__ wp,
    const float* __restrict__ rel_table, const int* __restrict__ rel_idx, const float* __restrict__ wo,
    const float* __restrict__ wi,
    unsigned short* __restrict__ wqb, unsigned short* __restrict__ wpb, float* __restrict__ bias6,
    unsigned short* __restrict__ wob, unsigned short* __restrict__ wib, float* __restrict__ gap){
    int idx = blockIdx.x*256 + threadIdx.x;
    if (idx < 576*192) wqb[idx] = f2bf(wq[idx]);
    if (idx < 192*192) wpb[idx] = f2bf(wp[idx]);
    if (idx < 64*128)  wob[idx] = f2bf(wo[idx]);
    if (idx < 256*64)  wib[idx] = f2bf(wi[idx]);
    if (idx < 256)     gap[idx] = 0.f;
    if (idx < 6*64*64){
        int h = idx >> 12; int ij = idx & 4095;
        bias6[idx] = rel_table[rel_idx[ij]*NHEADS + h];
    }
}

// ---------------- merged spectral kernel + circulant (bf16): one block per channel
__global__ __launch_bounds__(256) void k_kcirc(const float* __restrict__ wr, const float* __restrict__ wi,
                                               unsigned short* __restrict__ circ){
    __shared__ float ksl[64];
    int ch = blockIdx.x;
    int tid = threadIdx.x;
    if (tid < 64){
        int r = tid >> 3, c = tid & 7;
        float s = 0.f;
        for (int u = 0; u < 8; u++){
            for (int v = 0; v < 8; v++){
                float re, im;
                if (v <= 4){ re = wr[ch*40 + u*5 + v]; im = wi[ch*40 + u*5 + v]; }
                else { int u2 = (8-u)&7; int v2 = 8-v; re = wr[ch*40 + u2*5 + v2]; im = -wi[ch*40 + u2*5 + v2]; }
                float ang = (float)(u*r + v*c) * 0.78539816339744831f;
                float cs, sn; __sincosf(ang, &sn, &cs);
                s += re * cs - im * sn;
            }
        }
        ksl[tid] = s * (1.0f/64.0f);
    }
    __syncthreads();
    for (int idx = tid; idx < 4096; idx += 256){
        int o = idx >> 6, i = idx & 63;
        int dr = ((o >> 3) - (i >> 3)) & 7;
        int dc = ((o & 7) - (i & 7)) & 7;
        circ[(size_t)ch*4096 + idx] = f2bf(ksl[dr*8 + dc]);
    }
}

// ---------------- fused shifted-window MHSA via MFMA, in-place on window-major high (round-8 version)
__global__ __launch_bounds__(256, 3) void k_attn(unsigned short* __restrict__ high,
    const unsigned short* __restrict__ wqb, const unsigned short* __restrict__ wpb,
    const float* __restrict__ bqkv, const float* __restrict__ bproj,
    const float* __restrict__ bias6, const float* __restrict__ lnw, const float* __restrict__ lnb,
    const float* __restrict__ gate, const float* __restrict__ gm_p, const float* __restrict__ gc_p)
{
    __shared__ __align__(16) unsigned short xb[64][200];
    __shared__ __align__(16) unsigned short qs[64][40];
    __shared__ __align__(16) unsigned short ks2[64][40];
    __shared__ __align__(16) unsigned short vt[32][72];
    __shared__ __align__(16) unsigned short ps[64][72];
    __shared__ float st_s[4][64], st_ss[4][64];
    __shared__ float mu_s[64], rs_s[64];

    int tid = threadIdx.x;
    int lane = tid & 63;
    int wv = tid >> 6;
    int lrow = lane & 15;
    int lkg  = lane >> 4;
    int blk = blockIdx.x;
    int b  = blk >> 8;
    size_t wbase = (size_t)blk * 12288;
    const float scale = 0.17677669529663687f;
    float gm = gm_p[0], gc = gc_p[0];

    int t = lane, part = wv;
    float vals[48];
    {
        float s = 0.f, ss = 0.f;
        #pragma unroll
        for (int i = 0; i < 48; i++){
            float v = bf2f(high[wbase + (size_t)(part*48 + i)*64 + t]);
            vals[i] = v; s += v; ss += v*v;
        }
        st_s[part][t] = s; st_ss[part][t] = ss;
    }
    __syncthreads();
    if (tid < 64){
        float s = st_s[0][tid]+st_s[1][tid]+st_s[2][tid]+st_s[3][tid];
        float ss = st_ss[0][tid]+st_ss[1][tid]+st_ss[2][tid]+st_ss[3][tid];
        float mu = s*(1.f/C3);
        float var = ss*(1.f/C3) - mu*mu;
        mu_s[tid] = mu; rs_s[tid] = rsqrtf(var + 1e-6f);
    }
    __syncthreads();
    {
        float mu = mu_s[t], rs = rs_s[t];
        #pragma unroll
        for (int i8 = 0; i8 < 6; i8++){
            bf16x8 pk;
            #pragma unroll
            for (int jj = 0; jj < 8; jj++){
                int c = part*48 + i8*8 + jj;
                float nv = (vals[i8*8+jj] - mu) * rs * lnw[c] + lnb[c];
                pk[jj] = (short)f2bf(nv);
            }
            *(bf16x8*)&xb[t][part*48 + i8*8] = pk;
        }
    }
    __syncthreads();

    f32x4 pacc[3][4];
    #pragma unroll
    for (int mt3 = 0; mt3 < 3; mt3++)
        #pragma unroll
        for (int nt = 0; nt < 4; nt++) pacc[mt3][nt] = (f32x4){0.f,0.f,0.f,0.f};

    for (int h = 0; h < NHEADS; h++){
        f32x4 acc[6];
        #pragma unroll
        for (int nt = 0; nt < 6; nt++) acc[nt] = (f32x4){0.f,0.f,0.f,0.f};
        for (int ksU = 0; ksU < 6; ksU++){
            int c0 = ksU*32 + lkg*8;
            bf16x8 a = *(const bf16x8*)&xb[wv*16 + lrow][c0];
            #pragma unroll
            for (int nt = 0; nt < 6; nt++){
                int which = nt >> 1;
                int gr = which*C3 + h*32 + (nt&1)*16 + lrow;
                bf16x8 bb = *(const bf16x8*)&wqb[(size_t)gr*C3 + c0];
                acc[nt] = __builtin_amdgcn_mfma_f32_16x16x32_bf16(a, bb, acc[nt], 0, 0, 0);
            }
        }
        #pragma unroll
        for (int nt = 0; nt < 6; nt++){
            int which = nt >> 1;
            int d = (nt&1)*16 + lrow;
            float bias = bqkv[which*C3 + h*32 + d];
            #pragma unroll
            for (int r = 0; r < 4; r++){
                int row = wv*16 + lkg*4 + r;
                float v = acc[nt][r] + bias;
                if (which == 0)      qs[row][d]  = f2bf(v * scale);
                else if (which == 1) ks2[row][d] = f2bf(v);
                else                 vt[d][row]  = f2bf(v);
            }
        }
        __syncthreads();

        f32x4 sacc[4];
        {
            bf16x8 a = *(const bf16x8*)&qs[wv*16 + lrow][lkg*8];
            #pragma unroll
            for (int nt = 0; nt < 4; nt++){
                bf16x8 bb = *(const bf16x8*)&ks2[nt*16 + lrow][lkg*8];
                f32x4 z = (f32x4){0.f,0.f,0.f,0.f};
                sacc[nt] = __builtin_amdgcn_mfma_f32_16x16x32_bf16(a, bb, z, 0, 0, 0);
            }
        }
        {
            #pragma unroll
            for (int r = 0; r < 4; r++){
                int i = wv*16 + lkg*4 + r;
                float pv[4];
                float s = 0.f;
                #pragma unroll
                for (int nt = 0; nt < 4; nt++){
                    pv[nt] = __expf(sacc[nt][r] + bias6[h*4096 + i*64 + nt*16 + lrow]);
                    s += pv[nt];
                }
                s += __shfl_xor(s, 1); s += __shfl_xor(s, 2);
                s += __shfl_xor(s, 4); s += __shfl_xor(s, 8);
                float inv = 1.0f / s;
                #pragma unroll
                for (int nt = 0; nt < 4; nt++) ps[i][nt*16 + lrow] = f2bf(pv[nt] * inv);
            }
        }
        __syncthreads();

        f32x4 oacc[2];
        #pragma unroll
        for (int nt = 0; nt < 2; nt++) oacc[nt] = (f32x4){0.f,0.f,0.f,0.f};
        #pragma unroll
        for (int kst = 0; kst < 2; kst++){
            bf16x8 a = *(const bf16x8*)&ps[wv*16 + lrow][kst*32 + lkg*8];
            #pragma unroll
            for (int nt = 0; nt < 2; nt++){
                bf16x8 bb = *(const bf16x8*)&vt[nt*16 + lrow][kst*32 + lkg*8];
                oacc[nt] = __builtin_amdgcn_mfma_f32_16x16x32_bf16(a, bb, oacc[nt], 0, 0, 0);
            }
        }
        #pragma unroll
        for (int nt = 0; nt < 2; nt++)
            #pragma unroll
            for (int r = 0; r < 4; r++)
                qs[wv*16 + lkg*4 + r][nt*16 + lrow] = f2bf(oacc[nt][r]);
        __syncthreads();

        #pragma unroll
        for (int mt3 = 0; mt3 < 3; mt3++){
            int o = wv*48 + mt3*16 + lrow;
            bf16x8 a = *(const bf16x8*)&wpb[(size_t)o*C3 + h*32 + lkg*8];
            #pragma unroll
            for (int nt = 0; nt < 4; nt++){
                bf16x8 bb = *(const bf16x8*)&qs[nt*16 + lrow][lkg*8];
                pacc[mt3][nt] = __builtin_amdgcn_mfma_f32_16x16x32_bf16(a, bb, pacc[mt3][nt], 0, 0, 0);
            }
        }
        __syncthreads();
    }

    #pragma unroll
    for (int mt3 = 0; mt3 < 3; mt3++){
        #pragma unroll
        for (int r = 0; r < 4; r++){
            int o = wv*48 + mt3*16 + lkg*4 + r;
            float bias = bproj[o];
            float gf = 1.0f + gc * (gate[b*C3 + o] - 0.5f) * 2.0f;
            #pragma unroll
            for (int nt = 0; nt < 4; nt++){
                int token = nt*16 + lrow;
                size_t gi = wbase + (size_t)o*64 + token;
                float orig = bf2f(high[gi]);
                high[gi] = f2bf((orig + gm*(pacc[mt3][nt][r] + bias)) * gf);
            }
        }
    }
}

// ---------------- aux depthwise 3x3 + gelu
__global__ __launch_bounds__(256) void k_dwc_aux(const float* __restrict__ ll, const float* __restrict__ dw,
                                                 float* __restrict__ tmp, int nb){
    int idx = blockIdx.x*256 + threadIdx.x;
    int total = nb << 17;
    if (idx >= total) return;
    int c0 = (idx & 31) * 4;
    int h  = (idx >> 5) & 127;
    int ch = (idx >> 12) & 63;
    int b  = idx >> 18;
    const float* wd = dw + ch*9;
    const float* plane = ll + (((size_t)b*64 + ch) << 14);
    float acc[4] = {0.f, 0.f, 0.f, 0.f};
    #pragma unroll
    for (int dy = 0; dy < 3; dy++){
        int y = h + dy - 1;
        if (y < 0 || y > 127) continue;
        const float* rp = plane + y*128;
        float4 v = *(const float4*)(rp + c0);
        float l = (c0 > 0)   ? rp[c0 - 1] : 0.f;
        float rg = (c0 < 124) ? rp[c0 + 4] : 0.f;
        float w0 = wd[dy*3+0], w1 = wd[dy*3+1], w2 = wd[dy*3+2];
        acc[0] += w0*l   + w1*v.x + w2*v.y;
        acc[1] += w0*v.x + w1*v.y + w2*v.z;
        acc[2] += w0*v.y + w1*v.z + w2*v.w;
        acc[3] += w0*v.z + w1*v.w + w2*rg;
    }
    float4 o;
    o.x = gelu_f(acc[0]); o.y = gelu_f(acc[1]); o.z = gelu_f(acc[2]); o.w = gelu_f(acc[3]);
    *(float4*)&tmp[(((size_t)b*64 + ch) << 14) + h*128 + c0] = o;
}

// ---------------- aux pointwise, LDS-tiled
__global__ __launch_bounds__(256) void k_aux_pw(const float* __restrict__ ll, const float* __restrict__ tmp,
                                                const float* __restrict__ pw, const float* __restrict__ ga_p,
                                                float* __restrict__ rll, int nb){
    __shared__ float tl[64][65];
    int tid = threadIdx.x;
    int blk = blockIdx.x;
    int b = blk >> 8;
    int pix0 = (blk & 255) * 64;
    for (int idx = tid; idx < 4096; idx += 256){
        int c = idx >> 6, px = idx & 63;
        tl[c][px] = tmp[((size_t)(b*64 + c) << 14) + pix0 + px];
    }
    __syncthreads();
    int px = tid & 63, cq = tid >> 6;
    float ga = ga_p[0];
    for (int og = 0; og < 2; og++){
        int ob = cq*16 + og*8;
        float acc[8] = {0,0,0,0,0,0,0,0};
        for (int c = 0; c < 64; c++){
            float v = tl[c][px];
            #pragma unroll
            for (int j = 0; j < 8; j++) acc[j] += v * pw[(ob+j)*64 + c];
        }
        #pragma unroll
        for (int j = 0; j < 8; j++){
            size_t gi = ((size_t)(b*64 + ob + j) << 14) + pix0 + px;
            rll[gi] = ll[gi] + ga * acc[j];
        }
    }
}

// ---------------- IWT + (iwt - x) @ attn_out_w.T + x -> y1 (bf16)
__global__ __launch_bounds__(256) void k_iwt_proj(const float* __restrict__ rll,
    const unsigned short* __restrict__ high,
    const float* __restrict__ x, const float* __restrict__ wao,
    unsigned short* __restrict__ y1b, int nb, int b0){
    __shared__ float wt[64][65];
    __shared__ float dbuf[64][65];
    __shared__ float xt[64][65];
    int tid = threadIdx.x;
    for (int idx = tid; idx < 4096; idx += 256){
        int o = idx >> 6, i = idx & 63;
        wt[i][o] = wao[o*64 + i];
    }
    int blk = blockIdx.x;
    int seg = blk & 3;
    int ph  = (blk >> 2) & 255;
    int b   = blk >> 10;
    int pw0 = seg * 64;
    int h2 = ph >> 1, p = ph & 1;
    size_t xbase = ((size_t)(b0 + b) * DIMC) * 65536;
    int px = tid & 63;
    int ci = tid >> 6;
    int pwv = pw0 + px;
    int w2 = pwv >> 1, q = pwv & 1;
    float shl = q ? 1.f : -1.f;
    float slh = p ? 1.f : -1.f;
    float shh = (p == q) ? 1.f : -1.f;
    int hs = (h2 + SHIFTV) & 127; int wh = hs >> 3; int rr = hs & 7;
    int ws = (w2 + SHIFTV) & 127; int ww = ws >> 3; int cc = ws & 7;
    size_t wbase = ((size_t)(b*256 + wh*16 + ww)) * 12288 + rr*8 + cc;
    for (int i = ci; i < 64; i += 4){
        float llv = rll[(((size_t)b*64 + i)*128 + h2)*128 + w2];
        float hl = bf2f(high[wbase + (size_t)i*64]);
        float lh = bf2f(high[wbase + (size_t)(64 + i)*64]);
        float hh = bf2f(high[wbase + (size_t)(128 + i)*64]);
        float iw = 0.5f * (llv + shl*hl + slh*lh + shh*hh);
        float xv = x[xbase + (size_t)i*65536 + (size_t)ph*256 + pwv];
        xt[i][px] = xv;
        dbuf[i][px] = iw - xv;
    }
    __syncthreads();
    for (int o = ci; o < 64; o += 4){
        float s0=0.f,s1=0.f,s2=0.f,s3=0.f;
        for (int i = 0; i < 64; i += 4){
            s0 += dbuf[i+0][px] * wt[i+0][o];
            s1 += dbuf[i+1][px] * wt[i+1][o];
            s2 += dbuf[i+2][px] * wt[i+2][o];
            s3 += dbuf[i+3][px] * wt[i+3][o];
        }
        y1b[(((size_t)(b*64 + o)) << 16) + (size_t)ph*256 + pwv] =
            f2bf(xt[o][px] + (s0+s1)+(s2+s3));
    }
}

// ---------------- FFN part A: LN + conv1x1(64->256) via MFMA, bf16 in/out
__global__ __launch_bounds__(256) void k_ffn_a(const unsigned short* __restrict__ y1b,
    const float* __restrict__ lnw, const float* __restrict__ lnb,
    const unsigned short* __restrict__ wib, unsigned short* __restrict__ h, int nb)
{
    __shared__ float yl[64][72];
    __shared__ __align__(16) unsigned short xn[64][72];
    __shared__ __align__(16) unsigned short ho[128][72];
    __shared__ float mu_s[64], rs_s[64];
    int tid = threadIdx.x;
    int lane = tid & 63;
    int wv = tid >> 6;
    int lrow = lane & 15;
    int lkg  = lane >> 4;
    int blk = blockIdx.x;
    int b   = blk >> 10;
    int row = (blk >> 2) & 255;
    int q   = blk & 3;

    for (int idx = tid; idx < 512; idx += 256){
        int c = idx >> 3, p8 = idx & 7;
        bf16x8 v = *(const bf16x8*)&y1b[((size_t)(b*64 + c) << 16) + (size_t)row*256 + q*64 + p8*8];
        #pragma unroll
        for (int j = 0; j < 8; j++) yl[c][p8*8 + j] = bf2f((unsigned short)v[j]);
    }
    __syncthreads();
    if (tid < 64){
        float s = 0.f, ss = 0.f;
        for (int c = 0; c < 64; c++){ float v = yl[c][tid]; s += v; ss += v*v; }
        float mu = s * (1.f/64.f), var = ss * (1.f/64.f) - mu*mu;
        mu_s[tid] = mu; rs_s[tid] = rsqrtf(var + 1e-6f);
    }
    __syncthreads();
    for (int idx = tid; idx < 4096; idx += 256){
        int px = idx & 63, c = idx >> 6;
        xn[px][c] = f2bf((yl[c][px] - mu_s[px]) * rs_s[px] * lnw[c] + lnb[c]);
    }
    __syncthreads();

    for (int hh = 0; hh < 2; hh++){
        int oc0 = hh*128;
        f32x4 acc[8];
        #pragma unroll
        for (int nt = 0; nt < 8; nt++) acc[nt] = (f32x4){0.f,0.f,0.f,0.f};
        #pragma unroll
        for (int kst = 0; kst < 2; kst++){
            bf16x8 a = *(const bf16x8*)&xn[wv*16 + lrow][kst*32 + lkg*8];
            #pragma unroll
            for (int nt = 0; nt < 8; nt++){
                bf16x8 bb = *(const bf16x8*)&wib[(size_t)(oc0 + nt*16 + lrow)*64 + kst*32 + lkg*8];
                acc[nt] = __builtin_amdgcn_mfma_f32_16x16x32_bf16(a, bb, acc[nt], 0, 0, 0);
            }
        }
        #pragma unroll
        for (int nt = 0; nt < 8; nt++)
            #pragma unroll
            for (int r = 0; r < 4; r++)
                ho[nt*16 + lrow][wv*16 + lkg*4 + r] = f2bf(acc[nt][r]);
        __syncthreads();
        for (int idx = tid; idx < 1024; idx += 256){
            int oc = idx >> 3, p8 = idx & 7;
            bf16x8 v = *(const bf16x8*)&ho[oc][p8*8];
            *(bf16x8*)&h[(size_t)(b*256 + oc0 + oc)*65536 + (size_t)row*256 + q*64 + p8*8] = v;
        }
        __syncthreads();
    }
}

// ---------------- FUSED FFN-B + spectral conv: dwconv(h) in LDS -> circulant MFMA + gelu*gate -> mbuf
// block: (b, chc in [0,4), pc = patch-row in [0,32)); handles 32 channels x 32 patches
__global__ __launch_bounds__(256) void k_convb(const unsigned short* __restrict__ h,
    const float* __restrict__ w_dw, const unsigned short* __restrict__ circ,
    unsigned short* __restrict__ mbuf, int nb)
{
    __shared__ __align__(16) unsigned short stage[4][10][272];
    __shared__ __align__(16) unsigned short pm[4][2048];   // patch-major dwconv outputs
    int tid = threadIdx.x;
    int lane = tid & 63;
    int wv = tid >> 6;
    int lrow = lane & 15;
    int lkg  = lane >> 4;
    int blk = blockIdx.x;
    int b   = blk >> 7;
    int chc = (blk >> 5) & 3;
    int pc  = blk & 31;
    int r0 = pc*8;

    auto stage_fn = [&](int c16){
        int chA = chc*32 + c16;
        int chs[4] = {chA, chA+128, chA+16, chA+144};
        for (int j = tid; j < 1280; j += 256){
            int pl = j / 320;
            int rem = j - pl*320;
            int row10 = rem >> 5;
            int c0 = (rem & 31) << 3;
            int gr = r0 + row10 - 1;
            bf16x8 v = (bf16x8){0,0,0,0,0,0,0,0};
            if (gr >= 0 && gr < 256)
                v = *(const bf16x8*)&h[((size_t)(b*256 + chs[pl]) << 16) + (size_t)gr*256 + c0];
            *(bf16x8*)&stage[pl][row10][c0] = v;
        }
    };

    stage_fn(0);
    __syncthreads();

    for (int c16 = 0; c16 < 16; c16++){
        // dwconv: 4 planes x 8 rows x 256 cols (8 px/thread-chunk)
        {
            int chA = chc*32 + c16;
            int chs[4] = {chA, chA+128, chA+16, chA+144};
            for (int j = tid; j < 1024; j += 256){
                int pl = j >> 8;
                int rem = j & 255;
                int r = rem >> 5;
                int c0 = (rem & 31) << 3;
                const float* wd = w_dw + chs[pl]*9;
                float acc[8] = {0,0,0,0,0,0,0,0};
                #pragma unroll
                for (int dy = 0; dy < 3; dy++){
                    const unsigned short* rp = &stage[pl][r+dy][0];
                    bf16x8 v = *(const bf16x8*)&rp[c0];
                    float vf[8];
                    #pragma unroll
                    for (int jj = 0; jj < 8; jj++) vf[jj] = bf2f((unsigned short)v[jj]);
                    float l  = (c0 > 0)   ? bf2f(rp[c0 - 1]) : 0.f;
                    float rg = (c0 < 248) ? bf2f(rp[c0 + 8]) : 0.f;
                    float w0 = wd[dy*3+0], w1 = wd[dy*3+1], w2 = wd[dy*3+2];
                    acc[0] += w0*l + w1*vf[0] + w2*vf[1];
                    #pragma unroll
                    for (int jj = 1; jj < 7; jj++) acc[jj] += w0*vf[jj-1] + w1*vf[jj] + w2*vf[jj+1];
                    acc[7] += w0*vf[6] + w1*vf[7] + w2*rg;
                }
                bf16x8 o;
                #pragma unroll
                for (int jj = 0; jj < 8; jj++) o[jj] = (short)f2bf(acc[jj]);
                *(bf16x8*)&pm[pl][(c0 >> 3)*64 + r*8] = o;
            }
        }
        __syncthreads();
        if (c16 < 15) stage_fn(c16 + 1);
        // MFMA: A = pm[spec plane], B = circ[ch]; gate-mul; write mbuf
        {
            int spl = (wv & 1) * 2;
            int ch = chc*32 + (wv & 1)*16 + c16;
            const unsigned short* Bb = circ + (size_t)ch*4096;
            int plocal = (wv >> 1)*16;
            f32x4 acc4[4];
            #pragma unroll
            for (int nt = 0; nt < 4; nt++) acc4[nt] = (f32x4){0.f,0.f,0.f,0.f};
            #pragma unroll
            for (int kst = 0; kst < 2; kst++){
                bf16x8 a = *(const bf16x8*)&pm[spl][(plocal + lrow)*64 + kst*32 + lkg*8];
                #pragma unroll
                for (int nt = 0; nt < 4; nt++){
                    bf16x8 bb = *(const bf16x8*)&Bb[(size_t)(nt*16 + lrow)*64 + kst*32 + lkg*8];
                    acc4[nt] = __builtin_amdgcn_mfma_f32_16x16x32_bf16(a, bb, acc4[nt], 0, 0, 0);
                }
            }
            unsigned short* Mb = mbuf + ((size_t)(b*128 + ch) << 16);
            #pragma unroll
            for (int nt = 0; nt < 4; nt++){
                #pragma unroll
                for (int r = 0; r < 4; r++){
                    int pl2 = plocal + lkg*4 + r;
                    int px = nt*16 + lrow;
                    float g = bf2f(pm[spl + 1][pl2*64 + px]);
                    Mb[(size_t)(pc*32 + pl2)*64 + px] = f2bf(gelu_f(acc4[nt][r]) * g);
                }
            }
        }
        __syncthreads();
    }
}

// ---------------- FFN out-projection via MFMA: out = y1 + m @ w_out.T
__global__ __launch_bounds__(256) void k_out(const unsigned short* __restrict__ y1b,
    const unsigned short* __restrict__ mbuf, const unsigned short* __restrict__ wob,
    float* __restrict__ out, int b0)
{
    __shared__ __align__(16) unsigned short mlds[2][64][136];
    int tid = threadIdx.x;
    int lane = tid & 63;
    int wv = tid >> 6;
    int lrow = lane & 15;
    int lkg  = lane >> 4;
    int blk = blockIdx.x;
    int b  = blk >> 9;
    int pp = blk & 511;

    for (int it = 0; it < 8; it++){
        int chunk = tid + it*256;
        int ch = chunk >> 4;
        int p = (chunk >> 3) & 1;
        int px8 = chunk & 7;
        bf16x8 v = *(const bf16x8*)&mbuf[(((size_t)(b*128 + ch)) << 16) + (size_t)(2*pp + p)*64 + px8*8];
        #pragma unroll
        for (int j = 0; j < 8; j++) mlds[p][px8*8 + j][ch] = (unsigned short)v[j];
    }
    __syncthreads();

    int p = wv >> 1;
    int ochalf = wv & 1;
    f32x4 acc[2][4];
    #pragma unroll
    for (int mt = 0; mt < 2; mt++)
        #pragma unroll
        for (int nt = 0; nt < 4; nt++) acc[mt][nt] = (f32x4){0.f,0.f,0.f,0.f};
    #pragma unroll
    for (int kst = 0; kst < 4; kst++){
        bf16x8 a0 = *(const bf16x8*)&wob[(size_t)(ochalf*32 + 0  + lrow)*128 + kst*32 + lkg*8];
        bf16x8 a1 = *(const bf16x8*)&wob[(size_t)(ochalf*32 + 16 + lrow)*128 + kst*32 + lkg*8];
        #pragma unroll
        for (int nt = 0; nt < 4; nt++){
            bf16x8 bb = *(const bf16x8*)&mlds[p][nt*16 + lrow][kst*32 + lkg*8];
            acc[0][nt] = __builtin_amdgcn_mfma_f32_16x16x32_bf16(a0, bb, acc[0][nt], 0, 0, 0);
            acc[1][nt] = __builtin_amdgcn_mfma_f32_16x16x32_bf16(a1, bb, acc[1][nt], 0, 0, 0);
        }
    }
    int patchIdx = 2*pp + p;
    int Rb = (patchIdx >> 5) * 8, Cb = (patchIdx & 31) * 8;
    #pragma unroll
    for (int mt = 0; mt < 2; mt++){
        #pragma unroll
        for (int nt = 0; nt < 4; nt++){
            #pragma unroll
            for (int r = 0; r < 4; r++){
                int oc = ochalf*32 + mt*16 + lkg*4 + r;
                int px = nt*16 + lrow;
                int R = Rb + (px >> 3), C = Cb + (px & 7);
                size_t li = (((size_t)(b*64 + oc)) << 16) + (size_t)R*256 + C;
                size_t go = (((size_t)((b0 + b)*64 + oc)) << 16) + (size_t)R*256 + C;
                out[go] = bf2f(y1b[li]) + acc[mt][nt][r];
            }
        }
    }
}

extern "C" void kernel_launch(void* const* d_in, const int* in_sizes, int n_in,
                              void* d_out, int out_size, void* d_ws, size_t ws_size,
                              hipStream_t stream){
    const float* x        = (const float*)d_in[0];
    const float* ln_w     = (const float*)d_in[1];
    const float* ln_b     = (const float*)d_in[2];
    const float* lnh_w    = (const float*)d_in[3];
    const float* lnh_b    = (const float*)d_in[4];
    const float* w_qkv    = (const float*)d_in[5];
    const float* b_qkv    = (const float*)d_in[6];
    const float* w_proj   = (const float*)d_in[7];
    const float* b_proj   = (const float*)d_in[8];
    const float* rel_tab  = (const float*)d_in[9];
    const float* g_main   = (const float*)d_in[10];
    const float* g_aux    = (const float*)d_in[11];
    const float* g_cross  = (const float*)d_in[12];
    const float* aux_dw   = (const float*)d_in[13];
    const float* aux_pw   = (const float*)d_in[14];
    const float* cg_w1    = (const float*)d_in[15];
    const float* cg_w2    = (const float*)d_in[16];
    const float* attn_ow  = (const float*)d_in[17];
    const float* ffn_in_w = (const float*)d_in[18];
    const float* ffn_dw   = (const float*)d_in[19];
    const float* ffn_ow   = (const float*)d_in[20];
    const float* wb_re    = (const float*)d_in[21];
    const float* wb_im    = (const float*)d_in[22];
    const int*   rel_idx  = (const int*)d_in[23];
    float* out = (float*)d_out;
    (void)in_sizes; (void)n_in; (void)out_size;

    const size_t MBsz = (size_t)1 << 20;
    auto need = [&](int nb)->size_t { return (size_t)nb*72*MBsz + 2*MBsz; };
    int nbmax = 4;
    while (nbmax > 1 && need(nbmax) > ws_size) nbmax >>= 1;

    for (int b0 = 0; b0 < 4; b0 += nbmax){
        int nb = nbmax;
        char* p = (char*)d_ws;
        char* U = p;                      p += (size_t)nb*72*MBsz;
        float* gap  = (float*)p;          p += 4096;
        float* gate = (float*)p;          p += 4096;
        unsigned short* wqb = (unsigned short*)p; p += 576*192*2;
        unsigned short* wpb = (unsigned short*)p; p += 192*192*2;
        float* bias6 = (float*)p;         p += 6*64*64*4;
        unsigned short* circ = (unsigned short*)p; p += 128*4096*2;
        unsigned short* wob  = (unsigned short*)p; p += 64*128*2;
        unsigned short* wib  = (unsigned short*)p; p += 256*64*2;

        // phase-1 overlays in U[0, nb*18MB)
        float* ll            = (float*)U;                                   // nb*4MB
        unsigned short* highb= (unsigned short*)(U + (size_t)nb*4*MBsz);    // nb*6MB
        float* tmp           = (float*)(U + (size_t)nb*10*MBsz);            // nb*4MB
        float* rll           = (float*)(U + (size_t)nb*14*MBsz);            // nb*4MB
        // phase-2
        unsigned short* mbuf = (unsigned short*)U;                          // nb*16MB [0..16), overlays dead phase-1
        unsigned short* h    = (unsigned short*)(U + (size_t)nb*32*MBsz);   // nb*32MB [32..64)
        unsigned short* y1b  = (unsigned short*)(U + (size_t)nb*64*MBsz);   // nb*8MB  [64..72)

        k_kcirc<<<128, 256, 0, stream>>>(wb_re, wb_im, circ);
        k_cvt<<<432, 256, 0, stream>>>(w_qkv, w_proj, rel_tab, rel_idx, ffn_ow, ffn_in_w,
                                       wqb, wpb, bias6, wob, wib, gap);
        k_dwt<<<nb*2048, 256, 0, stream>>>(x, ll, highb, gap, nb, b0);
        k_gate<<<nb, 256, 0, stream>>>(gap, cg_w1, cg_w2, gate);
        k_attn<<<nb*256, 256, 0, stream>>>(highb, wqb, wpb, b_qkv, b_proj, bias6,
                                           lnh_w, lnh_b, gate, g_main, g_cross);
        k_dwc_aux<<<nb*512, 256, 0, stream>>>(ll, aux_dw, tmp, nb);
        k_aux_pw<<<nb*256, 256, 0, stream>>>(ll, tmp, aux_pw, g_aux, rll, nb);
        k_iwt_proj<<<nb*1024, 256, 0, stream>>>(rll, highb, x, attn_ow, y1b, nb, b0);
        k_ffn_a<<<nb*1024, 256, 0, stream>>>(y1b, ln_w, ln_b, wib, h, nb);
        k_convb<<<nb*128, 256, 0, stream>>>(h, ffn_dw, circ, mbuf, nb);
        k_out<<<nb*512, 256, 0, stream>>>(y1b, mbuf, wob, out, b0);
    }
}

// Round 12
// 710.630 us; speedup vs baseline: 1.1964x; 1.1836x over previous
//
#include <hip/hip_runtime.h>
#include <hip/hip_bf16.h>
#include <math.h>

#define DIMC 64
#define C3 192
#define NHEADS 6
#define DH 32
#define WSZ 8
#define SHIFTV 4
#define HIDC 128
#define FULLR 256
#define HALFR 128

typedef __attribute__((ext_vector_type(8))) short bf16x8;
typedef __attribute__((ext_vector_type(4))) float f32x4;

__device__ __forceinline__ float gelu_f(float x){
    return 0.5f * x * (1.0f + erff(x * 0.70710678118654752440f));
}
__device__ __forceinline__ unsigned short f2bf(float f){
    union { float f; unsigned u; } v; v.f = f;
    unsigned r = (v.u + 0x7FFF + ((v.u >> 16) & 1)) >> 16;
    return (unsigned short)r;
}
__device__ __forceinline__ float bf2f(unsigned short h){
    union { unsigned u; float f; } v; v.u = ((unsigned)h) << 16;
    return v.f;
}

// ---------------- DWT: ll fp32 (plane), high bf16 (window-token-major), + fused gap partial sums
__global__ __launch_bounds__(256) void k_dwt(const float* __restrict__ x, float* __restrict__ ll,
                                             unsigned short* __restrict__ high, float* __restrict__ gap,
                                             int nb, int b0){
    __shared__ float red[256];
    int idx = blockIdx.x * 256 + threadIdx.x;
    int total = nb << 19;
    if (idx >= total) return;
    int w4 = idx & 63;
    int h  = (idx >> 6) & 127;
    int c  = (idx >> 13) & 63;
    int b  = idx >> 19;
    const float* xp = x + (((size_t)(b0 + b) * DIMC + c) * FULLR + 2*h) * FULLR + 4*w4;
    float4 r0 = *(const float4*)xp;
    float4 r1 = *(const float4*)(xp + FULLR);
    size_t lbase = (((size_t)b*64 + c) << 14) + h*128 + w4*2;
    float x1a = 0.5f*r0.x, x3a = 0.5f*r0.y, x2a = 0.5f*r1.x, x4a = 0.5f*r1.y;
    float x1b = 0.5f*r0.z, x3b = 0.5f*r0.w, x2b = 0.5f*r1.z, x4b = 0.5f*r1.w;
    float2 v;
    v.x = x1a + x2a + x3a + x4a;           v.y = x1b + x2b + x3b + x4b;
    *(float2*)&ll[lbase] = v;
    int hs = (h + SHIFTV) & 127;  int wh = hs >> 3; int rr = hs & 7;
    int ws = (2*w4 + SHIFTV) & 127; int ww = ws >> 3; int cc = ws & 7;
    size_t wbase = ((size_t)(b*256 + wh*16 + ww)) * 12288 + rr*8 + cc;
    unsigned u;
    u = (unsigned)f2bf(-x1a - x2a + x3a + x4a) | ((unsigned)f2bf(-x1b - x2b + x3b + x4b) << 16);
    *(unsigned*)&high[wbase + (size_t)c*64] = u;
    u = (unsigned)f2bf(-x1a + x2a - x3a + x4a) | ((unsigned)f2bf(-x1b + x2b - x3b + x4b) << 16);
    *(unsigned*)&high[wbase + (size_t)(64 + c)*64] = u;
    u = (unsigned)f2bf( x1a - x2a - x3a + x4a) | ((unsigned)f2bf( x1b - x2b - x3b + x4b) << 16);
    *(unsigned*)&high[wbase + (size_t)(128 + c)*64] = u;
    red[threadIdx.x] = v.x + v.y;
    __syncthreads();
    for (int st = 128; st > 0; st >>= 1){
        if (threadIdx.x < st) red[threadIdx.x] += red[threadIdx.x + st];
        __syncthreads();
    }
    if (threadIdx.x == 0) atomicAdd(&gap[b*64 + c], red[0]);
}

// ---------------- gate MLP (gap holds SUM; fold 1/16384)
__global__ __launch_bounds__(256) void k_gate(const float* __restrict__ gap, const float* __restrict__ w1,
                                              const float* __restrict__ w2, float* __restrict__ gate){
    int b = blockIdx.x;
    __shared__ float hid[48];
    __shared__ float g[64];
    if (threadIdx.x < 64) g[threadIdx.x] = gap[b*64 + threadIdx.x] * (1.0f/16384.0f);
    __syncthreads();
    if (threadIdx.x < 48){
        float s = 0.f;
        for (int c = 0; c < 64; c++) s += g[c] * w1[threadIdx.x*64 + c];
        hid[threadIdx.x] = gelu_f(s);
    }
    __syncthreads();
    if (threadIdx.x < C3){
        float s = 0.f;
        for (int j = 0; j < 48; j++) s += hid[j] * w2[threadIdx.x*48 + j];
        gate[b*C3 + threadIdx.x] = 1.0f / (1.0f + expf(-s));
    }
}

// ---------------- weights -> bf16, rel bias table, gap zero
__global__ __launch_bounds__(256) void k_cvt(const float* __restrict__ wq, const float* __restrict__ wp,
    const float* __restrict__ rel_table, const int* __restrict__ rel_idx, const float* __restrict__ wo,
    const float* __restrict__ wi,
    unsigned short* __restrict__ wqb, unsigned short* __restrict__ wpb, float* __restrict__ bias6,
    unsigned short* __restrict__ wob, unsigned short* __restrict__ wib, float* __restrict__ gap){
    int idx = blockIdx.x*256 + threadIdx.x;
    if (idx < 576*192) wqb[idx] = f2bf(wq[idx]);
    if (idx < 192*192) wpb[idx] = f2bf(wp[idx]);
    if (idx < 64*128)  wob[idx] = f2bf(wo[idx]);
    if (idx < 256*64)  wib[idx] = f2bf(wi[idx]);
    if (idx < 256)     gap[idx] = 0.f;
    if (idx < 6*64*64){
        int h = idx >> 12; int ij = idx & 4095;
        bias6[idx] = rel_table[rel_idx[ij]*NHEADS + h];
    }
}

// ---------------- merged spectral kernel + circulant (bf16): one block per channel
__global__ __launch_bounds__(256) void k_kcirc(const float* __restrict__ wr, const float* __restrict__ wi,
                                               unsigned short* __restrict__ circ){
    __shared__ float ksl[64];
    int ch = blockIdx.x;
    int tid = threadIdx.x;
    if (tid < 64){
        int r = tid >> 3, c = tid & 7;
        float s = 0.f;
        for (int u = 0; u < 8; u++){
            for (int v = 0; v < 8; v++){
                float re, im;
                if (v <= 4){ re = wr[ch*40 + u*5 + v]; im = wi[ch*40 + u*5 + v]; }
                else { int u2 = (8-u)&7; int v2 = 8-v; re = wr[ch*40 + u2*5 + v2]; im = -wi[ch*40 + u2*5 + v2]; }
                float ang = (float)(u*r + v*c) * 0.78539816339744831f;
                float cs, sn; __sincosf(ang, &sn, &cs);
                s += re * cs - im * sn;
            }
        }
        ksl[tid] = s * (1.0f/64.0f);
    }
    __syncthreads();
    for (int idx = tid; idx < 4096; idx += 256){
        int o = idx >> 6, i = idx & 63;
        int dr = ((o >> 3) - (i >> 3)) & 7;
        int dc = ((o & 7) - (i & 7)) & 7;
        circ[(size_t)ch*4096 + idx] = f2bf(ksl[dr*8 + dc]);
    }
}

// ---------------- fused shifted-window MHSA via MFMA, in-place on window-major high
__global__ __launch_bounds__(256, 3) void k_attn(unsigned short* __restrict__ high,
    const unsigned short* __restrict__ wqb, const unsigned short* __restrict__ wpb,
    const float* __restrict__ bqkv, const float* __restrict__ bproj,
    const float* __restrict__ bias6, const float* __restrict__ lnw, const float* __restrict__ lnb,
    const float* __restrict__ gate, const float* __restrict__ gm_p, const float* __restrict__ gc_p)
{
    __shared__ __align__(16) unsigned short xb[64][200];
    __shared__ __align__(16) unsigned short qs[64][40];
    __shared__ __align__(16) unsigned short ks2[64][40];
    __shared__ __align__(16) unsigned short vt[32][72];
    __shared__ __align__(16) unsigned short ps[64][72];
    __shared__ float st_s[4][64], st_ss[4][64];
    __shared__ float mu_s[64], rs_s[64];

    int tid = threadIdx.x;
    int lane = tid & 63;
    int wv = tid >> 6;
    int lrow = lane & 15;
    int lkg  = lane >> 4;
    int blk = blockIdx.x;
    int b  = blk >> 8;
    size_t wbase = (size_t)blk * 12288;
    const float scale = 0.17677669529663687f;
    float gm = gm_p[0], gc = gc_p[0];

    int t = lane, part = wv;
    float vals[48];
    {
        float s = 0.f, ss = 0.f;
        #pragma unroll
        for (int i = 0; i < 48; i++){
            float v = bf2f(high[wbase + (size_t)(part*48 + i)*64 + t]);
            vals[i] = v; s += v; ss += v*v;
        }
        st_s[part][t] = s; st_ss[part][t] = ss;
    }
    __syncthreads();
    if (tid < 64){
        float s = st_s[0][tid]+st_s[1][tid]+st_s[2][tid]+st_s[3][tid];
        float ss = st_ss[0][tid]+st_ss[1][tid]+st_ss[2][tid]+st_ss[3][tid];
        float mu = s*(1.f/C3);
        float var = ss*(1.f/C3) - mu*mu;
        mu_s[tid] = mu; rs_s[tid] = rsqrtf(var + 1e-6f);
    }
    __syncthreads();
    {
        float mu = mu_s[t], rs = rs_s[t];
        #pragma unroll
        for (int i8 = 0; i8 < 6; i8++){
            bf16x8 pk;
            #pragma unroll
            for (int jj = 0; jj < 8; jj++){
                int c = part*48 + i8*8 + jj;
                float nv = (vals[i8*8+jj] - mu) * rs * lnw[c] + lnb[c];
                pk[jj] = (short)f2bf(nv);
            }
            *(bf16x8*)&xb[t][part*48 + i8*8] = pk;
        }
    }
    __syncthreads();

    f32x4 pacc[3][4];
    #pragma unroll
    for (int mt3 = 0; mt3 < 3; mt3++)
        #pragma unroll
        for (int nt = 0; nt < 4; nt++) pacc[mt3][nt] = (f32x4){0.f,0.f,0.f,0.f};

    for (int h = 0; h < NHEADS; h++){
        f32x4 acc[6];
        #pragma unroll
        for (int nt = 0; nt < 6; nt++) acc[nt] = (f32x4){0.f,0.f,0.f,0.f};
        for (int ksU = 0; ksU < 6; ksU++){
            int c0 = ksU*32 + lkg*8;
            bf16x8 a = *(const bf16x8*)&xb[wv*16 + lrow][c0];
            #pragma unroll
            for (int nt = 0; nt < 6; nt++){
                int which = nt >> 1;
                int gr = which*C3 + h*32 + (nt&1)*16 + lrow;
                bf16x8 bb = *(const bf16x8*)&wqb[(size_t)gr*C3 + c0];
                acc[nt] = __builtin_amdgcn_mfma_f32_16x16x32_bf16(a, bb, acc[nt], 0, 0, 0);
            }
        }
        #pragma unroll
        for (int nt = 0; nt < 6; nt++){
            int which = nt >> 1;
            int d = (nt&1)*16 + lrow;
            float bias = bqkv[which*C3 + h*32 + d];
            #pragma unroll
            for (int r = 0; r < 4; r++){
                int row = wv*16 + lkg*4 + r;
                float v = acc[nt][r] + bias;
                if (which == 0)      qs[row][d]  = f2bf(v * scale);
                else if (which == 1) ks2[row][d] = f2bf(v);
                else                 vt[d][row]  = f2bf(v);
            }
        }
        __syncthreads();

        f32x4 sacc[4];
        {
            bf16x8 a = *(const bf16x8*)&qs[wv*16 + lrow][lkg*8];
            #pragma unroll
            for (int nt = 0; nt < 4; nt++){
                bf16x8 bb = *(const bf16x8*)&ks2[nt*16 + lrow][lkg*8];
                f32x4 z = (f32x4){0.f,0.f,0.f,0.f};
                sacc[nt] = __builtin_amdgcn_mfma_f32_16x16x32_bf16(a, bb, z, 0, 0, 0);
            }
        }
        {
            #pragma unroll
            for (int r = 0; r < 4; r++){
                int i = wv*16 + lkg*4 + r;
                float pv[4];
                float s = 0.f;
                #pragma unroll
                for (int nt = 0; nt < 4; nt++){
                    pv[nt] = __expf(sacc[nt][r] + bias6[h*4096 + i*64 + nt*16 + lrow]);
                    s += pv[nt];
                }
                s += __shfl_xor(s, 1); s += __shfl_xor(s, 2);
                s += __shfl_xor(s, 4); s += __shfl_xor(s, 8);
                float inv = 1.0f / s;
                #pragma unroll
                for (int nt = 0; nt < 4; nt++) ps[i][nt*16 + lrow] = f2bf(pv[nt] * inv);
            }
        }
        __syncthreads();

        f32x4 oacc[2];
        #pragma unroll
        for (int nt = 0; nt < 2; nt++) oacc[nt] = (f32x4){0.f,0.f,0.f,0.f};
        #pragma unroll
        for (int kst = 0; kst < 2; kst++){
            bf16x8 a = *(const bf16x8*)&ps[wv*16 + lrow][kst*32 + lkg*8];
            #pragma unroll
            for (int nt = 0; nt < 2; nt++){
                bf16x8 bb = *(const bf16x8*)&vt[nt*16 + lrow][kst*32 + lkg*8];
                oacc[nt] = __builtin_amdgcn_mfma_f32_16x16x32_bf16(a, bb, oacc[nt], 0, 0, 0);
            }
        }
        #pragma unroll
        for (int nt = 0; nt < 2; nt++)
            #pragma unroll
            for (int r = 0; r < 4; r++)
                qs[wv*16 + lkg*4 + r][nt*16 + lrow] = f2bf(oacc[nt][r]);
        __syncthreads();

        #pragma unroll
        for (int mt3 = 0; mt3 < 3; mt3++){
            int o = wv*48 + mt3*16 + lrow;
            bf16x8 a = *(const bf16x8*)&wpb[(size_t)o*C3 + h*32 + lkg*8];
            #pragma unroll
            for (int nt = 0; nt < 4; nt++){
                bf16x8 bb = *(const bf16x8*)&qs[nt*16 + lrow][lkg*8];
                pacc[mt3][nt] = __builtin_amdgcn_mfma_f32_16x16x32_bf16(a, bb, pacc[mt3][nt], 0, 0, 0);
            }
        }
        __syncthreads();
    }

    #pragma unroll
    for (int mt3 = 0; mt3 < 3; mt3++){
        #pragma unroll
        for (int r = 0; r < 4; r++){
            int o = wv*48 + mt3*16 + lkg*4 + r;
            float bias = bproj[o];
            float gf = 1.0f + gc * (gate[b*C3 + o] - 0.5f) * 2.0f;
            #pragma unroll
            for (int nt = 0; nt < 4; nt++){
                int token = nt*16 + lrow;
                size_t gi = wbase + (size_t)o*64 + token;
                float orig = bf2f(high[gi]);
                high[gi] = f2bf((orig + gm*(pacc[mt3][nt][r] + bias)) * gf);
            }
        }
    }
}

// ---------------- aux depthwise 3x3 + gelu
__global__ __launch_bounds__(256) void k_dwc_aux(const float* __restrict__ ll, const float* __restrict__ dw,
                                                 float* __restrict__ tmp, int nb){
    int idx = blockIdx.x*256 + threadIdx.x;
    int total = nb << 17;
    if (idx >= total) return;
    int c0 = (idx & 31) * 4;
    int h  = (idx >> 5) & 127;
    int ch = (idx >> 12) & 63;
    int b  = idx >> 18;
    const float* wd = dw + ch*9;
    const float* plane = ll + (((size_t)b*64 + ch) << 14);
    float acc[4] = {0.f, 0.f, 0.f, 0.f};
    #pragma unroll
    for (int dy = 0; dy < 3; dy++){
        int y = h + dy - 1;
        if (y < 0 || y > 127) continue;
        const float* rp = plane + y*128;
        float4 v = *(const float4*)(rp + c0);
        float l = (c0 > 0)   ? rp[c0 - 1] : 0.f;
        float rg = (c0 < 124) ? rp[c0 + 4] : 0.f;
        float w0 = wd[dy*3+0], w1 = wd[dy*3+1], w2 = wd[dy*3+2];
        acc[0] += w0*l   + w1*v.x + w2*v.y;
        acc[1] += w0*v.x + w1*v.y + w2*v.z;
        acc[2] += w0*v.y + w1*v.z + w2*v.w;
        acc[3] += w0*v.z + w1*v.w + w2*rg;
    }
    float4 o;
    o.x = gelu_f(acc[0]); o.y = gelu_f(acc[1]); o.z = gelu_f(acc[2]); o.w = gelu_f(acc[3]);
    *(float4*)&tmp[(((size_t)b*64 + ch) << 14) + h*128 + c0] = o;
}

// ---------------- aux pointwise, LDS-tiled
__global__ __launch_bounds__(256) void k_aux_pw(const float* __restrict__ ll, const float* __restrict__ tmp,
                                                const float* __restrict__ pw, const float* __restrict__ ga_p,
                                                float* __restrict__ rll, int nb){
    __shared__ float tl[64][65];
    int tid = threadIdx.x;
    int blk = blockIdx.x;
    int b = blk >> 8;
    int pix0 = (blk & 255) * 64;
    for (int idx = tid; idx < 4096; idx += 256){
        int c = idx >> 6, px = idx & 63;
        tl[c][px] = tmp[((size_t)(b*64 + c) << 14) + pix0 + px];
    }
    __syncthreads();
    int px = tid & 63, cq = tid >> 6;
    float ga = ga_p[0];
    for (int og = 0; og < 2; og++){
        int ob = cq*16 + og*8;
        float acc[8] = {0,0,0,0,0,0,0,0};
        for (int c = 0; c < 64; c++){
            float v = tl[c][px];
            #pragma unroll
            for (int j = 0; j < 8; j++) acc[j] += v * pw[(ob+j)*64 + c];
        }
        #pragma unroll
        for (int j = 0; j < 8; j++){
            size_t gi = ((size_t)(b*64 + ob + j) << 14) + pix0 + px;
            rll[gi] = ll[gi] + ga * acc[j];
        }
    }
}

// ---------------- IWT + (iwt - x) @ attn_out_w.T + x -> y1 (bf16)
__global__ __launch_bounds__(256) void k_iwt_proj(const float* __restrict__ rll,
    const unsigned short* __restrict__ high,
    const float* __restrict__ x, const float* __restrict__ wao,
    unsigned short* __restrict__ y1b, int nb, int b0){
    __shared__ float wt[64][65];
    __shared__ float dbuf[64][65];
    __shared__ float xt[64][65];
    int tid = threadIdx.x;
    for (int idx = tid; idx < 4096; idx += 256){
        int o = idx >> 6, i = idx & 63;
        wt[i][o] = wao[o*64 + i];
    }
    int blk = blockIdx.x;
    int seg = blk & 3;
    int ph  = (blk >> 2) & 255;
    int b   = blk >> 10;
    int pw0 = seg * 64;
    int h2 = ph >> 1, p = ph & 1;
    size_t xbase = ((size_t)(b0 + b) * DIMC) * 65536;
    int px = tid & 63;
    int ci = tid >> 6;
    int pwv = pw0 + px;
    int w2 = pwv >> 1, q = pwv & 1;
    float shl = q ? 1.f : -1.f;
    float slh = p ? 1.f : -1.f;
    float shh = (p == q) ? 1.f : -1.f;
    int hs = (h2 + SHIFTV) & 127; int wh = hs >> 3; int rr = hs & 7;
    int ws = (w2 + SHIFTV) & 127; int ww = ws >> 3; int cc = ws & 7;
    size_t wbase = ((size_t)(b*256 + wh*16 + ww)) * 12288 + rr*8 + cc;
    for (int i = ci; i < 64; i += 4){
        float llv = rll[(((size_t)b*64 + i)*128 + h2)*128 + w2];
        float hl = bf2f(high[wbase + (size_t)i*64]);
        float lh = bf2f(high[wbase + (size_t)(64 + i)*64]);
        float hh = bf2f(high[wbase + (size_t)(128 + i)*64]);
        float iw = 0.5f * (llv + shl*hl + slh*lh + shh*hh);
        float xv = x[xbase + (size_t)i*65536 + (size_t)ph*256 + pwv];
        xt[i][px] = xv;
        dbuf[i][px] = iw - xv;
    }
    __syncthreads();
    for (int o = ci; o < 64; o += 4){
        float s0=0.f,s1=0.f,s2=0.f,s3=0.f;
        for (int i = 0; i < 64; i += 4){
            s0 += dbuf[i+0][px] * wt[i+0][o];
            s1 += dbuf[i+1][px] * wt[i+1][o];
            s2 += dbuf[i+2][px] * wt[i+2][o];
            s3 += dbuf[i+3][px] * wt[i+3][o];
        }
        y1b[(((size_t)(b*64 + o)) << 16) + (size_t)ph*256 + pwv] =
            f2bf(xt[o][px] + (s0+s1)+(s2+s3));
    }
}

// ---------------- FFN part A: LN + conv1x1(64->256) via MFMA, bf16 in/out
__global__ __launch_bounds__(256) void k_ffn_a(const unsigned short* __restrict__ y1b,
    const float* __restrict__ lnw, const float* __restrict__ lnb,
    const unsigned short* __restrict__ wib, unsigned short* __restrict__ h, int nb)
{
    __shared__ float yl[64][72];
    __shared__ __align__(16) unsigned short xn[64][72];
    __shared__ __align__(16) unsigned short ho[128][72];
    __shared__ float mu_s[64], rs_s[64];
    int tid = threadIdx.x;
    int lane = tid & 63;
    int wv = tid >> 6;
    int lrow = lane & 15;
    int lkg  = lane >> 4;
    int blk = blockIdx.x;
    int b   = blk >> 10;
    int row = (blk >> 2) & 255;
    int q   = blk & 3;

    for (int idx = tid; idx < 512; idx += 256){
        int c = idx >> 3, p8 = idx & 7;
        bf16x8 v = *(const bf16x8*)&y1b[((size_t)(b*64 + c) << 16) + (size_t)row*256 + q*64 + p8*8];
        #pragma unroll
        for (int j = 0; j < 8; j++) yl[c][p8*8 + j] = bf2f((unsigned short)v[j]);
    }
    __syncthreads();
    if (tid < 64){
        float s = 0.f, ss = 0.f;
        for (int c = 0; c < 64; c++){ float v = yl[c][tid]; s += v; ss += v*v; }
        float mu = s * (1.f/64.f), var = ss * (1.f/64.f) - mu*mu;
        mu_s[tid] = mu; rs_s[tid] = rsqrtf(var + 1e-6f);
    }
    __syncthreads();
    for (int idx = tid; idx < 4096; idx += 256){
        int px = idx & 63, c = idx >> 6;
        xn[px][c] = f2bf((yl[c][px] - mu_s[px]) * rs_s[px] * lnw[c] + lnb[c]);
    }
    __syncthreads();

    for (int hh = 0; hh < 2; hh++){
        int oc0 = hh*128;
        f32x4 acc[8];
        #pragma unroll
        for (int nt = 0; nt < 8; nt++) acc[nt] = (f32x4){0.f,0.f,0.f,0.f};
        #pragma unroll
        for (int kst = 0; kst < 2; kst++){
            bf16x8 a = *(const bf16x8*)&xn[wv*16 + lrow][kst*32 + lkg*8];
            #pragma unroll
            for (int nt = 0; nt < 8; nt++){
                bf16x8 bb = *(const bf16x8*)&wib[(size_t)(oc0 + nt*16 + lrow)*64 + kst*32 + lkg*8];
                acc[nt] = __builtin_amdgcn_mfma_f32_16x16x32_bf16(a, bb, acc[nt], 0, 0, 0);
            }
        }
        #pragma unroll
        for (int nt = 0; nt < 8; nt++)
            #pragma unroll
            for (int r = 0; r < 4; r++)
                ho[nt*16 + lrow][wv*16 + lkg*4 + r] = f2bf(acc[nt][r]);
        __syncthreads();
        for (int idx = tid; idx < 1024; idx += 256){
            int oc = idx >> 3, p8 = idx & 7;
            bf16x8 v = *(const bf16x8*)&ho[oc][p8*8];
            *(bf16x8*)&h[(size_t)(b*256 + oc0 + oc)*65536 + (size_t)row*256 + q*64 + p8*8] = v;
        }
        __syncthreads();
    }
}

// ---------------- FUSED FFN-B + spectral conv: dwconv(h) in LDS -> circulant MFMA + gelu*gate -> mbuf
// block: (b, chg in [0,16), pc = patch-row in [0,32)); handles 8 channels x 32 patches
#define PMS 68
__global__ __launch_bounds__(256) void k_convb(const unsigned short* __restrict__ h,
    const float* __restrict__ w_dw, const unsigned short* __restrict__ circ,
    unsigned short* __restrict__ mbuf, int nb)
{
    __shared__ __align__(16) unsigned short stage[4][10][272];
    __shared__ __align__(16) unsigned short pm[4][32*PMS];
    int tid = threadIdx.x;
    int lane = tid & 63;
    int wv = tid >> 6;
    int lrow = lane & 15;
    int lkg  = lane >> 4;
    int blk = blockIdx.x;
    int b   = blk >> 9;
    int chg = (blk >> 5) & 15;
    int pc  = blk & 31;
    int r0 = pc*8;

    auto stage_fn = [&](int c16){
        int chA = chg*8 + c16;
        int chs[4] = {chA, chA+128, chA+4, chA+132};
        for (int j = tid; j < 1280; j += 256){
            int pl = j / 320;
            int rem = j - pl*320;
            int row10 = rem >> 5;
            int c0 = (rem & 31) << 3;
            int gr = r0 + row10 - 1;
            bf16x8 v = (bf16x8){0,0,0,0,0,0,0,0};
            if (gr >= 0 && gr < 256)
                v = *(const bf16x8*)&h[((size_t)(b*256 + chs[pl]) << 16) + (size_t)gr*256 + c0];
            *(bf16x8*)&stage[pl][row10][c0] = v;
        }
    };

    stage_fn(0);
    __syncthreads();

    for (int c16 = 0; c16 < 4; c16++){
        // dwconv: 4 planes x 8 rows x 256 cols
        {
            int chA = chg*8 + c16;
            int chs[4] = {chA, chA+128, chA+4, chA+132};
            for (int j = tid; j < 1024; j += 256){
                int pl = j >> 8;
                int rem = j & 255;
                int r = rem >> 5;
                int c0 = (rem & 31) << 3;
                const float* wd = w_dw + chs[pl]*9;
                float acc[8] = {0,0,0,0,0,0,0,0};
                #pragma unroll
                for (int dy = 0; dy < 3; dy++){
                    const unsigned short* rp = &stage[pl][r+dy][0];
                    bf16x8 v = *(const bf16x8*)&rp[c0];
                    float vf[8];
                    #pragma unroll
                    for (int jj = 0; jj < 8; jj++) vf[jj] = bf2f((unsigned short)v[jj]);
                    float l  = (c0 > 0)   ? bf2f(rp[c0 - 1]) : 0.f;
                    float rg = (c0 < 248) ? bf2f(rp[c0 + 8]) : 0.f;
                    float w0 = wd[dy*3+0], w1 = wd[dy*3+1], w2 = wd[dy*3+2];
                    acc[0] += w0*l + w1*vf[0] + w2*vf[1];
                    #pragma unroll
                    for (int jj = 1; jj < 7; jj++) acc[jj] += w0*vf[jj-1] + w1*vf[jj] + w2*vf[jj+1];
                    acc[7] += w0*vf[6] + w1*vf[7] + w2*rg;
                }
                bf16x8 o;
                #pragma unroll
                for (int jj = 0; jj < 8; jj++) o[jj] = (short)f2bf(acc[jj]);
                *(bf16x8*)&pm[pl][(c0 >> 3)*PMS + r*8] = o;
            }
        }
        __syncthreads();
        if (c16 < 3) stage_fn(c16 + 1);
        // MFMA: A = pm[spec plane], B = circ[ch]; gate-mul; write mbuf
        {
            int spl = (wv & 1) * 2;
            int ch = chg*8 + (wv & 1)*4 + c16;
            const unsigned short* Bb = circ + (size_t)ch*4096;
            int plocal = (wv >> 1)*16;
            f32x4 acc4[4];
            #pragma unroll
            for (int nt = 0; nt < 4; nt++) acc4[nt] = (f32x4){0.f,0.f,0.f,0.f};
            #pragma unroll
            for (int kst = 0; kst < 2; kst++){
                bf16x8 a = *(const bf16x8*)&pm[spl][(plocal + lrow)*PMS + kst*32 + lkg*8];
                #pragma unroll
                for (int nt = 0; nt < 4; nt++){
                    bf16x8 bb = *(const bf16x8*)&Bb[(size_t)(nt*16 + lrow)*64 + kst*32 + lkg*8];
                    acc4[nt] = __builtin_amdgcn_mfma_f32_16x16x32_bf16(a, bb, acc4[nt], 0, 0, 0);
                }
            }
            unsigned short* Mb = mbuf + ((size_t)(b*128 + ch) << 16);
            #pragma unroll
            for (int nt = 0; nt < 4; nt++){
                #pragma unroll
                for (int r = 0; r < 4; r++){
                    int pl2 = plocal + lkg*4 + r;
                    int px = nt*16 + lrow;
                    float g = bf2f(pm[spl + 1][pl2*PMS + px]);
                    Mb[(size_t)(pc*32 + pl2)*64 + px] = f2bf(gelu_f(acc4[nt][r]) * g);
                }
            }
        }
        __syncthreads();
    }
}

// ---------------- FFN out-projection via MFMA: out = y1 + m @ w_out.T
__global__ __launch_bounds__(256) void k_out(const unsigned short* __restrict__ y1b,
    const unsigned short* __restrict__ mbuf, const unsigned short* __restrict__ wob,
    float* __restrict__ out, int b0)
{
    __shared__ __align__(16) unsigned short mlds[2][64][136];
    int tid = threadIdx.x;
    int lane = tid & 63;
    int wv = tid >> 6;
    int lrow = lane & 15;
    int lkg  = lane >> 4;
    int blk = blockIdx.x;
    int b  = blk >> 9;
    int pp = blk & 511;

    for (int it = 0; it < 8; it++){
        int chunk = tid + it*256;
        int ch = chunk >> 4;
        int p = (chunk >> 3) & 1;
        int px8 = chunk & 7;
        bf16x8 v = *(const bf16x8*)&mbuf[(((size_t)(b*128 + ch)) << 16) + (size_t)(2*pp + p)*64 + px8*8];
        #pragma unroll
        for (int j = 0; j < 8; j++) mlds[p][px8*8 + j][ch] = (unsigned short)v[j];
    }
    __syncthreads();

    int p = wv >> 1;
    int ochalf = wv & 1;
    f32x4 acc[2][4];
    #pragma unroll
    for (int mt = 0; mt < 2; mt++)
        #pragma unroll
        for (int nt = 0; nt < 4; nt++) acc[mt][nt] = (f32x4){0.f,0.f,0.f,0.f};
    #pragma unroll
    for (int kst = 0; kst < 4; kst++){
        bf16x8 a0 = *(const bf16x8*)&wob[(size_t)(ochalf*32 + 0  + lrow)*128 + kst*32 + lkg*8];
        bf16x8 a1 = *(const bf16x8*)&wob[(size_t)(ochalf*32 + 16 + lrow)*128 + kst*32 + lkg*8];
        #pragma unroll
        for (int nt = 0; nt < 4; nt++){
            bf16x8 bb = *(const bf16x8*)&mlds[p][nt*16 + lrow][kst*32 + lkg*8];
            acc[0][nt] = __builtin_amdgcn_mfma_f32_16x16x32_bf16(a0, bb, acc[0][nt], 0, 0, 0);
            acc[1][nt] = __builtin_amdgcn_mfma_f32_16x16x32_bf16(a1, bb, acc[1][nt], 0, 0, 0);
        }
    }
    int patchIdx = 2*pp + p;
    int Rb = (patchIdx >> 5) * 8, Cb = (patchIdx & 31) * 8;
    #pragma unroll
    for (int mt = 0; mt < 2; mt++){
        #pragma unroll
        for (int nt = 0; nt < 4; nt++){
            #pragma unroll
            for (int r = 0; r < 4; r++){
                int oc = ochalf*32 + mt*16 + lkg*4 + r;
                int px = nt*16 + lrow;
                int R = Rb + (px >> 3), C = Cb + (px & 7);
                size_t li = (((size_t)(b*64 + oc)) << 16) + (size_t)R*256 + C;
                size_t go = (((size_t)((b0 + b)*64 + oc)) << 16) + (size_t)R*256 + C;
                out[go] = bf2f(y1b[li]) + acc[mt][nt][r];
            }
        }
    }
}

extern "C" void kernel_launch(void* const* d_in, const int* in_sizes, int n_in,
                              void* d_out, int out_size, void* d_ws, size_t ws_size,
                              hipStream_t stream){
    const float* x        = (const float*)d_in[0];
    const float* ln_w     = (const float*)d_in[1];
    const float* ln_b     = (const float*)d_in[2];
    const float* lnh_w    = (const float*)d_in[3];
    const float* lnh_b    = (const float*)d_in[4];
    const float* w_qkv    = (const float*)d_in[5];
    const float* b_qkv    = (const float*)d_in[6];
    const float* w_proj   = (const float*)d_in[7];
    const float* b_proj   = (const float*)d_in[8];
    const float* rel_tab  = (const float*)d_in[9];
    const float* g_main   = (const float*)d_in[10];
    const float* g_aux    = (const float*)d_in[11];
    const float* g_cross  = (const float*)d_in[12];
    const float* aux_dw   = (const float*)d_in[13];
    const float* aux_pw   = (const float*)d_in[14];
    const float* cg_w1    = (const float*)d_in[15];
    const float* cg_w2    = (const float*)d_in[16];
    const float* attn_ow  = (const float*)d_in[17];
    const float* ffn_in_w = (const float*)d_in[18];
    const float* ffn_dw   = (const float*)d_in[19];
    const float* ffn_ow   = (const float*)d_in[20];
    const float* wb_re    = (const float*)d_in[21];
    const float* wb_im    = (const float*)d_in[22];
    const int*   rel_idx  = (const int*)d_in[23];
    float* out = (float*)d_out;
    (void)in_sizes; (void)n_in; (void)out_size;

    const size_t MBsz = (size_t)1 << 20;
    auto need = [&](int nb)->size_t { return (size_t)nb*72*MBsz + 2*MBsz; };
    int nbmax = 4;
    while (nbmax > 1 && need(nbmax) > ws_size) nbmax >>= 1;

    for (int b0 = 0; b0 < 4; b0 += nbmax){
        int nb = nbmax;
        char* p = (char*)d_ws;
        char* U = p;                      p += (size_t)nb*72*MBsz;
        float* gap  = (float*)p;          p += 4096;
        float* gate = (float*)p;          p += 4096;
        unsigned short* wqb = (unsigned short*)p; p += 576*192*2;
        unsigned short* wpb = (unsigned short*)p; p += 192*192*2;
        float* bias6 = (float*)p;         p += 6*64*64*4;
        unsigned short* circ = (unsigned short*)p; p += 128*4096*2;
        unsigned short* wob  = (unsigned short*)p; p += 64*128*2;
        unsigned short* wib  = (unsigned short*)p; p += 256*64*2;

        float* ll            = (float*)U;
        unsigned short* highb= (unsigned short*)(U + (size_t)nb*4*MBsz);
        float* tmp           = (float*)(U + (size_t)nb*10*MBsz);
        float* rll           = (float*)(U + (size_t)nb*14*MBsz);
        unsigned short* mbuf = (unsigned short*)U;
        unsigned short* h    = (unsigned short*)(U + (size_t)nb*32*MBsz);
        unsigned short* y1b  = (unsigned short*)(U + (size_t)nb*64*MBsz);

        k_kcirc<<<128, 256, 0, stream>>>(wb_re, wb_im, circ);
        k_cvt<<<432, 256, 0, stream>>>(w_qkv, w_proj, rel_tab, rel_idx, ffn_ow, ffn_in_w,
                                       wqb, wpb, bias6, wob, wib, gap);
        k_dwt<<<nb*2048, 256, 0, stream>>>(x, ll, highb, gap, nb, b0);
        k_gate<<<nb, 256, 0, stream>>>(gap, cg_w1, cg_w2, gate);
        k_attn<<<nb*256, 256, 0, stream>>>(highb, wqb, wpb, b_qkv, b_proj, bias6,
                                           lnh_w, lnh_b, gate, g_main, g_cross);
        k_dwc_aux<<<nb*512, 256, 0, stream>>>(ll, aux_dw, tmp, nb);
        k_aux_pw<<<nb*256, 256, 0, stream>>>(ll, tmp, aux_pw, g_aux, rll, nb);
        k_iwt_proj<<<nb*1024, 256, 0, stream>>>(rll, highb, x, attn_ow, y1b, nb, b0);
        k_ffn_a<<<nb*1024, 256, 0, stream>>>(y1b, ln_w, ln_b, wib, h, nb);
        k_convb<<<nb*512, 256, 0, stream>>>(h, ffn_dw, circ, mbuf, nb);
        k_out<<<nb*512, 256, 0, stream>>>(y1b, mbuf, wob, out, b0);
    }
}

// Round 13
// 703.195 us; speedup vs baseline: 1.2090x; 1.0106x over previous
//
#include <hip/hip_runtime.h>
#include <hip/hip_bf16.h>
#include <math.h>

#define DIMC 64
#define C3 192
#define NHEADS 6
#define DH 32
#define WSZ 8
#define SHIFTV 4
#define HIDC 128
#define FULLR 256
#define HALFR 128

typedef __attribute__((ext_vector_type(8))) short bf16x8;
typedef __attribute__((ext_vector_type(4))) float f32x4;

__device__ __forceinline__ float gelu_f(float x){
    return 0.5f * x * (1.0f + erff(x * 0.70710678118654752440f));
}
__device__ __forceinline__ unsigned short f2bf(float f){
    union { float f; unsigned u; } v; v.f = f;
    unsigned r = (v.u + 0x7FFF + ((v.u >> 16) & 1)) >> 16;
    return (unsigned short)r;
}
__device__ __forceinline__ float bf2f(unsigned short h){
    union { unsigned u; float f; } v; v.u = ((unsigned)h) << 16;
    return v.f;
}

// ---------------- DWT: ll bf16 (plane), high bf16 (window-token-major), + fused gap partial sums
__global__ __launch_bounds__(256) void k_dwt(const float* __restrict__ x, unsigned short* __restrict__ ll,
                                             unsigned short* __restrict__ high, float* __restrict__ gap,
                                             int nb, int b0){
    __shared__ float red[256];
    int idx = blockIdx.x * 256 + threadIdx.x;
    int total = nb << 19;
    if (idx >= total) return;
    int w4 = idx & 63;
    int h  = (idx >> 6) & 127;
    int c  = (idx >> 13) & 63;
    int b  = idx >> 19;
    const float* xp = x + (((size_t)(b0 + b) * DIMC + c) * FULLR + 2*h) * FULLR + 4*w4;
    float4 r0 = *(const float4*)xp;
    float4 r1 = *(const float4*)(xp + FULLR);
    size_t lbase = (((size_t)b*64 + c) << 14) + h*128 + w4*2;
    float x1a = 0.5f*r0.x, x3a = 0.5f*r0.y, x2a = 0.5f*r1.x, x4a = 0.5f*r1.y;
    float x1b = 0.5f*r0.z, x3b = 0.5f*r0.w, x2b = 0.5f*r1.z, x4b = 0.5f*r1.w;
    float lva = x1a + x2a + x3a + x4a;
    float lvb = x1b + x2b + x3b + x4b;
    *(unsigned*)&ll[lbase] = (unsigned)f2bf(lva) | ((unsigned)f2bf(lvb) << 16);
    int hs = (h + SHIFTV) & 127;  int wh = hs >> 3; int rr = hs & 7;
    int ws = (2*w4 + SHIFTV) & 127; int ww = ws >> 3; int cc = ws & 7;
    size_t wbase = ((size_t)(b*256 + wh*16 + ww)) * 12288 + rr*8 + cc;
    unsigned u;
    u = (unsigned)f2bf(-x1a - x2a + x3a + x4a) | ((unsigned)f2bf(-x1b - x2b + x3b + x4b) << 16);
    *(unsigned*)&high[wbase + (size_t)c*64] = u;
    u = (unsigned)f2bf(-x1a + x2a - x3a + x4a) | ((unsigned)f2bf(-x1b + x2b - x3b + x4b) << 16);
    *(unsigned*)&high[wbase + (size_t)(64 + c)*64] = u;
    u = (unsigned)f2bf( x1a - x2a - x3a + x4a) | ((unsigned)f2bf( x1b - x2b - x3b + x4b) << 16);
    *(unsigned*)&high[wbase + (size_t)(128 + c)*64] = u;
    red[threadIdx.x] = lva + lvb;
    __syncthreads();
    for (int st = 128; st > 0; st >>= 1){
        if (threadIdx.x < st) red[threadIdx.x] += red[threadIdx.x + st];
        __syncthreads();
    }
    if (threadIdx.x == 0) atomicAdd(&gap[b*64 + c], red[0]);
}

// ---------------- gate MLP (gap holds SUM; fold 1/16384)
__global__ __launch_bounds__(256) void k_gate(const float* __restrict__ gap, const float* __restrict__ w1,
                                              const float* __restrict__ w2, float* __restrict__ gate){
    int b = blockIdx.x;
    __shared__ float hid[48];
    __shared__ float g[64];
    if (threadIdx.x < 64) g[threadIdx.x] = gap[b*64 + threadIdx.x] * (1.0f/16384.0f);
    __syncthreads();
    if (threadIdx.x < 48){
        float s = 0.f;
        for (int c = 0; c < 64; c++) s += g[c] * w1[threadIdx.x*64 + c];
        hid[threadIdx.x] = gelu_f(s);
    }
    __syncthreads();
    if (threadIdx.x < C3){
        float s = 0.f;
        for (int j = 0; j < 48; j++) s += hid[j] * w2[threadIdx.x*48 + j];
        gate[b*C3 + threadIdx.x] = 1.0f / (1.0f + expf(-s));
    }
}

// ---------------- weights -> bf16, rel bias table, gap zero
__global__ __launch_bounds__(256) void k_cvt(const float* __restrict__ wq, const float* __restrict__ wp,
    const float* __restrict__ rel_table, const int* __restrict__ rel_idx, const float* __restrict__ wo,
    const float* __restrict__ wi,
    unsigned short* __restrict__ wqb, unsigned short* __restrict__ wpb, float* __restrict__ bias6,
    unsigned short* __restrict__ wob, unsigned short* __restrict__ wib, float* __restrict__ gap){
    int idx = blockIdx.x*256 + threadIdx.x;
    if (idx < 576*192) wqb[idx] = f2bf(wq[idx]);
    if (idx < 192*192) wpb[idx] = f2bf(wp[idx]);
    if (idx < 64*128)  wob[idx] = f2bf(wo[idx]);
    if (idx < 256*64)  wib[idx] = f2bf(wi[idx]);
    if (idx < 256)     gap[idx] = 0.f;
    if (idx < 6*64*64){
        int h = idx >> 12; int ij = idx & 4095;
        bias6[idx] = rel_table[rel_idx[ij]*NHEADS + h];
    }
}

// ---------------- merged spectral kernel + circulant (bf16): one block per channel
__global__ __launch_bounds__(256) void k_kcirc(const float* __restrict__ wr, const float* __restrict__ wi,
                                               unsigned short* __restrict__ circ){
    __shared__ float ksl[64];
    int ch = blockIdx.x;
    int tid = threadIdx.x;
    if (tid < 64){
        int r = tid >> 3, c = tid & 7;
        float s = 0.f;
        for (int u = 0; u < 8; u++){
            for (int v = 0; v < 8; v++){
                float re, im;
                if (v <= 4){ re = wr[ch*40 + u*5 + v]; im = wi[ch*40 + u*5 + v]; }
                else { int u2 = (8-u)&7; int v2 = 8-v; re = wr[ch*40 + u2*5 + v2]; im = -wi[ch*40 + u2*5 + v2]; }
                float ang = (float)(u*r + v*c) * 0.78539816339744831f;
                float cs, sn; __sincosf(ang, &sn, &cs);
                s += re * cs - im * sn;
            }
        }
        ksl[tid] = s * (1.0f/64.0f);
    }
    __syncthreads();
    for (int idx = tid; idx < 4096; idx += 256){
        int o = idx >> 6, i = idx & 63;
        int dr = ((o >> 3) - (i >> 3)) & 7;
        int dc = ((o & 7) - (i & 7)) & 7;
        circ[(size_t)ch*4096 + idx] = f2bf(ksl[dr*8 + dc]);
    }
}

// ---------------- fused shifted-window MHSA via MFMA, in-place on window-major high
__global__ __launch_bounds__(256, 3) void k_attn(unsigned short* __restrict__ high,
    const unsigned short* __restrict__ wqb, const unsigned short* __restrict__ wpb,
    const float* __restrict__ bqkv, const float* __restrict__ bproj,
    const float* __restrict__ bias6, const float* __restrict__ lnw, const float* __restrict__ lnb,
    const float* __restrict__ gate, const float* __restrict__ gm_p, const float* __restrict__ gc_p)
{
    __shared__ __align__(16) unsigned short xb[64][200];
    __shared__ __align__(16) unsigned short qs[64][40];
    __shared__ __align__(16) unsigned short ks2[64][40];
    __shared__ __align__(16) unsigned short vt[32][72];
    __shared__ __align__(16) unsigned short ps[64][72];
    __shared__ float st_s[4][64], st_ss[4][64];
    __shared__ float mu_s[64], rs_s[64];

    int tid = threadIdx.x;
    int lane = tid & 63;
    int wv = tid >> 6;
    int lrow = lane & 15;
    int lkg  = lane >> 4;
    int blk = blockIdx.x;
    int b  = blk >> 8;
    size_t wbase = (size_t)blk * 12288;
    const float scale = 0.17677669529663687f;
    float gm = gm_p[0], gc = gc_p[0];

    int t = lane, part = wv;
    float vals[48];
    {
        float s = 0.f, ss = 0.f;
        #pragma unroll
        for (int i = 0; i < 48; i++){
            float v = bf2f(high[wbase + (size_t)(part*48 + i)*64 + t]);
            vals[i] = v; s += v; ss += v*v;
        }
        st_s[part][t] = s; st_ss[part][t] = ss;
    }
    __syncthreads();
    if (tid < 64){
        float s = st_s[0][tid]+st_s[1][tid]+st_s[2][tid]+st_s[3][tid];
        float ss = st_ss[0][tid]+st_ss[1][tid]+st_ss[2][tid]+st_ss[3][tid];
        float mu = s*(1.f/C3);
        float var = ss*(1.f/C3) - mu*mu;
        mu_s[tid] = mu; rs_s[tid] = rsqrtf(var + 1e-6f);
    }
    __syncthreads();
    {
        float mu = mu_s[t], rs = rs_s[t];
        #pragma unroll
        for (int i8 = 0; i8 < 6; i8++){
            bf16x8 pk;
            #pragma unroll
            for (int jj = 0; jj < 8; jj++){
                int c = part*48 + i8*8 + jj;
                float nv = (vals[i8*8+jj] - mu) * rs * lnw[c] + lnb[c];
                pk[jj] = (short)f2bf(nv);
            }
            *(bf16x8*)&xb[t][part*48 + i8*8] = pk;
        }
    }
    __syncthreads();

    f32x4 pacc[3][4];
    #pragma unroll
    for (int mt3 = 0; mt3 < 3; mt3++)
        #pragma unroll
        for (int nt = 0; nt < 4; nt++) pacc[mt3][nt] = (f32x4){0.f,0.f,0.f,0.f};

    for (int h = 0; h < NHEADS; h++){
        f32x4 acc[6];
        #pragma unroll
        for (int nt = 0; nt < 6; nt++) acc[nt] = (f32x4){0.f,0.f,0.f,0.f};
        for (int ksU = 0; ksU < 6; ksU++){
            int c0 = ksU*32 + lkg*8;
            bf16x8 a = *(const bf16x8*)&xb[wv*16 + lrow][c0];
            #pragma unroll
            for (int nt = 0; nt < 6; nt++){
                int which = nt >> 1;
                int gr = which*C3 + h*32 + (nt&1)*16 + lrow;
                bf16x8 bb = *(const bf16x8*)&wqb[(size_t)gr*C3 + c0];
                acc[nt] = __builtin_amdgcn_mfma_f32_16x16x32_bf16(a, bb, acc[nt], 0, 0, 0);
            }
        }
        #pragma unroll
        for (int nt = 0; nt < 6; nt++){
            int which = nt >> 1;
            int d = (nt&1)*16 + lrow;
            float bias = bqkv[which*C3 + h*32 + d];
            #pragma unroll
            for (int r = 0; r < 4; r++){
                int row = wv*16 + lkg*4 + r;
                float v = acc[nt][r] + bias;
                if (which == 0)      qs[row][d]  = f2bf(v * scale);
                else if (which == 1) ks2[row][d] = f2bf(v);
                else                 vt[d][row]  = f2bf(v);
            }
        }
        __syncthreads();

        f32x4 sacc[4];
        {
            bf16x8 a = *(const bf16x8*)&qs[wv*16 + lrow][lkg*8];
            #pragma unroll
            for (int nt = 0; nt < 4; nt++){
                bf16x8 bb = *(const bf16x8*)&ks2[nt*16 + lrow][lkg*8];
                f32x4 z = (f32x4){0.f,0.f,0.f,0.f};
                sacc[nt] = __builtin_amdgcn_mfma_f32_16x16x32_bf16(a, bb, z, 0, 0, 0);
            }
        }
        {
            #pragma unroll
            for (int r = 0; r < 4; r++){
                int i = wv*16 + lkg*4 + r;
                float pv[4];
                float s = 0.f;
                #pragma unroll
                for (int nt = 0; nt < 4; nt++){
                    pv[nt] = __expf(sacc[nt][r] + bias6[h*4096 + i*64 + nt*16 + lrow]);
                    s += pv[nt];
                }
                s += __shfl_xor(s, 1); s += __shfl_xor(s, 2);
                s += __shfl_xor(s, 4); s += __shfl_xor(s, 8);
                float inv = 1.0f / s;
                #pragma unroll
                for (int nt = 0; nt < 4; nt++) ps[i][nt*16 + lrow] = f2bf(pv[nt] * inv);
            }
        }
        __syncthreads();

        f32x4 oacc[2];
        #pragma unroll
        for (int nt = 0; nt < 2; nt++) oacc[nt] = (f32x4){0.f,0.f,0.f,0.f};
        #pragma unroll
        for (int kst = 0; kst < 2; kst++){
            bf16x8 a = *(const bf16x8*)&ps[wv*16 + lrow][kst*32 + lkg*8];
            #pragma unroll
            for (int nt = 0; nt < 2; nt++){
                bf16x8 bb = *(const bf16x8*)&vt[nt*16 + lrow][kst*32 + lkg*8];
                oacc[nt] = __builtin_amdgcn_mfma_f32_16x16x32_bf16(a, bb, oacc[nt], 0, 0, 0);
            }
        }
        #pragma unroll
        for (int nt = 0; nt < 2; nt++)
            #pragma unroll
            for (int r = 0; r < 4; r++)
                qs[wv*16 + lkg*4 + r][nt*16 + lrow] = f2bf(oacc[nt][r]);
        __syncthreads();

        #pragma unroll
        for (int mt3 = 0; mt3 < 3; mt3++){
            int o = wv*48 + mt3*16 + lrow;
            bf16x8 a = *(const bf16x8*)&wpb[(size_t)o*C3 + h*32 + lkg*8];
            #pragma unroll
            for (int nt = 0; nt < 4; nt++){
                bf16x8 bb = *(const bf16x8*)&qs[nt*16 + lrow][lkg*8];
                pacc[mt3][nt] = __builtin_amdgcn_mfma_f32_16x16x32_bf16(a, bb, pacc[mt3][nt], 0, 0, 0);
            }
        }
        __syncthreads();
    }

    #pragma unroll
    for (int mt3 = 0; mt3 < 3; mt3++){
        #pragma unroll
        for (int r = 0; r < 4; r++){
            int o = wv*48 + mt3*16 + lkg*4 + r;
            float bias = bproj[o];
            float gf = 1.0f + gc * (gate[b*C3 + o] - 0.5f) * 2.0f;
            #pragma unroll
            for (int nt = 0; nt < 4; nt++){
                int token = nt*16 + lrow;
                size_t gi = wbase + (size_t)o*64 + token;
                float orig = bf2f(high[gi]);
                high[gi] = f2bf((orig + gm*(pacc[mt3][nt][r] + bias)) * gf);
            }
        }
    }
}

// ---------------- FUSED aux path: dwconv3x3 + gelu + pointwise, rll = ll + ga*(...), all bf16
// block: (b, row in [0,128), seg in [0,2)) -> 64 output px x 64 channels
__global__ __launch_bounds__(256) void k_aux(const unsigned short* __restrict__ ll,
    const float* __restrict__ dw, const float* __restrict__ pw, const float* __restrict__ ga_p,
    unsigned short* __restrict__ rll, int nb)
{
    __shared__ __align__(16) unsigned short sll[64][3][80];   // 30720 B
    __shared__ float tl[64][65];                              // 16640 B
    int tid = threadIdx.x;
    int blk = blockIdx.x;
    int b   = blk >> 8;
    int row = (blk >> 1) & 127;
    int seg = blk & 1;
    int px0 = seg*64;

    for (int j = tid; j < 1920; j += 256){
        int c = j / 30;
        int rem = j % 30;
        int dy = rem / 10;
        int i8 = rem % 10;
        int gr = row + dy - 1;
        int gp = px0 - 8 + i8*8;
        bf16x8 v = (bf16x8){0,0,0,0,0,0,0,0};
        if (gr >= 0 && gr < 128 && gp >= 0 && gp < 128)
            v = *(const bf16x8*)&ll[(((size_t)b*64 + c) << 14) + gr*128 + gp];
        *(bf16x8*)&sll[c][dy][i8*8] = v;
    }
    __syncthreads();

    int px = tid & 63, cq = tid >> 6;
    for (int ci = cq; ci < 64; ci += 4){
        const float* wd = dw + ci*9;
        float s = 0.f;
        #pragma unroll
        for (int dy = 0; dy < 3; dy++){
            float a0 = bf2f(sll[ci][dy][px+7]);
            float a1 = bf2f(sll[ci][dy][px+8]);
            float a2 = bf2f(sll[ci][dy][px+9]);
            s += wd[dy*3+0]*a0 + wd[dy*3+1]*a1 + wd[dy*3+2]*a2;
        }
        tl[ci][px] = gelu_f(s);
    }
    __syncthreads();

    float ga = ga_p[0];
    for (int og = 0; og < 2; og++){
        int ob = cq*16 + og*8;
        float acc[8] = {0,0,0,0,0,0,0,0};
        for (int c = 0; c < 64; c++){
            float v = tl[c][px];
            #pragma unroll
            for (int j = 0; j < 8; j++) acc[j] += v * pw[(ob+j)*64 + c];
        }
        #pragma unroll
        for (int j = 0; j < 8; j++){
            float base = bf2f(sll[ob+j][1][px+8]);
            rll[(((size_t)b*64 + ob + j) << 14) + row*128 + px0 + px] = f2bf(base + ga * acc[j]);
        }
    }
}

// ---------------- IWT + (iwt - x) @ attn_out_w.T + x -> y1 (bf16)
__global__ __launch_bounds__(256) void k_iwt_proj(const unsigned short* __restrict__ rll,
    const unsigned short* __restrict__ high,
    const float* __restrict__ x, const float* __restrict__ wao,
    unsigned short* __restrict__ y1b, int nb, int b0){
    __shared__ float wt[64][65];
    __shared__ float dbuf[64][65];
    __shared__ float xt[64][65];
    int tid = threadIdx.x;
    for (int idx = tid; idx < 4096; idx += 256){
        int o = idx >> 6, i = idx & 63;
        wt[i][o] = wao[o*64 + i];
    }
    int blk = blockIdx.x;
    int seg = blk & 3;
    int ph  = (blk >> 2) & 255;
    int b   = blk >> 10;
    int pw0 = seg * 64;
    int h2 = ph >> 1, p = ph & 1;
    size_t xbase = ((size_t)(b0 + b) * DIMC) * 65536;
    int px = tid & 63;
    int ci = tid >> 6;
    int pwv = pw0 + px;
    int w2 = pwv >> 1, q = pwv & 1;
    float shl = q ? 1.f : -1.f;
    float slh = p ? 1.f : -1.f;
    float shh = (p == q) ? 1.f : -1.f;
    int hs = (h2 + SHIFTV) & 127; int wh = hs >> 3; int rr = hs & 7;
    int ws = (w2 + SHIFTV) & 127; int ww = ws >> 3; int cc = ws & 7;
    size_t wbase = ((size_t)(b*256 + wh*16 + ww)) * 12288 + rr*8 + cc;
    for (int i = ci; i < 64; i += 4){
        float llv = bf2f(rll[(((size_t)b*64 + i) << 14) + h2*128 + w2]);
        float hl = bf2f(high[wbase + (size_t)i*64]);
        float lh = bf2f(high[wbase + (size_t)(64 + i)*64]);
        float hh = bf2f(high[wbase + (size_t)(128 + i)*64]);
        float iw = 0.5f * (llv + shl*hl + slh*lh + shh*hh);
        float xv = x[xbase + (size_t)i*65536 + (size_t)ph*256 + pwv];
        xt[i][px] = xv;
        dbuf[i][px] = iw - xv;
    }
    __syncthreads();
    for (int o = ci; o < 64; o += 4){
        float s0=0.f,s1=0.f,s2=0.f,s3=0.f;
        for (int i = 0; i < 64; i += 4){
            s0 += dbuf[i+0][px] * wt[i+0][o];
            s1 += dbuf[i+1][px] * wt[i+1][o];
            s2 += dbuf[i+2][px] * wt[i+2][o];
            s3 += dbuf[i+3][px] * wt[i+3][o];
        }
        y1b[(((size_t)(b*64 + o)) << 16) + (size_t)ph*256 + pwv] =
            f2bf(xt[o][px] + (s0+s1)+(s2+s3));
    }
}

// ---------------- FFN part A: LN + conv1x1(64->256) via MFMA, bf16 in/out
__global__ __launch_bounds__(256) void k_ffn_a(const unsigned short* __restrict__ y1b,
    const float* __restrict__ lnw, const float* __restrict__ lnb,
    const unsigned short* __restrict__ wib, unsigned short* __restrict__ h, int nb)
{
    __shared__ float yl[64][72];
    __shared__ __align__(16) unsigned short xn[64][72];
    __shared__ __align__(16) unsigned short ho[128][72];
    __shared__ float mu_s[64], rs_s[64];
    int tid = threadIdx.x;
    int lane = tid & 63;
    int wv = tid >> 6;
    int lrow = lane & 15;
    int lkg  = lane >> 4;
    int blk = blockIdx.x;
    int b   = blk >> 10;
    int row = (blk >> 2) & 255;
    int q   = blk & 3;

    for (int idx = tid; idx < 512; idx += 256){
        int c = idx >> 3, p8 = idx & 7;
        bf16x8 v = *(const bf16x8*)&y1b[((size_t)(b*64 + c) << 16) + (size_t)row*256 + q*64 + p8*8];
        #pragma unroll
        for (int j = 0; j < 8; j++) yl[c][p8*8 + j] = bf2f((unsigned short)v[j]);
    }
    __syncthreads();
    if (tid < 64){
        float s = 0.f, ss = 0.f;
        for (int c = 0; c < 64; c++){ float v = yl[c][tid]; s += v; ss += v*v; }
        float mu = s * (1.f/64.f), var = ss * (1.f/64.f) - mu*mu;
        mu_s[tid] = mu; rs_s[tid] = rsqrtf(var + 1e-6f);
    }
    __syncthreads();
    for (int idx = tid; idx < 4096; idx += 256){
        int px = idx & 63, c = idx >> 6;
        xn[px][c] = f2bf((yl[c][px] - mu_s[px]) * rs_s[px] * lnw[c] + lnb[c]);
    }
    __syncthreads();

    for (int hh = 0; hh < 2; hh++){
        int oc0 = hh*128;
        f32x4 acc[8];
        #pragma unroll
        for (int nt = 0; nt < 8; nt++) acc[nt] = (f32x4){0.f,0.f,0.f,0.f};
        #pragma unroll
        for (int kst = 0; kst < 2; kst++){
            bf16x8 a = *(const bf16x8*)&xn[wv*16 + lrow][kst*32 + lkg*8];
            #pragma unroll
            for (int nt = 0; nt < 8; nt++){
                bf16x8 bb = *(const bf16x8*)&wib[(size_t)(oc0 + nt*16 + lrow)*64 + kst*32 + lkg*8];
                acc[nt] = __builtin_amdgcn_mfma_f32_16x16x32_bf16(a, bb, acc[nt], 0, 0, 0);
            }
        }
        #pragma unroll
        for (int nt = 0; nt < 8; nt++)
            #pragma unroll
            for (int r = 0; r < 4; r++)
                ho[nt*16 + lrow][wv*16 + lkg*4 + r] = f2bf(acc[nt][r]);
        __syncthreads();
        for (int idx = tid; idx < 1024; idx += 256){
            int oc = idx >> 3, p8 = idx & 7;
            bf16x8 v = *(const bf16x8*)&ho[oc][p8*8];
            *(bf16x8*)&h[(size_t)(b*256 + oc0 + oc)*65536 + (size_t)row*256 + q*64 + p8*8] = v;
        }
        __syncthreads();
    }
}

// ---------------- FUSED FFN-B + spectral conv: dwconv(h) in LDS -> circulant MFMA + gelu*gate -> mbuf
#define PMS 68
__global__ __launch_bounds__(256) void k_convb(const unsigned short* __restrict__ h,
    const float* __restrict__ w_dw, const unsigned short* __restrict__ circ,
    unsigned short* __restrict__ mbuf, int nb)
{
    __shared__ __align__(16) unsigned short stage[4][10][272];
    __shared__ __align__(16) unsigned short pm[4][32*PMS];
    int tid = threadIdx.x;
    int lane = tid & 63;
    int wv = tid >> 6;
    int lrow = lane & 15;
    int lkg  = lane >> 4;
    int blk = blockIdx.x;
    int b   = blk >> 9;
    int chg = (blk >> 5) & 15;
    int pc  = blk & 31;
    int r0 = pc*8;

    auto stage_fn = [&](int c16){
        int chA = chg*8 + c16;
        int chs[4] = {chA, chA+128, chA+4, chA+132};
        for (int j = tid; j < 1280; j += 256){
            int pl = j / 320;
            int rem = j - pl*320;
            int row10 = rem >> 5;
            int c0 = (rem & 31) << 3;
            int gr = r0 + row10 - 1;
            bf16x8 v = (bf16x8){0,0,0,0,0,0,0,0};
            if (gr >= 0 && gr < 256)
                v = *(const bf16x8*)&h[((size_t)(b*256 + chs[pl]) << 16) + (size_t)gr*256 + c0];
            *(bf16x8*)&stage[pl][row10][c0] = v;
        }
    };

    stage_fn(0);
    __syncthreads();

    for (int c16 = 0; c16 < 4; c16++){
        {
            int chA = chg*8 + c16;
            int chs[4] = {chA, chA+128, chA+4, chA+132};
            for (int j = tid; j < 1024; j += 256){
                int pl = j >> 8;
                int rem = j & 255;
                int r = rem >> 5;
                int c0 = (rem & 31) << 3;
                const float* wd = w_dw + chs[pl]*9;
                float acc[8] = {0,0,0,0,0,0,0,0};
                #pragma unroll
                for (int dy = 0; dy < 3; dy++){
                    const unsigned short* rp = &stage[pl][r+dy][0];
                    bf16x8 v = *(const bf16x8*)&rp[c0];
                    float vf[8];
                    #pragma unroll
                    for (int jj = 0; jj < 8; jj++) vf[jj] = bf2f((unsigned short)v[jj]);
                    float l  = (c0 > 0)   ? bf2f(rp[c0 - 1]) : 0.f;
                    float rg = (c0 < 248) ? bf2f(rp[c0 + 8]) : 0.f;
                    float w0 = wd[dy*3+0], w1 = wd[dy*3+1], w2 = wd[dy*3+2];
                    acc[0] += w0*l + w1*vf[0] + w2*vf[1];
                    #pragma unroll
                    for (int jj = 1; jj < 7; jj++) acc[jj] += w0*vf[jj-1] + w1*vf[jj] + w2*vf[jj+1];
                    acc[7] += w0*vf[6] + w1*vf[7] + w2*rg;
                }
                bf16x8 o;
                #pragma unroll
                for (int jj = 0; jj < 8; jj++) o[jj] = (short)f2bf(acc[jj]);
                *(bf16x8*)&pm[pl][(c0 >> 3)*PMS + r*8] = o;
            }
        }
        __syncthreads();
        if (c16 < 3) stage_fn(c16 + 1);
        {
            int spl = (wv & 1) * 2;
            int ch = chg*8 + (wv & 1)*4 + c16;
            const unsigned short* Bb = circ + (size_t)ch*4096;
            int plocal = (wv >> 1)*16;
            f32x4 acc4[4];
            #pragma unroll
            for (int nt = 0; nt < 4; nt++) acc4[nt] = (f32x4){0.f,0.f,0.f,0.f};
            #pragma unroll
            for (int kst = 0; kst < 2; kst++){
                bf16x8 a = *(const bf16x8*)&pm[spl][(plocal + lrow)*PMS + kst*32 + lkg*8];
                #pragma unroll
                for (int nt = 0; nt < 4; nt++){
                    bf16x8 bb = *(const bf16x8*)&Bb[(size_t)(nt*16 + lrow)*64 + kst*32 + lkg*8];
                    acc4[nt] = __builtin_amdgcn_mfma_f32_16x16x32_bf16(a, bb, acc4[nt], 0, 0, 0);
                }
            }
            unsigned short* Mb = mbuf + ((size_t)(b*128 + ch) << 16);
            #pragma unroll
            for (int nt = 0; nt < 4; nt++){
                #pragma unroll
                for (int r = 0; r < 4; r++){
                    int pl2 = plocal + lkg*4 + r;
                    int px = nt*16 + lrow;
                    float g = bf2f(pm[spl + 1][pl2*PMS + px]);
                    Mb[(size_t)(pc*32 + pl2)*64 + px] = f2bf(gelu_f(acc4[nt][r]) * g);
                }
            }
        }
        __syncthreads();
    }
}

// ---------------- FFN out-projection via MFMA: out = y1 + m @ w_out.T
__global__ __launch_bounds__(256) void k_out(const unsigned short* __restrict__ y1b,
    const unsigned short* __restrict__ mbuf, const unsigned short* __restrict__ wob,
    float* __restrict__ out, int b0)
{
    __shared__ __align__(16) unsigned short mlds[2][64][136];
    int tid = threadIdx.x;
    int lane = tid & 63;
    int wv = tid >> 6;
    int lrow = lane & 15;
    int lkg  = lane >> 4;
    int blk = blockIdx.x;
    int b  = blk >> 9;
    int pp = blk & 511;

    for (int it = 0; it < 8; it++){
        int chunk = tid + it*256;
        int ch = chunk >> 4;
        int p = (chunk >> 3) & 1;
        int px8 = chunk & 7;
        bf16x8 v = *(const bf16x8*)&mbuf[(((size_t)(b*128 + ch)) << 16) + (size_t)(2*pp + p)*64 + px8*8];
        #pragma unroll
        for (int j = 0; j < 8; j++) mlds[p][px8*8 + j][ch] = (unsigned short)v[j];
    }
    __syncthreads();

    int p = wv >> 1;
    int ochalf = wv & 1;
    f32x4 acc[2][4];
    #pragma unroll
    for (int mt = 0; mt < 2; mt++)
        #pragma unroll
        for (int nt = 0; nt < 4; nt++) acc[mt][nt] = (f32x4){0.f,0.f,0.f,0.f};
    #pragma unroll
    for (int kst = 0; kst < 4; kst++){
        bf16x8 a0 = *(const bf16x8*)&wob[(size_t)(ochalf*32 + 0  + lrow)*128 + kst*32 + lkg*8];
        bf16x8 a1 = *(const bf16x8*)&wob[(size_t)(ochalf*32 + 16 + lrow)*128 + kst*32 + lkg*8];
        #pragma unroll
        for (int nt = 0; nt < 4; nt++){
            bf16x8 bb = *(const bf16x8*)&mlds[p][nt*16 + lrow][kst*32 + lkg*8];
            acc[0][nt] = __builtin_amdgcn_mfma_f32_16x16x32_bf16(a0, bb, acc[0][nt], 0, 0, 0);
            acc[1][nt] = __builtin_amdgcn_mfma_f32_16x16x32_bf16(a1, bb, acc[1][nt], 0, 0, 0);
        }
    }
    int patchIdx = 2*pp + p;
    int Rb = (patchIdx >> 5) * 8, Cb = (patchIdx & 31) * 8;
    #pragma unroll
    for (int mt = 0; mt < 2; mt++){
        #pragma unroll
        for (int nt = 0; nt < 4; nt++){
            #pragma unroll
            for (int r = 0; r < 4; r++){
                int oc = ochalf*32 + mt*16 + lkg*4 + r;
                int px = nt*16 + lrow;
                int R = Rb + (px >> 3), C = Cb + (px & 7);
                size_t li = (((size_t)(b*64 + oc)) << 16) + (size_t)R*256 + C;
                size_t go = (((size_t)((b0 + b)*64 + oc)) << 16) + (size_t)R*256 + C;
                out[go] = bf2f(y1b[li]) + acc[mt][nt][r];
            }
        }
    }
}

extern "C" void kernel_launch(void* const* d_in, const int* in_sizes, int n_in,
                              void* d_out, int out_size, void* d_ws, size_t ws_size,
                              hipStream_t stream){
    const float* x        = (const float*)d_in[0];
    const float* ln_w     = (const float*)d_in[1];
    const float* ln_b     = (const float*)d_in[2];
    const float* lnh_w    = (const float*)d_in[3];
    const float* lnh_b    = (const float*)d_in[4];
    const float* w_qkv    = (const float*)d_in[5];
    const float* b_qkv    = (const float*)d_in[6];
    const float* w_proj   = (const float*)d_in[7];
    const float* b_proj   = (const float*)d_in[8];
    const float* rel_tab  = (const float*)d_in[9];
    const float* g_main   = (const float*)d_in[10];
    const float* g_aux    = (const float*)d_in[11];
    const float* g_cross  = (const float*)d_in[12];
    const float* aux_dw   = (const float*)d_in[13];
    const float* aux_pw   = (const float*)d_in[14];
    const float* cg_w1    = (const float*)d_in[15];
    const float* cg_w2    = (const float*)d_in[16];
    const float* attn_ow  = (const float*)d_in[17];
    const float* ffn_in_w = (const float*)d_in[18];
    const float* ffn_dw   = (const float*)d_in[19];
    const float* ffn_ow   = (const float*)d_in[20];
    const float* wb_re    = (const float*)d_in[21];
    const float* wb_im    = (const float*)d_in[22];
    const int*   rel_idx  = (const int*)d_in[23];
    float* out = (float*)d_out;
    (void)in_sizes; (void)n_in; (void)out_size;

    const size_t MBsz = (size_t)1 << 20;
    auto need = [&](int nb)->size_t { return (size_t)nb*72*MBsz + 2*MBsz; };
    int nbmax = 4;
    while (nbmax > 1 && need(nbmax) > ws_size) nbmax >>= 1;

    for (int b0 = 0; b0 < 4; b0 += nbmax){
        int nb = nbmax;
        char* p = (char*)d_ws;
        char* U = p;                      p += (size_t)nb*72*MBsz;
        float* gap  = (float*)p;          p += 4096;
        float* gate = (float*)p;          p += 4096;
        unsigned short* wqb = (unsigned short*)p; p += 576*192*2;
        unsigned short* wpb = (unsigned short*)p; p += 192*192*2;
        float* bias6 = (float*)p;         p += 6*64*64*4;
        unsigned short* circ = (unsigned short*)p; p += 128*4096*2;
        unsigned short* wob  = (unsigned short*)p; p += 64*128*2;
        unsigned short* wib  = (unsigned short*)p; p += 256*64*2;

        // phase-1 overlays in U[0, nb*10MB) (inside mbuf's future [0, nb*16MB))
        unsigned short* ll   = (unsigned short*)U;                          // nb*2MB
        unsigned short* highb= (unsigned short*)(U + (size_t)nb*2*MBsz);    // nb*6MB
        unsigned short* rll  = (unsigned short*)(U + (size_t)nb*8*MBsz);    // nb*2MB
        // phase-2
        unsigned short* mbuf = (unsigned short*)U;                          // nb*16MB
        unsigned short* h    = (unsigned short*)(U + (size_t)nb*32*MBsz);   // nb*32MB
        unsigned short* y1b  = (unsigned short*)(U + (size_t)nb*64*MBsz);   // nb*8MB

        k_kcirc<<<128, 256, 0, stream>>>(wb_re, wb_im, circ);
        k_cvt<<<432, 256, 0, stream>>>(w_qkv, w_proj, rel_tab, rel_idx, ffn_ow, ffn_in_w,
                                       wqb, wpb, bias6, wob, wib, gap);
        k_dwt<<<nb*2048, 256, 0, stream>>>(x, ll, highb, gap, nb, b0);
        k_gate<<<nb, 256, 0, stream>>>(gap, cg_w1, cg_w2, gate);
        k_attn<<<nb*256, 256, 0, stream>>>(highb, wqb, wpb, b_qkv, b_proj, bias6,
                                           lnh_w, lnh_b, gate, g_main, g_cross);
        k_aux<<<nb*256, 256, 0, stream>>>(ll, aux_dw, aux_pw, g_aux, rll, nb);
        k_iwt_proj<<<nb*1024, 256, 0, stream>>>(rll, highb, x, attn_ow, y1b, nb, b0);
        k_ffn_a<<<nb*1024, 256, 0, stream>>>(y1b, ln_w, ln_b, wib, h, nb);
        k_convb<<<nb*512, 256, 0, stream>>>(h, ffn_dw, circ, mbuf, nb);
        k_out<<<nb*512, 256, 0, stream>>>(y1b, mbuf, wob, out, b0);
    }
}

// Round 14
// 517.920 us; speedup vs baseline: 1.6415x; 1.3577x over previous
//
#include <hip/hip_runtime.h>
#include <hip/hip_bf16.h>
#include <math.h>

#define DIMC 64
#define C3 192
#define NHEADS 6
#define DH 32
#define WSZ 8
#define SHIFTV 4
#define HIDC 128
#define FULLR 256
#define HALFR 128

typedef __attribute__((ext_vector_type(8))) short bf16x8;
typedef __attribute__((ext_vector_type(4))) float f32x4;

__device__ __forceinline__ float gelu_f(float x){
    return 0.5f * x * (1.0f + erff(x * 0.70710678118654752440f));
}
__device__ __forceinline__ unsigned short f2bf(float f){
    union { float f; unsigned u; } v; v.f = f;
    unsigned r = (v.u + 0x7FFF + ((v.u >> 16) & 1)) >> 16;
    return (unsigned short)r;
}
__device__ __forceinline__ float bf2f(unsigned short h){
    union { unsigned u; float f; } v; v.u = ((unsigned)h) << 16;
    return v.f;
}

// ---------------- DWT: ll bf16 (plane), high bf16 (window-token-major), + fused gap partial sums
__global__ __launch_bounds__(256) void k_dwt(const float* __restrict__ x, unsigned short* __restrict__ ll,
                                             unsigned short* __restrict__ high, float* __restrict__ gap,
                                             int nb, int b0){
    __shared__ float red[256];
    int idx = blockIdx.x * 256 + threadIdx.x;
    int total = nb << 19;
    if (idx >= total) return;
    int w4 = idx & 63;
    int h  = (idx >> 6) & 127;
    int c  = (idx >> 13) & 63;
    int b  = idx >> 19;
    const float* xp = x + (((size_t)(b0 + b) * DIMC + c) * FULLR + 2*h) * FULLR + 4*w4;
    float4 r0 = *(const float4*)xp;
    float4 r1 = *(const float4*)(xp + FULLR);
    size_t lbase = (((size_t)b*64 + c) << 14) + h*128 + w4*2;
    float x1a = 0.5f*r0.x, x3a = 0.5f*r0.y, x2a = 0.5f*r1.x, x4a = 0.5f*r1.y;
    float x1b = 0.5f*r0.z, x3b = 0.5f*r0.w, x2b = 0.5f*r1.z, x4b = 0.5f*r1.w;
    float lva = x1a + x2a + x3a + x4a;
    float lvb = x1b + x2b + x3b + x4b;
    *(unsigned*)&ll[lbase] = (unsigned)f2bf(lva) | ((unsigned)f2bf(lvb) << 16);
    int hs = (h + SHIFTV) & 127;  int wh = hs >> 3; int rr = hs & 7;
    int ws = (2*w4 + SHIFTV) & 127; int ww = ws >> 3; int cc = ws & 7;
    size_t wbase = ((size_t)(b*256 + wh*16 + ww)) * 12288 + rr*8 + cc;
    unsigned u;
    u = (unsigned)f2bf(-x1a - x2a + x3a + x4a) | ((unsigned)f2bf(-x1b - x2b + x3b + x4b) << 16);
    *(unsigned*)&high[wbase + (size_t)c*64] = u;
    u = (unsigned)f2bf(-x1a + x2a - x3a + x4a) | ((unsigned)f2bf(-x1b + x2b - x3b + x4b) << 16);
    *(unsigned*)&high[wbase + (size_t)(64 + c)*64] = u;
    u = (unsigned)f2bf( x1a - x2a - x3a + x4a) | ((unsigned)f2bf( x1b - x2b - x3b + x4b) << 16);
    *(unsigned*)&high[wbase + (size_t)(128 + c)*64] = u;
    red[threadIdx.x] = lva + lvb;
    __syncthreads();
    for (int st = 128; st > 0; st >>= 1){
        if (threadIdx.x < st) red[threadIdx.x] += red[threadIdx.x + st];
        __syncthreads();
    }
    if (threadIdx.x == 0) atomicAdd(&gap[b*64 + c], red[0]);
}

// ---------------- gate MLP (gap holds SUM; fold 1/16384)
__global__ __launch_bounds__(256) void k_gate(const float* __restrict__ gap, const float* __restrict__ w1,
                                              const float* __restrict__ w2, float* __restrict__ gate){
    int b = blockIdx.x;
    __shared__ float hid[48];
    __shared__ float g[64];
    if (threadIdx.x < 64) g[threadIdx.x] = gap[b*64 + threadIdx.x] * (1.0f/16384.0f);
    __syncthreads();
    if (threadIdx.x < 48){
        float s = 0.f;
        for (int c = 0; c < 64; c++) s += g[c] * w1[threadIdx.x*64 + c];
        hid[threadIdx.x] = gelu_f(s);
    }
    __syncthreads();
    if (threadIdx.x < C3){
        float s = 0.f;
        for (int j = 0; j < 48; j++) s += hid[j] * w2[threadIdx.x*48 + j];
        gate[b*C3 + threadIdx.x] = 1.0f / (1.0f + expf(-s));
    }
}

// ---------------- weights -> bf16, rel bias table, gap zero
__global__ __launch_bounds__(256) void k_cvt(const float* __restrict__ wq, const float* __restrict__ wp,
    const float* __restrict__ rel_table, const int* __restrict__ rel_idx, const float* __restrict__ wo,
    const float* __restrict__ wi, const float* __restrict__ wao, const float* __restrict__ pwa,
    unsigned short* __restrict__ wqb, unsigned short* __restrict__ wpb, float* __restrict__ bias6,
    unsigned short* __restrict__ wob, unsigned short* __restrict__ wib,
    unsigned short* __restrict__ waob, unsigned short* __restrict__ pwab, float* __restrict__ gap){
    int idx = blockIdx.x*256 + threadIdx.x;
    if (idx < 576*192) wqb[idx] = f2bf(wq[idx]);
    if (idx < 192*192) wpb[idx] = f2bf(wp[idx]);
    if (idx < 64*128)  wob[idx] = f2bf(wo[idx]);
    if (idx < 256*64)  wib[idx] = f2bf(wi[idx]);
    if (idx < 64*64){  waob[idx] = f2bf(wao[idx]); pwab[idx] = f2bf(pwa[idx]); }
    if (idx < 256)     gap[idx] = 0.f;
    if (idx < 6*64*64){
        int h = idx >> 12; int ij = idx & 4095;
        bias6[idx] = rel_table[rel_idx[ij]*NHEADS + h];
    }
}

// ---------------- merged spectral kernel + circulant (bf16): one block per channel
__global__ __launch_bounds__(256) void k_kcirc(const float* __restrict__ wr, const float* __restrict__ wi,
                                               unsigned short* __restrict__ circ){
    __shared__ float ksl[64];
    int ch = blockIdx.x;
    int tid = threadIdx.x;
    if (tid < 64){
        int r = tid >> 3, c = tid & 7;
        float s = 0.f;
        for (int u = 0; u < 8; u++){
            for (int v = 0; v < 8; v++){
                float re, im;
                if (v <= 4){ re = wr[ch*40 + u*5 + v]; im = wi[ch*40 + u*5 + v]; }
                else { int u2 = (8-u)&7; int v2 = 8-v; re = wr[ch*40 + u2*5 + v2]; im = -wi[ch*40 + u2*5 + v2]; }
                float ang = (float)(u*r + v*c) * 0.78539816339744831f;
                float cs, sn; __sincosf(ang, &sn, &cs);
                s += re * cs - im * sn;
            }
        }
        ksl[tid] = s * (1.0f/64.0f);
    }
    __syncthreads();
    for (int idx = tid; idx < 4096; idx += 256){
        int o = idx >> 6, i = idx & 63;
        int dr = ((o >> 3) - (i >> 3)) & 7;
        int dc = ((o & 7) - (i & 7)) & 7;
        circ[(size_t)ch*4096 + idx] = f2bf(ksl[dr*8 + dc]);
    }
}

// ---------------- fused shifted-window MHSA via MFMA, in-place on window-major high
__global__ __launch_bounds__(256, 3) void k_attn(unsigned short* __restrict__ high,
    const unsigned short* __restrict__ wqb, const unsigned short* __restrict__ wpb,
    const float* __restrict__ bqkv, const float* __restrict__ bproj,
    const float* __restrict__ bias6, const float* __restrict__ lnw, const float* __restrict__ lnb,
    const float* __restrict__ gate, const float* __restrict__ gm_p, const float* __restrict__ gc_p)
{
    __shared__ __align__(16) unsigned short xb[64][200];
    __shared__ __align__(16) unsigned short qs[64][40];
    __shared__ __align__(16) unsigned short ks2[64][40];
    __shared__ __align__(16) unsigned short vt[32][72];
    __shared__ __align__(16) unsigned short ps[64][72];
    __shared__ float st_s[4][64], st_ss[4][64];
    __shared__ float mu_s[64], rs_s[64];

    int tid = threadIdx.x;
    int lane = tid & 63;
    int wv = tid >> 6;
    int lrow = lane & 15;
    int lkg  = lane >> 4;
    int blk = blockIdx.x;
    int b  = blk >> 8;
    size_t wbase = (size_t)blk * 12288;
    const float scale = 0.17677669529663687f;
    float gm = gm_p[0], gc = gc_p[0];

    int t = lane, part = wv;
    float vals[48];
    {
        float s = 0.f, ss = 0.f;
        #pragma unroll
        for (int i = 0; i < 48; i++){
            float v = bf2f(high[wbase + (size_t)(part*48 + i)*64 + t]);
            vals[i] = v; s += v; ss += v*v;
        }
        st_s[part][t] = s; st_ss[part][t] = ss;
    }
    __syncthreads();
    if (tid < 64){
        float s = st_s[0][tid]+st_s[1][tid]+st_s[2][tid]+st_s[3][tid];
        float ss = st_ss[0][tid]+st_ss[1][tid]+st_ss[2][tid]+st_ss[3][tid];
        float mu = s*(1.f/C3);
        float var = ss*(1.f/C3) - mu*mu;
        mu_s[tid] = mu; rs_s[tid] = rsqrtf(var + 1e-6f);
    }
    __syncthreads();
    {
        float mu = mu_s[t], rs = rs_s[t];
        #pragma unroll
        for (int i8 = 0; i8 < 6; i8++){
            bf16x8 pk;
            #pragma unroll
            for (int jj = 0; jj < 8; jj++){
                int c = part*48 + i8*8 + jj;
                float nv = (vals[i8*8+jj] - mu) * rs * lnw[c] + lnb[c];
                pk[jj] = (short)f2bf(nv);
            }
            *(bf16x8*)&xb[t][part*48 + i8*8] = pk;
        }
    }
    __syncthreads();

    f32x4 pacc[3][4];
    #pragma unroll
    for (int mt3 = 0; mt3 < 3; mt3++)
        #pragma unroll
        for (int nt = 0; nt < 4; nt++) pacc[mt3][nt] = (f32x4){0.f,0.f,0.f,0.f};

    for (int h = 0; h < NHEADS; h++){
        f32x4 acc[6];
        #pragma unroll
        for (int nt = 0; nt < 6; nt++) acc[nt] = (f32x4){0.f,0.f,0.f,0.f};
        __builtin_amdgcn_s_setprio(1);
        for (int ksU = 0; ksU < 6; ksU++){
            int c0 = ksU*32 + lkg*8;
            bf16x8 a = *(const bf16x8*)&xb[wv*16 + lrow][c0];
            #pragma unroll
            for (int nt = 0; nt < 6; nt++){
                int which = nt >> 1;
                int gr = which*C3 + h*32 + (nt&1)*16 + lrow;
                bf16x8 bb = *(const bf16x8*)&wqb[(size_t)gr*C3 + c0];
                acc[nt] = __builtin_amdgcn_mfma_f32_16x16x32_bf16(a, bb, acc[nt], 0, 0, 0);
            }
        }
        __builtin_amdgcn_s_setprio(0);
        #pragma unroll
        for (int nt = 0; nt < 6; nt++){
            int which = nt >> 1;
            int d = (nt&1)*16 + lrow;
            float bias = bqkv[which*C3 + h*32 + d];
            #pragma unroll
            for (int r = 0; r < 4; r++){
                int row = wv*16 + lkg*4 + r;
                float v = acc[nt][r] + bias;
                if (which == 0)      qs[row][d]  = f2bf(v * scale);
                else if (which == 1) ks2[row][d] = f2bf(v);
                else                 vt[d][row]  = f2bf(v);
            }
        }
        __syncthreads();

        f32x4 sacc[4];
        {
            bf16x8 a = *(const bf16x8*)&qs[wv*16 + lrow][lkg*8];
            #pragma unroll
            for (int nt = 0; nt < 4; nt++){
                bf16x8 bb = *(const bf16x8*)&ks2[nt*16 + lrow][lkg*8];
                f32x4 z = (f32x4){0.f,0.f,0.f,0.f};
                sacc[nt] = __builtin_amdgcn_mfma_f32_16x16x32_bf16(a, bb, z, 0, 0, 0);
            }
        }
        {
            #pragma unroll
            for (int r = 0; r < 4; r++){
                int i = wv*16 + lkg*4 + r;
                float pv[4];
                float s = 0.f;
                #pragma unroll
                for (int nt = 0; nt < 4; nt++){
                    pv[nt] = __expf(sacc[nt][r] + bias6[h*4096 + i*64 + nt*16 + lrow]);
                    s += pv[nt];
                }
                s += __shfl_xor(s, 1); s += __shfl_xor(s, 2);
                s += __shfl_xor(s, 4); s += __shfl_xor(s, 8);
                float inv = 1.0f / s;
                #pragma unroll
                for (int nt = 0; nt < 4; nt++) ps[i][nt*16 + lrow] = f2bf(pv[nt] * inv);
            }
        }
        __syncthreads();

        f32x4 oacc[2];
        #pragma unroll
        for (int nt = 0; nt < 2; nt++) oacc[nt] = (f32x4){0.f,0.f,0.f,0.f};
        #pragma unroll
        for (int kst = 0; kst < 2; kst++){
            bf16x8 a = *(const bf16x8*)&ps[wv*16 + lrow][kst*32 + lkg*8];
            #pragma unroll
            for (int nt = 0; nt < 2; nt++){
                bf16x8 bb = *(const bf16x8*)&vt[nt*16 + lrow][kst*32 + lkg*8];
                oacc[nt] = __builtin_amdgcn_mfma_f32_16x16x32_bf16(a, bb, oacc[nt], 0, 0, 0);
            }
        }
        #pragma unroll
        for (int nt = 0; nt < 2; nt++)
            #pragma unroll
            for (int r = 0; r < 4; r++)
                qs[wv*16 + lkg*4 + r][nt*16 + lrow] = f2bf(oacc[nt][r]);
        __syncthreads();

        __builtin_amdgcn_s_setprio(1);
        #pragma unroll
        for (int mt3 = 0; mt3 < 3; mt3++){
            int o = wv*48 + mt3*16 + lrow;
            bf16x8 a = *(const bf16x8*)&wpb[(size_t)o*C3 + h*32 + lkg*8];
            #pragma unroll
            for (int nt = 0; nt < 4; nt++){
                bf16x8 bb = *(const bf16x8*)&qs[nt*16 + lrow][lkg*8];
                pacc[mt3][nt] = __builtin_amdgcn_mfma_f32_16x16x32_bf16(a, bb, pacc[mt3][nt], 0, 0, 0);
            }
        }
        __builtin_amdgcn_s_setprio(0);
        __syncthreads();
    }

    #pragma unroll
    for (int mt3 = 0; mt3 < 3; mt3++){
        #pragma unroll
        for (int r = 0; r < 4; r++){
            int o = wv*48 + mt3*16 + lkg*4 + r;
            float bias = bproj[o];
            float gf = 1.0f + gc * (gate[b*C3 + o] - 0.5f) * 2.0f;
            #pragma unroll
            for (int nt = 0; nt < 4; nt++){
                int token = nt*16 + lrow;
                size_t gi = wbase + (size_t)o*64 + token;
                float orig = bf2f(high[gi]);
                high[gi] = f2bf((orig + gm*(pacc[mt3][nt][r] + bias)) * gf);
            }
        }
    }
}

// ---------------- FUSED aux path: dwconv3x3 + gelu + pointwise (MFMA), rll = ll + ga*(...), bf16
// block: (b, row in [0,128), seg in [0,2)) -> 64 output px x 64 channels
__global__ __launch_bounds__(256) void k_aux(const unsigned short* __restrict__ ll,
    const float* __restrict__ dw, const unsigned short* __restrict__ pwab, const float* __restrict__ ga_p,
    unsigned short* __restrict__ rll, int nb)
{
    __shared__ __align__(16) unsigned short sll[64][3][80];   // 30720 B
    __shared__ __align__(16) unsigned short tlb[64][72];      // 9216 B
    int tid = threadIdx.x;
    int blk = blockIdx.x;
    int b   = blk >> 8;
    int row = (blk >> 1) & 127;
    int seg = blk & 1;
    int px0 = seg*64;

    for (int j = tid; j < 1920; j += 256){
        int c = j / 30;
        int rem = j % 30;
        int dy = rem / 10;
        int i8 = rem % 10;
        int gr = row + dy - 1;
        int gp = px0 - 8 + i8*8;
        bf16x8 v = (bf16x8){0,0,0,0,0,0,0,0};
        if (gr >= 0 && gr < 128 && gp >= 0 && gp < 128)
            v = *(const bf16x8*)&ll[(((size_t)b*64 + c) << 14) + gr*128 + gp];
        *(bf16x8*)&sll[c][dy][i8*8] = v;
    }
    __syncthreads();

    int px = tid & 63, cq = tid >> 6;
    for (int ci = cq; ci < 64; ci += 4){
        const float* wd = dw + ci*9;
        float s = 0.f;
        #pragma unroll
        for (int dy = 0; dy < 3; dy++){
            float a0 = bf2f(sll[ci][dy][px+7]);
            float a1 = bf2f(sll[ci][dy][px+8]);
            float a2 = bf2f(sll[ci][dy][px+9]);
            s += wd[dy*3+0]*a0 + wd[dy*3+1]*a1 + wd[dy*3+2]*a2;
        }
        tlb[px][ci] = f2bf(gelu_f(s));
    }
    __syncthreads();

    int lane = tid & 63;
    int wv = tid >> 6;
    int lrow = lane & 15;
    int lkg  = lane >> 4;
    float ga = ga_p[0];
    f32x4 acc[4];
    #pragma unroll
    for (int nt = 0; nt < 4; nt++) acc[nt] = (f32x4){0.f,0.f,0.f,0.f};
    #pragma unroll
    for (int kst = 0; kst < 2; kst++){
        bf16x8 a = *(const bf16x8*)&pwab[(size_t)(wv*16 + lrow)*64 + kst*32 + lkg*8];
        #pragma unroll
        for (int nt = 0; nt < 4; nt++){
            bf16x8 bb = *(const bf16x8*)&tlb[nt*16 + lrow][kst*32 + lkg*8];
            acc[nt] = __builtin_amdgcn_mfma_f32_16x16x32_bf16(a, bb, acc[nt], 0, 0, 0);
        }
    }
    #pragma unroll
    for (int nt = 0; nt < 4; nt++){
        #pragma unroll
        for (int r = 0; r < 4; r++){
            int o = wv*16 + lkg*4 + r;
            int pxx = nt*16 + lrow;
            float base = bf2f(sll[o][1][pxx + 8]);
            rll[(((size_t)b*64 + o) << 14) + row*128 + px0 + pxx] = f2bf(base + ga * acc[nt][r]);
        }
    }
}

// ---------------- IWT + (iwt - x) @ attn_out_w.T + x -> y1 (bf16), proj via MFMA
__global__ __launch_bounds__(256) void k_iwt_proj(const unsigned short* __restrict__ rll,
    const unsigned short* __restrict__ high,
    const float* __restrict__ x, const unsigned short* __restrict__ waob,
    unsigned short* __restrict__ y1b, int nb, int b0){
    __shared__ __align__(16) unsigned short dbufT[64][72];    // [px][i]
    __shared__ float xt[64][65];
    int tid = threadIdx.x;
    int blk = blockIdx.x;
    int seg = blk & 3;
    int ph  = (blk >> 2) & 255;
    int b   = blk >> 10;
    int pw0 = seg * 64;
    int h2 = ph >> 1, p = ph & 1;
    size_t xbase = ((size_t)(b0 + b) * DIMC) * 65536;
    int px = tid & 63;
    int ci = tid >> 6;
    int pwv = pw0 + px;
    int w2 = pwv >> 1, q = pwv & 1;
    float shl = q ? 1.f : -1.f;
    float slh = p ? 1.f : -1.f;
    float shh = (p == q) ? 1.f : -1.f;
    int hs = (h2 + SHIFTV) & 127; int wh = hs >> 3; int rr = hs & 7;
    int ws = (w2 + SHIFTV) & 127; int ww = ws >> 3; int cc = ws & 7;
    size_t wbase = ((size_t)(b*256 + wh*16 + ww)) * 12288 + rr*8 + cc;
    for (int i = ci; i < 64; i += 4){
        float llv = bf2f(rll[(((size_t)b*64 + i) << 14) + h2*128 + w2]);
        float hl = bf2f(high[wbase + (size_t)i*64]);
        float lh = bf2f(high[wbase + (size_t)(64 + i)*64]);
        float hh = bf2f(high[wbase + (size_t)(128 + i)*64]);
        float iw = 0.5f * (llv + shl*hl + slh*lh + shh*hh);
        float xv = x[xbase + (size_t)i*65536 + (size_t)ph*256 + pwv];
        xt[i][px] = xv;
        dbufT[px][i] = f2bf(iw - xv);
    }
    __syncthreads();
    int lane = tid & 63;
    int wv = tid >> 6;
    int lrow = lane & 15;
    int lkg  = lane >> 4;
    f32x4 acc[4];
    #pragma unroll
    for (int nt = 0; nt < 4; nt++) acc[nt] = (f32x4){0.f,0.f,0.f,0.f};
    #pragma unroll
    for (int kst = 0; kst < 2; kst++){
        bf16x8 a = *(const bf16x8*)&waob[(size_t)(wv*16 + lrow)*64 + kst*32 + lkg*8];
        #pragma unroll
        for (int nt = 0; nt < 4; nt++){
            bf16x8 bb = *(const bf16x8*)&dbufT[nt*16 + lrow][kst*32 + lkg*8];
            acc[nt] = __builtin_amdgcn_mfma_f32_16x16x32_bf16(a, bb, acc[nt], 0, 0, 0);
        }
    }
    #pragma unroll
    for (int nt = 0; nt < 4; nt++){
        #pragma unroll
        for (int r = 0; r < 4; r++){
            int o = wv*16 + lkg*4 + r;
            int pxx = nt*16 + lrow;
            y1b[(((size_t)(b*64 + o)) << 16) + (size_t)ph*256 + pw0 + pxx] =
                f2bf(xt[o][pxx] + acc[nt][r]);
        }
    }
}

// ---------------- FFN part A: LN + conv1x1(64->256) via MFMA, bf16 in/out
__global__ __launch_bounds__(256) void k_ffn_a(const unsigned short* __restrict__ y1b,
    const float* __restrict__ lnw, const float* __restrict__ lnb,
    const unsigned short* __restrict__ wib, unsigned short* __restrict__ h, int nb)
{
    __shared__ float yl[64][72];
    __shared__ __align__(16) unsigned short xn[64][72];
    __shared__ __align__(16) unsigned short ho[128][72];
    __shared__ float mu_s[64], rs_s[64];
    int tid = threadIdx.x;
    int lane = tid & 63;
    int wv = tid >> 6;
    int lrow = lane & 15;
    int lkg  = lane >> 4;
    int blk = blockIdx.x;
    int b   = blk >> 10;
    int row = (blk >> 2) & 255;
    int q   = blk & 3;

    for (int idx = tid; idx < 512; idx += 256){
        int c = idx >> 3, p8 = idx & 7;
        bf16x8 v = *(const bf16x8*)&y1b[((size_t)(b*64 + c) << 16) + (size_t)row*256 + q*64 + p8*8];
        #pragma unroll
        for (int j = 0; j < 8; j++) yl[c][p8*8 + j] = bf2f((unsigned short)v[j]);
    }
    __syncthreads();
    if (tid < 64){
        float s = 0.f, ss = 0.f;
        for (int c = 0; c < 64; c++){ float v = yl[c][tid]; s += v; ss += v*v; }
        float mu = s * (1.f/64.f), var = ss * (1.f/64.f) - mu*mu;
        mu_s[tid] = mu; rs_s[tid] = rsqrtf(var + 1e-6f);
    }
    __syncthreads();
    for (int idx = tid; idx < 4096; idx += 256){
        int px = idx & 63, c = idx >> 6;
        xn[px][c] = f2bf((yl[c][px] - mu_s[px]) * rs_s[px] * lnw[c] + lnb[c]);
    }
    __syncthreads();

    for (int hh = 0; hh < 2; hh++){
        int oc0 = hh*128;
        f32x4 acc[8];
        #pragma unroll
        for (int nt = 0; nt < 8; nt++) acc[nt] = (f32x4){0.f,0.f,0.f,0.f};
        #pragma unroll
        for (int kst = 0; kst < 2; kst++){
            bf16x8 a = *(const bf16x8*)&xn[wv*16 + lrow][kst*32 + lkg*8];
            #pragma unroll
            for (int nt = 0; nt < 8; nt++){
                bf16x8 bb = *(const bf16x8*)&wib[(size_t)(oc0 + nt*16 + lrow)*64 + kst*32 + lkg*8];
                acc[nt] = __builtin_amdgcn_mfma_f32_16x16x32_bf16(a, bb, acc[nt], 0, 0, 0);
            }
        }
        #pragma unroll
        for (int nt = 0; nt < 8; nt++)
            #pragma unroll
            for (int r = 0; r < 4; r++)
                ho[nt*16 + lrow][wv*16 + lkg*4 + r] = f2bf(acc[nt][r]);
        __syncthreads();
        for (int idx = tid; idx < 1024; idx += 256){
            int oc = idx >> 3, p8 = idx & 7;
            bf16x8 v = *(const bf16x8*)&ho[oc][p8*8];
            *(bf16x8*)&h[(size_t)(b*256 + oc0 + oc)*65536 + (size_t)row*256 + q*64 + p8*8] = v;
        }
        __syncthreads();
    }
}

// ---------------- FUSED FFN-B + spectral conv: dwconv(h) in LDS -> circulant MFMA + gelu*gate -> mbuf
#define PMS 68
__global__ __launch_bounds__(256) void k_convb(const unsigned short* __restrict__ h,
    const float* __restrict__ w_dw, const unsigned short* __restrict__ circ,
    unsigned short* __restrict__ mbuf, int nb)
{
    __shared__ __align__(16) unsigned short stage[4][10][272];
    __shared__ __align__(16) unsigned short pm[4][32*PMS];
    int tid = threadIdx.x;
    int lane = tid & 63;
    int wv = tid >> 6;
    int lrow = lane & 15;
    int lkg  = lane >> 4;
    int blk = blockIdx.x;
    int b   = blk >> 9;
    int chg = (blk >> 5) & 15;
    int pc  = blk & 31;
    int r0 = pc*8;

    auto stage_fn = [&](int c16){
        int chA = chg*8 + c16;
        int chs[4] = {chA, chA+128, chA+4, chA+132};
        for (int j = tid; j < 1280; j += 256){
            int pl = j / 320;
            int rem = j - pl*320;
            int row10 = rem >> 5;
            int c0 = (rem & 31) << 3;
            int gr = r0 + row10 - 1;
            bf16x8 v = (bf16x8){0,0,0,0,0,0,0,0};
            if (gr >= 0 && gr < 256)
                v = *(const bf16x8*)&h[((size_t)(b*256 + chs[pl]) << 16) + (size_t)gr*256 + c0];
            *(bf16x8*)&stage[pl][row10][c0] = v;
        }
    };

    stage_fn(0);
    __syncthreads();

    for (int c16 = 0; c16 < 4; c16++){
        {
            int chA = chg*8 + c16;
            int chs[4] = {chA, chA+128, chA+4, chA+132};
            for (int j = tid; j < 1024; j += 256){
                int pl = j >> 8;
                int rem = j & 255;
                int r = rem >> 5;
                int c0 = (rem & 31) << 3;
                const float* wd = w_dw + chs[pl]*9;
                float acc[8] = {0,0,0,0,0,0,0,0};
                #pragma unroll
                for (int dy = 0; dy < 3; dy++){
                    const unsigned short* rp = &stage[pl][r+dy][0];
                    bf16x8 v = *(const bf16x8*)&rp[c0];
                    float vf[8];
                    #pragma unroll
                    for (int jj = 0; jj < 8; jj++) vf[jj] = bf2f((unsigned short)v[jj]);
                    float l  = (c0 > 0)   ? bf2f(rp[c0 - 1]) : 0.f;
                    float rg = (c0 < 248) ? bf2f(rp[c0 + 8]) : 0.f;
                    float w0 = wd[dy*3+0], w1 = wd[dy*3+1], w2 = wd[dy*3+2];
                    acc[0] += w0*l + w1*vf[0] + w2*vf[1];
                    #pragma unroll
                    for (int jj = 1; jj < 7; jj++) acc[jj] += w0*vf[jj-1] + w1*vf[jj] + w2*vf[jj+1];
                    acc[7] += w0*vf[6] + w1*vf[7] + w2*rg;
                }
                bf16x8 o;
                #pragma unroll
                for (int jj = 0; jj < 8; jj++) o[jj] = (short)f2bf(acc[jj]);
                *(bf16x8*)&pm[pl][(c0 >> 3)*PMS + r*8] = o;
            }
        }
        __syncthreads();
        if (c16 < 3) stage_fn(c16 + 1);
        {
            int spl = (wv & 1) * 2;
            int ch = chg*8 + (wv & 1)*4 + c16;
            const unsigned short* Bb = circ + (size_t)ch*4096;
            int plocal = (wv >> 1)*16;
            f32x4 acc4[4];
            #pragma unroll
            for (int nt = 0; nt < 4; nt++) acc4[nt] = (f32x4){0.f,0.f,0.f,0.f};
            #pragma unroll
            for (int kst = 0; kst < 2; kst++){
                bf16x8 a = *(const bf16x8*)&pm[spl][(plocal + lrow)*PMS + kst*32 + lkg*8];
                #pragma unroll
                for (int nt = 0; nt < 4; nt++){
                    bf16x8 bb = *(const bf16x8*)&Bb[(size_t)(nt*16 + lrow)*64 + kst*32 + lkg*8];
                    acc4[nt] = __builtin_amdgcn_mfma_f32_16x16x32_bf16(a, bb, acc4[nt], 0, 0, 0);
                }
            }
            unsigned short* Mb = mbuf + ((size_t)(b*128 + ch) << 16);
            #pragma unroll
            for (int nt = 0; nt < 4; nt++){
                #pragma unroll
                for (int r = 0; r < 4; r++){
                    int pl2 = plocal + lkg*4 + r;
                    int px = nt*16 + lrow;
                    float g = bf2f(pm[spl + 1][pl2*PMS + px]);
                    Mb[(size_t)(pc*32 + pl2)*64 + px] = f2bf(gelu_f(acc4[nt][r]) * g);
                }
            }
        }
        __syncthreads();
    }
}

// ---------------- FFN out-projection via MFMA: out = y1 + m @ w_out.T
__global__ __launch_bounds__(256) void k_out(const unsigned short* __restrict__ y1b,
    const unsigned short* __restrict__ mbuf, const unsigned short* __restrict__ wob,
    float* __restrict__ out, int b0)
{
    __shared__ __align__(16) unsigned short mlds[2][64][136];
    int tid = threadIdx.x;
    int lane = tid & 63;
    int wv = tid >> 6;
    int lrow = lane & 15;
    int lkg  = lane >> 4;
    int blk = blockIdx.x;
    int b  = blk >> 9;
    int pp = blk & 511;

    for (int it = 0; it < 8; it++){
        int chunk = tid + it*256;
        int ch = chunk >> 4;
        int p = (chunk >> 3) & 1;
        int px8 = chunk & 7;
        bf16x8 v = *(const bf16x8*)&mbuf[(((size_t)(b*128 + ch)) << 16) + (size_t)(2*pp + p)*64 + px8*8];
        #pragma unroll
        for (int j = 0; j < 8; j++) mlds[p][px8*8 + j][ch] = (unsigned short)v[j];
    }
    __syncthreads();

    int p = wv >> 1;
    int ochalf = wv & 1;
    f32x4 acc[2][4];
    #pragma unroll
    for (int mt = 0; mt < 2; mt++)
        #pragma unroll
        for (int nt = 0; nt < 4; nt++) acc[mt][nt] = (f32x4){0.f,0.f,0.f,0.f};
    #pragma unroll
    for (int kst = 0; kst < 4; kst++){
        bf16x8 a0 = *(const bf16x8*)&wob[(size_t)(ochalf*32 + 0  + lrow)*128 + kst*32 + lkg*8];
        bf16x8 a1 = *(const bf16x8*)&wob[(size_t)(ochalf*32 + 16 + lrow)*128 + kst*32 + lkg*8];
        #pragma unroll
        for (int nt = 0; nt < 4; nt++){
            bf16x8 bb = *(const bf16x8*)&mlds[p][nt*16 + lrow][kst*32 + lkg*8];
            acc[0][nt] = __builtin_amdgcn_mfma_f32_16x16x32_bf16(a0, bb, acc[0][nt], 0, 0, 0);
            acc[1][nt] = __builtin_amdgcn_mfma_f32_16x16x32_bf16(a1, bb, acc[1][nt], 0, 0, 0);
        }
    }
    int patchIdx = 2*pp + p;
    int Rb = (patchIdx >> 5) * 8, Cb = (patchIdx & 31) * 8;
    #pragma unroll
    for (int mt = 0; mt < 2; mt++){
        #pragma unroll
        for (int nt = 0; nt < 4; nt++){
            #pragma unroll
            for (int r = 0; r < 4; r++){
                int oc = ochalf*32 + mt*16 + lkg*4 + r;
                int px = nt*16 + lrow;
                int R = Rb + (px >> 3), C = Cb + (px & 7);
                size_t li = (((size_t)(b*64 + oc)) << 16) + (size_t)R*256 + C;
                size_t go = (((size_t)((b0 + b)*64 + oc)) << 16) + (size_t)R*256 + C;
                out[go] = bf2f(y1b[li]) + acc[mt][nt][r];
            }
        }
    }
}

extern "C" void kernel_launch(void* const* d_in, const int* in_sizes, int n_in,
                              void* d_out, int out_size, void* d_ws, size_t ws_size,
                              hipStream_t stream){
    const float* x        = (const float*)d_in[0];
    const float* ln_w     = (const float*)d_in[1];
    const float* ln_b     = (const float*)d_in[2];
    const float* lnh_w    = (const float*)d_in[3];
    const float* lnh_b    = (const float*)d_in[4];
    const float* w_qkv    = (const float*)d_in[5];
    const float* b_qkv    = (const float*)d_in[6];
    const float* w_proj   = (const float*)d_in[7];
    const float* b_proj   = (const float*)d_in[8];
    const float* rel_tab  = (const float*)d_in[9];
    const float* g_main   = (const float*)d_in[10];
    const float* g_aux    = (const float*)d_in[11];
    const float* g_cross  = (const float*)d_in[12];
    const float* aux_dw   = (const float*)d_in[13];
    const float* aux_pw   = (const float*)d_in[14];
    const float* cg_w1    = (const float*)d_in[15];
    const float* cg_w2    = (const float*)d_in[16];
    const float* attn_ow  = (const float*)d_in[17];
    const float* ffn_in_w = (const float*)d_in[18];
    const float* ffn_dw   = (const float*)d_in[19];
    const float* ffn_ow   = (const float*)d_in[20];
    const float* wb_re    = (const float*)d_in[21];
    const float* wb_im    = (const float*)d_in[22];
    const int*   rel_idx  = (const int*)d_in[23];
    float* out = (float*)d_out;
    (void)in_sizes; (void)n_in; (void)out_size;

    const size_t MBsz = (size_t)1 << 20;
    auto need = [&](int nb)->size_t { return (size_t)nb*72*MBsz + 2*MBsz; };
    int nbmax = 4;
    while (nbmax > 1 && need(nbmax) > ws_size) nbmax >>= 1;

    for (int b0 = 0; b0 < 4; b0 += nbmax){
        int nb = nbmax;
        char* p = (char*)d_ws;
        char* U = p;                      p += (size_t)nb*72*MBsz;
        float* gap  = (float*)p;          p += 4096;
        float* gate = (float*)p;          p += 4096;
        unsigned short* wqb = (unsigned short*)p; p += 576*192*2;
        unsigned short* wpb = (unsigned short*)p; p += 192*192*2;
        float* bias6 = (float*)p;         p += 6*64*64*4;
        unsigned short* circ = (unsigned short*)p; p += 128*4096*2;
        unsigned short* wob  = (unsigned short*)p; p += 64*128*2;
        unsigned short* wib  = (unsigned short*)p; p += 256*64*2;
        unsigned short* waob = (unsigned short*)p; p += 64*64*2;
        unsigned short* pwab = (unsigned short*)p; p += 64*64*2;

        // phase-1 overlays in U[0, nb*10MB) (inside mbuf's future [0, nb*16MB))
        unsigned short* ll   = (unsigned short*)U;                          // nb*2MB
        unsigned short* highb= (unsigned short*)(U + (size_t)nb*2*MBsz);    // nb*6MB
        unsigned short* rll  = (unsigned short*)(U + (size_t)nb*8*MBsz);    // nb*2MB
        // phase-2
        unsigned short* mbuf = (unsigned short*)U;                          // nb*16MB
        unsigned short* h    = (unsigned short*)(U + (size_t)nb*32*MBsz);   // nb*32MB
        unsigned short* y1b  = (unsigned short*)(U + (size_t)nb*64*MBsz);   // nb*8MB

        k_kcirc<<<128, 256, 0, stream>>>(wb_re, wb_im, circ);
        k_cvt<<<432, 256, 0, stream>>>(w_qkv, w_proj, rel_tab, rel_idx, ffn_ow, ffn_in_w,
                                       attn_ow, aux_pw,
                                       wqb, wpb, bias6, wob, wib, waob, pwab, gap);
        k_dwt<<<nb*2048, 256, 0, stream>>>(x, ll, highb, gap, nb, b0);
        k_gate<<<nb, 256, 0, stream>>>(gap, cg_w1, cg_w2, gate);
        k_attn<<<nb*256, 256, 0, stream>>>(highb, wqb, wpb, b_qkv, b_proj, bias6,
                                           lnh_w, lnh_b, gate, g_main, g_cross);
        k_aux<<<nb*256, 256, 0, stream>>>(ll, aux_dw, pwab, g_aux, rll, nb);
        k_iwt_proj<<<nb*1024, 256, 0, stream>>>(rll, highb, x, waob, y1b, nb, b0);
        k_ffn_a<<<nb*1024, 256, 0, stream>>>(y1b, ln_w, ln_b, wib, h, nb);
        k_convb<<<nb*512, 256, 0, stream>>>(h, ffn_dw, circ, mbuf, nb);
        k_out<<<nb*512, 256, 0, stream>>>(y1b, mbuf, wob, out, b0);
    }
}

// Round 15
// 495.783 us; speedup vs baseline: 1.7148x; 1.0447x over previous
//
#include <hip/hip_runtime.h>
#include <hip/hip_bf16.h>
#include <math.h>

#define DIMC 64
#define C3 192
#define NHEADS 6
#define DH 32
#define WSZ 8
#define SHIFTV 4
#define HIDC 128
#define FULLR 256
#define HALFR 128

typedef __attribute__((ext_vector_type(8))) short bf16x8;
typedef __attribute__((ext_vector_type(4))) float f32x4;

__device__ __forceinline__ float gelu_f(float x){
    return 0.5f * x * (1.0f + erff(x * 0.70710678118654752440f));
}
__device__ __forceinline__ unsigned short f2bf(float f){
    union { float f; unsigned u; } v; v.f = f;
    unsigned r = (v.u + 0x7FFF + ((v.u >> 16) & 1)) >> 16;
    return (unsigned short)r;
}
__device__ __forceinline__ float bf2f(unsigned short h){
    union { unsigned u; float f; } v; v.u = ((unsigned)h) << 16;
    return v.f;
}

// ---------------- DWT: ll bf16 (plane), high bf16 (window-token-major), + fused gap partial sums
__global__ __launch_bounds__(256) void k_dwt(const float* __restrict__ x, unsigned short* __restrict__ ll,
                                             unsigned short* __restrict__ high, float* __restrict__ gap,
                                             int nb, int b0){
    __shared__ float red[256];
    int idx = blockIdx.x * 256 + threadIdx.x;
    int total = nb << 19;
    if (idx >= total) return;
    int w4 = idx & 63;
    int h  = (idx >> 6) & 127;
    int c  = (idx >> 13) & 63;
    int b  = idx >> 19;
    const float* xp = x + (((size_t)(b0 + b) * DIMC + c) * FULLR + 2*h) * FULLR + 4*w4;
    float4 r0 = *(const float4*)xp;
    float4 r1 = *(const float4*)(xp + FULLR);
    size_t lbase = (((size_t)b*64 + c) << 14) + h*128 + w4*2;
    float x1a = 0.5f*r0.x, x3a = 0.5f*r0.y, x2a = 0.5f*r1.x, x4a = 0.5f*r1.y;
    float x1b = 0.5f*r0.z, x3b = 0.5f*r0.w, x2b = 0.5f*r1.z, x4b = 0.5f*r1.w;
    float lva = x1a + x2a + x3a + x4a;
    float lvb = x1b + x2b + x3b + x4b;
    *(unsigned*)&ll[lbase] = (unsigned)f2bf(lva) | ((unsigned)f2bf(lvb) << 16);
    int hs = (h + SHIFTV) & 127;  int wh = hs >> 3; int rr = hs & 7;
    int ws = (2*w4 + SHIFTV) & 127; int ww = ws >> 3; int cc = ws & 7;
    size_t wbase = ((size_t)(b*256 + wh*16 + ww)) * 12288 + rr*8 + cc;
    unsigned u;
    u = (unsigned)f2bf(-x1a - x2a + x3a + x4a) | ((unsigned)f2bf(-x1b - x2b + x3b + x4b) << 16);
    *(unsigned*)&high[wbase + (size_t)c*64] = u;
    u = (unsigned)f2bf(-x1a + x2a - x3a + x4a) | ((unsigned)f2bf(-x1b + x2b - x3b + x4b) << 16);
    *(unsigned*)&high[wbase + (size_t)(64 + c)*64] = u;
    u = (unsigned)f2bf( x1a - x2a - x3a + x4a) | ((unsigned)f2bf( x1b - x2b - x3b + x4b) << 16);
    *(unsigned*)&high[wbase + (size_t)(128 + c)*64] = u;
    red[threadIdx.x] = lva + lvb;
    __syncthreads();
    for (int st = 128; st > 0; st >>= 1){
        if (threadIdx.x < st) red[threadIdx.x] += red[threadIdx.x + st];
        __syncthreads();
    }
    if (threadIdx.x == 0) atomicAdd(&gap[b*64 + c], red[0]);
}

// ---------------- gate MLP (gap holds SUM; fold 1/16384)
__global__ __launch_bounds__(256) void k_gate(const float* __restrict__ gap, const float* __restrict__ w1,
                                              const float* __restrict__ w2, float* __restrict__ gate){
    int b = blockIdx.x;
    __shared__ float hid[48];
    __shared__ float g[64];
    if (threadIdx.x < 64) g[threadIdx.x] = gap[b*64 + threadIdx.x] * (1.0f/16384.0f);
    __syncthreads();
    if (threadIdx.x < 48){
        float s = 0.f;
        for (int c = 0; c < 64; c++) s += g[c] * w1[threadIdx.x*64 + c];
        hid[threadIdx.x] = gelu_f(s);
    }
    __syncthreads();
    if (threadIdx.x < C3){
        float s = 0.f;
        for (int j = 0; j < 48; j++) s += hid[j] * w2[threadIdx.x*48 + j];
        gate[b*C3 + threadIdx.x] = 1.0f / (1.0f + expf(-s));
    }
}

// ---------------- weights -> bf16, rel bias table, gap zero
__global__ __launch_bounds__(256) void k_cvt(const float* __restrict__ wq, const float* __restrict__ wp,
    const float* __restrict__ rel_table, const int* __restrict__ rel_idx, const float* __restrict__ wo,
    const float* __restrict__ wi, const float* __restrict__ wao, const float* __restrict__ pwa,
    unsigned short* __restrict__ wqb, unsigned short* __restrict__ wpb, float* __restrict__ bias6,
    unsigned short* __restrict__ wob, unsigned short* __restrict__ wib,
    unsigned short* __restrict__ waob, unsigned short* __restrict__ pwab, float* __restrict__ gap){
    int idx = blockIdx.x*256 + threadIdx.x;
    if (idx < 576*192) wqb[idx] = f2bf(wq[idx]);
    if (idx < 192*192) wpb[idx] = f2bf(wp[idx]);
    if (idx < 64*128)  wob[idx] = f2bf(wo[idx]);
    if (idx < 256*64)  wib[idx] = f2bf(wi[idx]);
    if (idx < 64*64){  waob[idx] = f2bf(wao[idx]); pwab[idx] = f2bf(pwa[idx]); }
    if (idx < 256)     gap[idx] = 0.f;
    if (idx < 6*64*64){
        int h = idx >> 12; int ij = idx & 4095;
        bias6[idx] = rel_table[rel_idx[ij]*NHEADS + h];
    }
}

// ---------------- merged spectral kernel + circulant (bf16): one block per channel
__global__ __launch_bounds__(256) void k_kcirc(const float* __restrict__ wr, const float* __restrict__ wi,
                                               unsigned short* __restrict__ circ){
    __shared__ float ksl[64];
    int ch = blockIdx.x;
    int tid = threadIdx.x;
    if (tid < 64){
        int r = tid >> 3, c = tid & 7;
        float s = 0.f;
        for (int u = 0; u < 8; u++){
            for (int v = 0; v < 8; v++){
                float re, im;
                if (v <= 4){ re = wr[ch*40 + u*5 + v]; im = wi[ch*40 + u*5 + v]; }
                else { int u2 = (8-u)&7; int v2 = 8-v; re = wr[ch*40 + u2*5 + v2]; im = -wi[ch*40 + u2*5 + v2]; }
                float ang = (float)(u*r + v*c) * 0.78539816339744831f;
                float cs, sn; __sincosf(ang, &sn, &cs);
                s += re * cs - im * sn;
            }
        }
        ksl[tid] = s * (1.0f/64.0f);
    }
    __syncthreads();
    for (int idx = tid; idx < 4096; idx += 256){
        int o = idx >> 6, i = idx & 63;
        int dr = ((o >> 3) - (i >> 3)) & 7;
        int dc = ((o & 7) - (i & 7)) & 7;
        circ[(size_t)ch*4096 + idx] = f2bf(ksl[dr*8 + dc]);
    }
}

// ---------------- fused shifted-window MHSA via MFMA, in-place on window-major high
__global__ __launch_bounds__(256, 3) void k_attn(unsigned short* __restrict__ high,
    const unsigned short* __restrict__ wqb, const unsigned short* __restrict__ wpb,
    const float* __restrict__ bqkv, const float* __restrict__ bproj,
    const float* __restrict__ bias6, const float* __restrict__ lnw, const float* __restrict__ lnb,
    const float* __restrict__ gate, const float* __restrict__ gm_p, const float* __restrict__ gc_p)
{
    __shared__ __align__(16) unsigned short xb[64][200];
    __shared__ __align__(16) unsigned short qs[64][40];
    __shared__ __align__(16) unsigned short ks2[64][40];
    __shared__ __align__(16) unsigned short vt[32][72];
    __shared__ __align__(16) unsigned short ps[64][72];
    __shared__ float st_s[4][64], st_ss[4][64];
    __shared__ float mu_s[64], rs_s[64];

    int tid = threadIdx.x;
    int lane = tid & 63;
    int wv = tid >> 6;
    int lrow = lane & 15;
    int lkg  = lane >> 4;
    int blk = blockIdx.x;
    int b  = blk >> 8;
    size_t wbase = (size_t)blk * 12288;
    const float scale = 0.17677669529663687f;
    float gm = gm_p[0], gc = gc_p[0];

    int t = lane, part = wv;
    float vals[48];
    {
        float s = 0.f, ss = 0.f;
        #pragma unroll
        for (int i = 0; i < 48; i++){
            float v = bf2f(high[wbase + (size_t)(part*48 + i)*64 + t]);
            vals[i] = v; s += v; ss += v*v;
        }
        st_s[part][t] = s; st_ss[part][t] = ss;
    }
    __syncthreads();
    if (tid < 64){
        float s = st_s[0][tid]+st_s[1][tid]+st_s[2][tid]+st_s[3][tid];
        float ss = st_ss[0][tid]+st_ss[1][tid]+st_ss[2][tid]+st_ss[3][tid];
        float mu = s*(1.f/C3);
        float var = ss*(1.f/C3) - mu*mu;
        mu_s[tid] = mu; rs_s[tid] = rsqrtf(var + 1e-6f);
    }
    __syncthreads();
    {
        float mu = mu_s[t], rs = rs_s[t];
        #pragma unroll
        for (int i8 = 0; i8 < 6; i8++){
            bf16x8 pk;
            #pragma unroll
            for (int jj = 0; jj < 8; jj++){
                int c = part*48 + i8*8 + jj;
                float nv = (vals[i8*8+jj] - mu) * rs * lnw[c] + lnb[c];
                pk[jj] = (short)f2bf(nv);
            }
            *(bf16x8*)&xb[t][part*48 + i8*8] = pk;
        }
    }
    __syncthreads();

    f32x4 pacc[3][4];
    #pragma unroll
    for (int mt3 = 0; mt3 < 3; mt3++)
        #pragma unroll
        for (int nt = 0; nt < 4; nt++) pacc[mt3][nt] = (f32x4){0.f,0.f,0.f,0.f};

    for (int h = 0; h < NHEADS; h++){
        f32x4 acc[6];
        #pragma unroll
        for (int nt = 0; nt < 6; nt++) acc[nt] = (f32x4){0.f,0.f,0.f,0.f};
        __builtin_amdgcn_s_setprio(1);
        for (int ksU = 0; ksU < 6; ksU++){
            int c0 = ksU*32 + lkg*8;
            bf16x8 a = *(const bf16x8*)&xb[wv*16 + lrow][c0];
            #pragma unroll
            for (int nt = 0; nt < 6; nt++){
                int which = nt >> 1;
                int gr = which*C3 + h*32 + (nt&1)*16 + lrow;
                bf16x8 bb = *(const bf16x8*)&wqb[(size_t)gr*C3 + c0];
                acc[nt] = __builtin_amdgcn_mfma_f32_16x16x32_bf16(a, bb, acc[nt], 0, 0, 0);
            }
        }
        __builtin_amdgcn_s_setprio(0);
        #pragma unroll
        for (int nt = 0; nt < 6; nt++){
            int which = nt >> 1;
            int d = (nt&1)*16 + lrow;
            float bias = bqkv[which*C3 + h*32 + d];
            #pragma unroll
            for (int r = 0; r < 4; r++){
                int row = wv*16 + lkg*4 + r;
                float v = acc[nt][r] + bias;
                if (which == 0)      qs[row][d]  = f2bf(v * scale);
                else if (which == 1) ks2[row][d] = f2bf(v);
                else                 vt[d][row]  = f2bf(v);
            }
        }
        __syncthreads();

        f32x4 sacc[4];
        {
            bf16x8 a = *(const bf16x8*)&qs[wv*16 + lrow][lkg*8];
            #pragma unroll
            for (int nt = 0; nt < 4; nt++){
                bf16x8 bb = *(const bf16x8*)&ks2[nt*16 + lrow][lkg*8];
                f32x4 z = (f32x4){0.f,0.f,0.f,0.f};
                sacc[nt] = __builtin_amdgcn_mfma_f32_16x16x32_bf16(a, bb, z, 0, 0, 0);
            }
        }
        {
            #pragma unroll
            for (int r = 0; r < 4; r++){
                int i = wv*16 + lkg*4 + r;
                float pv[4];
                float s = 0.f;
                #pragma unroll
                for (int nt = 0; nt < 4; nt++){
                    pv[nt] = __expf(sacc[nt][r] + bias6[h*4096 + i*64 + nt*16 + lrow]);
                    s += pv[nt];
                }
                s += __shfl_xor(s, 1); s += __shfl_xor(s, 2);
                s += __shfl_xor(s, 4); s += __shfl_xor(s, 8);
                float inv = 1.0f / s;
                #pragma unroll
                for (int nt = 0; nt < 4; nt++) ps[i][nt*16 + lrow] = f2bf(pv[nt] * inv);
            }
        }
        __syncthreads();

        f32x4 oacc[2];
        #pragma unroll
        for (int nt = 0; nt < 2; nt++) oacc[nt] = (f32x4){0.f,0.f,0.f,0.f};
        #pragma unroll
        for (int kst = 0; kst < 2; kst++){
            bf16x8 a = *(const bf16x8*)&ps[wv*16 + lrow][kst*32 + lkg*8];
            #pragma unroll
            for (int nt = 0; nt < 2; nt++){
                bf16x8 bb = *(const bf16x8*)&vt[nt*16 + lrow][kst*32 + lkg*8];
                oacc[nt] = __builtin_amdgcn_mfma_f32_16x16x32_bf16(a, bb, oacc[nt], 0, 0, 0);
            }
        }
        #pragma unroll
        for (int nt = 0; nt < 2; nt++)
            #pragma unroll
            for (int r = 0; r < 4; r++)
                qs[wv*16 + lkg*4 + r][nt*16 + lrow] = f2bf(oacc[nt][r]);
        __syncthreads();

        __builtin_amdgcn_s_setprio(1);
        #pragma unroll
        for (int mt3 = 0; mt3 < 3; mt3++){
            int o = wv*48 + mt3*16 + lrow;
            bf16x8 a = *(const bf16x8*)&wpb[(size_t)o*C3 + h*32 + lkg*8];
            #pragma unroll
            for (int nt = 0; nt < 4; nt++){
                bf16x8 bb = *(const bf16x8*)&qs[nt*16 + lrow][lkg*8];
                pacc[mt3][nt] = __builtin_amdgcn_mfma_f32_16x16x32_bf16(a, bb, pacc[mt3][nt], 0, 0, 0);
            }
        }
        __builtin_amdgcn_s_setprio(0);
        __syncthreads();
    }

    #pragma unroll
    for (int mt3 = 0; mt3 < 3; mt3++){
        #pragma unroll
        for (int r = 0; r < 4; r++){
            int o = wv*48 + mt3*16 + lkg*4 + r;
            float bias = bproj[o];
            float gf = 1.0f + gc * (gate[b*C3 + o] - 0.5f) * 2.0f;
            #pragma unroll
            for (int nt = 0; nt < 4; nt++){
                int token = nt*16 + lrow;
                size_t gi = wbase + (size_t)o*64 + token;
                float orig = bf2f(high[gi]);
                high[gi] = f2bf((orig + gm*(pacc[mt3][nt][r] + bias)) * gf);
            }
        }
    }
}

// ---------------- FUSED aux path: dwconv3x3 + gelu + pointwise (MFMA), rll = ll + ga*(...), bf16
__global__ __launch_bounds__(256) void k_aux(const unsigned short* __restrict__ ll,
    const float* __restrict__ dw, const unsigned short* __restrict__ pwab, const float* __restrict__ ga_p,
    unsigned short* __restrict__ rll, int nb)
{
    __shared__ __align__(16) unsigned short sll[64][3][80];
    __shared__ __align__(16) unsigned short tlb[64][72];
    int tid = threadIdx.x;
    int blk = blockIdx.x;
    int b   = blk >> 8;
    int row = (blk >> 1) & 127;
    int seg = blk & 1;
    int px0 = seg*64;

    for (int j = tid; j < 1920; j += 256){
        int c = j / 30;
        int rem = j % 30;
        int dy = rem / 10;
        int i8 = rem % 10;
        int gr = row + dy - 1;
        int gp = px0 - 8 + i8*8;
        bf16x8 v = (bf16x8){0,0,0,0,0,0,0,0};
        if (gr >= 0 && gr < 128 && gp >= 0 && gp < 128)
            v = *(const bf16x8*)&ll[(((size_t)b*64 + c) << 14) + gr*128 + gp];
        *(bf16x8*)&sll[c][dy][i8*8] = v;
    }
    __syncthreads();

    int px = tid & 63, cq = tid >> 6;
    for (int ci = cq; ci < 64; ci += 4){
        const float* wd = dw + ci*9;
        float s = 0.f;
        #pragma unroll
        for (int dy = 0; dy < 3; dy++){
            float a0 = bf2f(sll[ci][dy][px+7]);
            float a1 = bf2f(sll[ci][dy][px+8]);
            float a2 = bf2f(sll[ci][dy][px+9]);
            s += wd[dy*3+0]*a0 + wd[dy*3+1]*a1 + wd[dy*3+2]*a2;
        }
        tlb[px][ci] = f2bf(gelu_f(s));
    }
    __syncthreads();

    int lane = tid & 63;
    int wv = tid >> 6;
    int lrow = lane & 15;
    int lkg  = lane >> 4;
    float ga = ga_p[0];
    f32x4 acc[4];
    #pragma unroll
    for (int nt = 0; nt < 4; nt++) acc[nt] = (f32x4){0.f,0.f,0.f,0.f};
    __builtin_amdgcn_s_setprio(1);
    #pragma unroll
    for (int kst = 0; kst < 2; kst++){
        bf16x8 a = *(const bf16x8*)&pwab[(size_t)(wv*16 + lrow)*64 + kst*32 + lkg*8];
        #pragma unroll
        for (int nt = 0; nt < 4; nt++){
            bf16x8 bb = *(const bf16x8*)&tlb[nt*16 + lrow][kst*32 + lkg*8];
            acc[nt] = __builtin_amdgcn_mfma_f32_16x16x32_bf16(a, bb, acc[nt], 0, 0, 0);
        }
    }
    __builtin_amdgcn_s_setprio(0);
    #pragma unroll
    for (int nt = 0; nt < 4; nt++){
        #pragma unroll
        for (int r = 0; r < 4; r++){
            int o = wv*16 + lkg*4 + r;
            int pxx = nt*16 + lrow;
            float base = bf2f(sll[o][1][pxx + 8]);
            rll[(((size_t)b*64 + o) << 14) + row*128 + px0 + pxx] = f2bf(base + ga * acc[nt][r]);
        }
    }
}

// ---------------- FUSED IWT + proj + residual -> y1b, then LN + conv1x1(64->256) -> h (all MFMA)
__global__ __launch_bounds__(256) void k_iwt_ffn(const unsigned short* __restrict__ rll,
    const unsigned short* __restrict__ high, const float* __restrict__ x,
    const unsigned short* __restrict__ waob,
    const float* __restrict__ lnw, const float* __restrict__ lnb,
    const unsigned short* __restrict__ wib,
    unsigned short* __restrict__ y1b, unsigned short* __restrict__ h, int nb, int b0)
{
    __shared__ __align__(16) char smem[38912];
    float* xt            = (float*)smem;                       // [64][65] (phase 1-2), 16640 B of 18432
    unsigned short* ho   = (unsigned short*)smem;              // [128][72] (phase 4, overlays xt)
    unsigned short* dbufT= (unsigned short*)(smem + 18432);    // [64][72]
    unsigned short* xn   = (unsigned short*)(smem + 27648);    // [64][72]
    float* pss           = (float*)(smem + 36864);             // [4][64]
    float* psss          = (float*)(smem + 37888);             // [4][64]

    int tid = threadIdx.x;
    int blk = blockIdx.x;
    int seg = blk & 3;
    int ph  = (blk >> 2) & 255;
    int b   = blk >> 10;
    int pw0 = seg * 64;
    int h2 = ph >> 1, p = ph & 1;
    size_t xbase = ((size_t)(b0 + b) * DIMC) * 65536;
    int px = tid & 63;
    int ci = tid >> 6;
    int pwv = pw0 + px;
    int w2 = pwv >> 1, q = pwv & 1;
    float shl = q ? 1.f : -1.f;
    float slh = p ? 1.f : -1.f;
    float shh = (p == q) ? 1.f : -1.f;
    int hs = (h2 + SHIFTV) & 127; int wh = hs >> 3; int rr = hs & 7;
    int ws = (w2 + SHIFTV) & 127; int ww = ws >> 3; int cc = ws & 7;
    size_t wbase = ((size_t)(b*256 + wh*16 + ww)) * 12288 + rr*8 + cc;
    // phase 1: gather
    for (int i = ci; i < 64; i += 4){
        float llv = bf2f(rll[(((size_t)b*64 + i) << 14) + h2*128 + w2]);
        float hl = bf2f(high[wbase + (size_t)i*64]);
        float lh = bf2f(high[wbase + (size_t)(64 + i)*64]);
        float hh = bf2f(high[wbase + (size_t)(128 + i)*64]);
        float iw = 0.5f * (llv + shl*hl + slh*lh + shh*hh);
        float xv = x[xbase + (size_t)i*65536 + (size_t)ph*256 + pwv];
        xt[i*65 + px] = xv;
        dbufT[px*72 + i] = f2bf(iw - xv);
    }
    __syncthreads();

    int lane = tid & 63;
    int wv = tid >> 6;
    int lrow = lane & 15;
    int lkg  = lane >> 4;
    // phase 2: proj MFMA + y1b write + LN partial stats
    f32x4 acc[4];
    #pragma unroll
    for (int nt = 0; nt < 4; nt++) acc[nt] = (f32x4){0.f,0.f,0.f,0.f};
    __builtin_amdgcn_s_setprio(1);
    #pragma unroll
    for (int kst = 0; kst < 2; kst++){
        bf16x8 a = *(const bf16x8*)&waob[(size_t)(wv*16 + lrow)*64 + kst*32 + lkg*8];
        #pragma unroll
        for (int nt = 0; nt < 4; nt++){
            bf16x8 bb = *(const bf16x8*)&dbufT[(nt*16 + lrow)*72 + kst*32 + lkg*8];
            acc[nt] = __builtin_amdgcn_mfma_f32_16x16x32_bf16(a, bb, acc[nt], 0, 0, 0);
        }
    }
    __builtin_amdgcn_s_setprio(0);
    float yv[4][4];
    float s4[4], ss4[4];
    #pragma unroll
    for (int nt = 0; nt < 4; nt++){ s4[nt] = 0.f; ss4[nt] = 0.f; }
    #pragma unroll
    for (int nt = 0; nt < 4; nt++){
        int pxx = nt*16 + lrow;
        #pragma unroll
        for (int r = 0; r < 4; r++){
            int o = wv*16 + lkg*4 + r;
            float v = xt[o*65 + pxx] + acc[nt][r];
            yv[nt][r] = v;
            s4[nt] += v; ss4[nt] += v*v;
            y1b[(((size_t)(b*64 + o)) << 16) + (size_t)ph*256 + pw0 + pxx] = f2bf(v);
        }
    }
    #pragma unroll
    for (int nt = 0; nt < 4; nt++){
        s4[nt]  += __shfl_xor(s4[nt], 16);  s4[nt]  += __shfl_xor(s4[nt], 32);
        ss4[nt] += __shfl_xor(ss4[nt], 16); ss4[nt] += __shfl_xor(ss4[nt], 32);
    }
    if (lkg == 0){
        #pragma unroll
        for (int nt = 0; nt < 4; nt++){
            pss[wv*64 + nt*16 + lrow]  = s4[nt];
            psss[wv*64 + nt*16 + lrow] = ss4[nt];
        }
    }
    __syncthreads();
    // phase 3: LN + write xn[px][c]
    #pragma unroll
    for (int nt = 0; nt < 4; nt++){
        int pxx = nt*16 + lrow;
        float s  = pss[pxx]  + pss[64 + pxx]  + pss[128 + pxx]  + pss[192 + pxx];
        float ss = psss[pxx] + psss[64 + pxx] + psss[128 + pxx] + psss[192 + pxx];
        float mu = s * (1.f/64.f);
        float var = ss * (1.f/64.f) - mu*mu;
        float rs = rsqrtf(var + 1e-6f);
        #pragma unroll
        for (int r = 0; r < 4; r++){
            int o = wv*16 + lkg*4 + r;
            xn[pxx*72 + o] = f2bf((yv[nt][r] - mu) * rs * lnw[o] + lnb[o]);
        }
    }
    __syncthreads();
    // phase 4: conv1x1 64->256 MFMA -> ho -> h
    for (int hh = 0; hh < 2; hh++){
        int oc0 = hh*128;
        f32x4 cacc[8];
        #pragma unroll
        for (int nt = 0; nt < 8; nt++) cacc[nt] = (f32x4){0.f,0.f,0.f,0.f};
        __builtin_amdgcn_s_setprio(1);
        #pragma unroll
        for (int kst = 0; kst < 2; kst++){
            bf16x8 a = *(const bf16x8*)&xn[(wv*16 + lrow)*72 + kst*32 + lkg*8];
            #pragma unroll
            for (int nt = 0; nt < 8; nt++){
                bf16x8 bb = *(const bf16x8*)&wib[(size_t)(oc0 + nt*16 + lrow)*64 + kst*32 + lkg*8];
                cacc[nt] = __builtin_amdgcn_mfma_f32_16x16x32_bf16(a, bb, cacc[nt], 0, 0, 0);
            }
        }
        __builtin_amdgcn_s_setprio(0);
        #pragma unroll
        for (int nt = 0; nt < 8; nt++)
            #pragma unroll
            for (int r = 0; r < 4; r++)
                ho[(nt*16 + lrow)*72 + wv*16 + lkg*4 + r] = f2bf(cacc[nt][r]);
        __syncthreads();
        for (int idx = tid; idx < 1024; idx += 256){
            int oc = idx >> 3, p8 = idx & 7;
            bf16x8 v = *(const bf16x8*)&ho[oc*72 + p8*8];
            *(bf16x8*)&h[(size_t)(b*256 + oc0 + oc)*65536 + (size_t)ph*256 + pw0 + p8*8] = v;
        }
        __syncthreads();
    }
}

// ---------------- FUSED FFN-B + spectral conv: dwconv(h) in LDS -> circulant MFMA + gelu*gate -> mbuf
#define PMS 68
__global__ __launch_bounds__(256) void k_convb(const unsigned short* __restrict__ h,
    const float* __restrict__ w_dw, const unsigned short* __restrict__ circ,
    unsigned short* __restrict__ mbuf, int nb)
{
    __shared__ __align__(16) unsigned short stage[4][10][272];
    __shared__ __align__(16) unsigned short pm[4][32*PMS];
    int tid = threadIdx.x;
    int lane = tid & 63;
    int wv = tid >> 6;
    int lrow = lane & 15;
    int lkg  = lane >> 4;
    int blk = blockIdx.x;
    int b   = blk >> 9;
    int chg = (blk >> 5) & 15;
    int pc  = blk & 31;
    int r0 = pc*8;

    auto stage_fn = [&](int c16){
        int chA = chg*8 + c16;
        int chs[4] = {chA, chA+128, chA+4, chA+132};
        for (int j = tid; j < 1280; j += 256){
            int pl = j / 320;
            int rem = j - pl*320;
            int row10 = rem >> 5;
            int c0 = (rem & 31) << 3;
            int gr = r0 + row10 - 1;
            bf16x8 v = (bf16x8){0,0,0,0,0,0,0,0};
            if (gr >= 0 && gr < 256)
                v = *(const bf16x8*)&h[((size_t)(b*256 + chs[pl]) << 16) + (size_t)gr*256 + c0];
            *(bf16x8*)&stage[pl][row10][c0] = v;
        }
    };

    stage_fn(0);
    __syncthreads();

    for (int c16 = 0; c16 < 4; c16++){
        {
            int chA = chg*8 + c16;
            int chs[4] = {chA, chA+128, chA+4, chA+132};
            for (int j = tid; j < 1024; j += 256){
                int pl = j >> 8;
                int rem = j & 255;
                int r = rem >> 5;
                int c0 = (rem & 31) << 3;
                const float* wd = w_dw + chs[pl]*9;
                float acc[8] = {0,0,0,0,0,0,0,0};
                #pragma unroll
                for (int dy = 0; dy < 3; dy++){
                    const unsigned short* rp = &stage[pl][r+dy][0];
                    bf16x8 v = *(const bf16x8*)&rp[c0];
                    float vf[8];
                    #pragma unroll
                    for (int jj = 0; jj < 8; jj++) vf[jj] = bf2f((unsigned short)v[jj]);
                    float l  = (c0 > 0)   ? bf2f(rp[c0 - 1]) : 0.f;
                    float rg = (c0 < 248) ? bf2f(rp[c0 + 8]) : 0.f;
                    float w0 = wd[dy*3+0], w1 = wd[dy*3+1], w2 = wd[dy*3+2];
                    acc[0] += w0*l + w1*vf[0] + w2*vf[1];
                    #pragma unroll
                    for (int jj = 1; jj < 7; jj++) acc[jj] += w0*vf[jj-1] + w1*vf[jj] + w2*vf[jj+1];
                    acc[7] += w0*vf[6] + w1*vf[7] + w2*rg;
                }
                bf16x8 o;
                #pragma unroll
                for (int jj = 0; jj < 8; jj++) o[jj] = (short)f2bf(acc[jj]);
                *(bf16x8*)&pm[pl][(c0 >> 3)*PMS + r*8] = o;
            }
        }
        __syncthreads();
        if (c16 < 3) stage_fn(c16 + 1);
        {
            int spl = (wv & 1) * 2;
            int ch = chg*8 + (wv & 1)*4 + c16;
            const unsigned short* Bb = circ + (size_t)ch*4096;
            int plocal = (wv >> 1)*16;
            f32x4 acc4[4];
            #pragma unroll
            for (int nt = 0; nt < 4; nt++) acc4[nt] = (f32x4){0.f,0.f,0.f,0.f};
            __builtin_amdgcn_s_setprio(1);
            #pragma unroll
            for (int kst = 0; kst < 2; kst++){
                bf16x8 a = *(const bf16x8*)&pm[spl][(plocal + lrow)*PMS + kst*32 + lkg*8];
                #pragma unroll
                for (int nt = 0; nt < 4; nt++){
                    bf16x8 bb = *(const bf16x8*)&Bb[(size_t)(nt*16 + lrow)*64 + kst*32 + lkg*8];
                    acc4[nt] = __builtin_amdgcn_mfma_f32_16x16x32_bf16(a, bb, acc4[nt], 0, 0, 0);
                }
            }
            __builtin_amdgcn_s_setprio(0);
            unsigned short* Mb = mbuf + ((size_t)(b*128 + ch) << 16);
            #pragma unroll
            for (int nt = 0; nt < 4; nt++){
                #pragma unroll
                for (int r = 0; r < 4; r++){
                    int pl2 = plocal + lkg*4 + r;
                    int px = nt*16 + lrow;
                    float g = bf2f(pm[spl + 1][pl2*PMS + px]);
                    Mb[(size_t)(pc*32 + pl2)*64 + px] = f2bf(gelu_f(acc4[nt][r]) * g);
                }
            }
        }
        __syncthreads();
    }
}

// ---------------- FFN out-projection via MFMA: out = y1 + m @ w_out.T
__global__ __launch_bounds__(256) void k_out(const unsigned short* __restrict__ y1b,
    const unsigned short* __restrict__ mbuf, const unsigned short* __restrict__ wob,
    float* __restrict__ out, int b0)
{
    __shared__ __align__(16) unsigned short mlds[2][64][136];
    int tid = threadIdx.x;
    int lane = tid & 63;
    int wv = tid >> 6;
    int lrow = lane & 15;
    int lkg  = lane >> 4;
    int blk = blockIdx.x;
    int b  = blk >> 9;
    int pp = blk & 511;

    for (int it = 0; it < 8; it++){
        int chunk = tid + it*256;
        int ch = chunk >> 4;
        int p = (chunk >> 3) & 1;
        int px8 = chunk & 7;
        bf16x8 v = *(const bf16x8*)&mbuf[(((size_t)(b*128 + ch)) << 16) + (size_t)(2*pp + p)*64 + px8*8];
        #pragma unroll
        for (int j = 0; j < 8; j++) mlds[p][px8*8 + j][ch] = (unsigned short)v[j];
    }
    __syncthreads();

    int p = wv >> 1;
    int ochalf = wv & 1;
    f32x4 acc[2][4];
    #pragma unroll
    for (int mt = 0; mt < 2; mt++)
        #pragma unroll
        for (int nt = 0; nt < 4; nt++) acc[mt][nt] = (f32x4){0.f,0.f,0.f,0.f};
    __builtin_amdgcn_s_setprio(1);
    #pragma unroll
    for (int kst = 0; kst < 4; kst++){
        bf16x8 a0 = *(const bf16x8*)&wob[(size_t)(ochalf*32 + 0  + lrow)*128 + kst*32 + lkg*8];
        bf16x8 a1 = *(const bf16x8*)&wob[(size_t)(ochalf*32 + 16 + lrow)*128 + kst*32 + lkg*8];
        #pragma unroll
        for (int nt = 0; nt < 4; nt++){
            bf16x8 bb = *(const bf16x8*)&mlds[p][nt*16 + lrow][kst*32 + lkg*8];
            acc[0][nt] = __builtin_amdgcn_mfma_f32_16x16x32_bf16(a0, bb, acc[0][nt], 0, 0, 0);
            acc[1][nt] = __builtin_amdgcn_mfma_f32_16x16x32_bf16(a1, bb, acc[1][nt], 0, 0, 0);
        }
    }
    __builtin_amdgcn_s_setprio(0);
    int patchIdx = 2*pp + p;
    int Rb = (patchIdx >> 5) * 8, Cb = (patchIdx & 31) * 8;
    #pragma unroll
    for (int mt = 0; mt < 2; mt++){
        #pragma unroll
        for (int nt = 0; nt < 4; nt++){
            #pragma unroll
            for (int r = 0; r < 4; r++){
                int oc = ochalf*32 + mt*16 + lkg*4 + r;
                int px = nt*16 + lrow;
                int R = Rb + (px >> 3), C = Cb + (px & 7);
                size_t li = (((size_t)(b*64 + oc)) << 16) + (size_t)R*256 + C;
                size_t go = (((size_t)((b0 + b)*64 + oc)) << 16) + (size_t)R*256 + C;
                out[go] = bf2f(y1b[li]) + acc[mt][nt][r];
            }
        }
    }
}

extern "C" void kernel_launch(void* const* d_in, const int* in_sizes, int n_in,
                              void* d_out, int out_size, void* d_ws, size_t ws_size,
                              hipStream_t stream){
    const float* x        = (const float*)d_in[0];
    const float* ln_w     = (const float*)d_in[1];
    const float* ln_b     = (const float*)d_in[2];
    const float* lnh_w    = (const float*)d_in[3];
    const float* lnh_b    = (const float*)d_in[4];
    const float* w_qkv    = (const float*)d_in[5];
    const float* b_qkv    = (const float*)d_in[6];
    const float* w_proj   = (const float*)d_in[7];
    const float* b_proj   = (const float*)d_in[8];
    const float* rel_tab  = (const float*)d_in[9];
    const float* g_main   = (const float*)d_in[10];
    const float* g_aux    = (const float*)d_in[11];
    const float* g_cross  = (const float*)d_in[12];
    const float* aux_dw   = (const float*)d_in[13];
    const float* aux_pw   = (const float*)d_in[14];
    const float* cg_w1    = (const float*)d_in[15];
    const float* cg_w2    = (const float*)d_in[16];
    const float* attn_ow  = (const float*)d_in[17];
    const float* ffn_in_w = (const float*)d_in[18];
    const float* ffn_dw   = (const float*)d_in[19];
    const float* ffn_ow   = (const float*)d_in[20];
    const float* wb_re    = (const float*)d_in[21];
    const float* wb_im    = (const float*)d_in[22];
    const int*   rel_idx  = (const int*)d_in[23];
    float* out = (float*)d_out;
    (void)in_sizes; (void)n_in; (void)out_size;

    const size_t MBsz = (size_t)1 << 20;
    auto need = [&](int nb)->size_t { return (size_t)nb*72*MBsz + 2*MBsz; };
    int nbmax = 4;
    while (nbmax > 1 && need(nbmax) > ws_size) nbmax >>= 1;

    for (int b0 = 0; b0 < 4; b0 += nbmax){
        int nb = nbmax;
        char* p = (char*)d_ws;
        char* U = p;                      p += (size_t)nb*72*MBsz;
        float* gap  = (float*)p;          p += 4096;
        float* gate = (float*)p;          p += 4096;
        unsigned short* wqb = (unsigned short*)p; p += 576*192*2;
        unsigned short* wpb = (unsigned short*)p; p += 192*192*2;
        float* bias6 = (float*)p;         p += 6*64*64*4;
        unsigned short* circ = (unsigned short*)p; p += 128*4096*2;
        unsigned short* wob  = (unsigned short*)p; p += 64*128*2;
        unsigned short* wib  = (unsigned short*)p; p += 256*64*2;
        unsigned short* waob = (unsigned short*)p; p += 64*64*2;
        unsigned short* pwab = (unsigned short*)p; p += 64*64*2;

        // phase-1 overlays in U[0, nb*10MB) (inside mbuf's future [0, nb*16MB))
        unsigned short* ll   = (unsigned short*)U;                          // nb*2MB
        unsigned short* highb= (unsigned short*)(U + (size_t)nb*2*MBsz);    // nb*6MB
        unsigned short* rll  = (unsigned short*)(U + (size_t)nb*8*MBsz);    // nb*2MB
        // phase-2
        unsigned short* mbuf = (unsigned short*)U;                          // nb*16MB
        unsigned short* h    = (unsigned short*)(U + (size_t)nb*32*MBsz);   // nb*32MB
        unsigned short* y1b  = (unsigned short*)(U + (size_t)nb*64*MBsz);   // nb*8MB

        k_kcirc<<<128, 256, 0, stream>>>(wb_re, wb_im, circ);
        k_cvt<<<432, 256, 0, stream>>>(w_qkv, w_proj, rel_tab, rel_idx, ffn_ow, ffn_in_w,
                                       attn_ow, aux_pw,
                                       wqb, wpb, bias6, wob, wib, waob, pwab, gap);
        k_dwt<<<nb*2048, 256, 0, stream>>>(x, ll, highb, gap, nb, b0);
        k_gate<<<nb, 256, 0, stream>>>(gap, cg_w1, cg_w2, gate);
        k_attn<<<nb*256, 256, 0, stream>>>(highb, wqb, wpb, b_qkv, b_proj, bias6,
                                           lnh_w, lnh_b, gate, g_main, g_cross);
        k_aux<<<nb*256, 256, 0, stream>>>(ll, aux_dw, pwab, g_aux, rll, nb);
        k_iwt_ffn<<<nb*1024, 256, 0, stream>>>(rll, highb, x, waob, ln_w, ln_b, wib,
                                               y1b, h, nb, b0);
        k_convb<<<nb*512, 256, 0, stream>>>(h, ffn_dw, circ, mbuf, nb);
        k_out<<<nb*512, 256, 0, stream>>>(y1b, mbuf, wob, out, b0);
    }
}

// Round 16
// 472.764 us; speedup vs baseline: 1.7983x; 1.0487x over previous
//
#include <hip/hip_runtime.h>
#include <hip/hip_bf16.h>
#include <math.h>

#define DIMC 64
#define C3 192
#define NHEADS 6
#define DH 32
#define WSZ 8
#define SHIFTV 4
#define HIDC 128
#define FULLR 256
#define HALFR 128

typedef __attribute__((ext_vector_type(8))) short bf16x8;
typedef __attribute__((ext_vector_type(4))) float f32x4;

__device__ __forceinline__ float gelu_f(float x){
    return 0.5f * x * (1.0f + erff(x * 0.70710678118654752440f));
}
__device__ __forceinline__ unsigned short f2bf(float f){
    union { float f; unsigned u; } v; v.f = f;
    unsigned r = (v.u + 0x7FFF + ((v.u >> 16) & 1)) >> 16;
    return (unsigned short)r;
}
__device__ __forceinline__ float bf2f(unsigned short h){
    union { unsigned u; float f; } v; v.u = ((unsigned)h) << 16;
    return v.f;
}

// ---------------- DWT: ll bf16 (plane), high bf16 (window-token-major), + fused gap partial sums
__global__ __launch_bounds__(256) void k_dwt(const float* __restrict__ x, unsigned short* __restrict__ ll,
                                             unsigned short* __restrict__ high, float* __restrict__ gap,
                                             int nb, int b0){
    __shared__ float red[256];
    int idx = blockIdx.x * 256 + threadIdx.x;
    int total = nb << 19;
    if (idx >= total) return;
    int w4 = idx & 63;
    int h  = (idx >> 6) & 127;
    int c  = (idx >> 13) & 63;
    int b  = idx >> 19;
    const float* xp = x + (((size_t)(b0 + b) * DIMC + c) * FULLR + 2*h) * FULLR + 4*w4;
    float4 r0 = *(const float4*)xp;
    float4 r1 = *(const float4*)(xp + FULLR);
    size_t lbase = (((size_t)b*64 + c) << 14) + h*128 + w4*2;
    float x1a = 0.5f*r0.x, x3a = 0.5f*r0.y, x2a = 0.5f*r1.x, x4a = 0.5f*r1.y;
    float x1b = 0.5f*r0.z, x3b = 0.5f*r0.w, x2b = 0.5f*r1.z, x4b = 0.5f*r1.w;
    float lva = x1a + x2a + x3a + x4a;
    float lvb = x1b + x2b + x3b + x4b;
    *(unsigned*)&ll[lbase] = (unsigned)f2bf(lva) | ((unsigned)f2bf(lvb) << 16);
    int hs = (h + SHIFTV) & 127;  int wh = hs >> 3; int rr = hs & 7;
    int ws = (2*w4 + SHIFTV) & 127; int ww = ws >> 3; int cc = ws & 7;
    size_t wbase = ((size_t)(b*256 + wh*16 + ww)) * 12288 + rr*8 + cc;
    unsigned u;
    u = (unsigned)f2bf(-x1a - x2a + x3a + x4a) | ((unsigned)f2bf(-x1b - x2b + x3b + x4b) << 16);
    *(unsigned*)&high[wbase + (size_t)c*64] = u;
    u = (unsigned)f2bf(-x1a + x2a - x3a + x4a) | ((unsigned)f2bf(-x1b + x2b - x3b + x4b) << 16);
    *(unsigned*)&high[wbase + (size_t)(64 + c)*64] = u;
    u = (unsigned)f2bf( x1a - x2a - x3a + x4a) | ((unsigned)f2bf( x1b - x2b - x3b + x4b) << 16);
    *(unsigned*)&high[wbase + (size_t)(128 + c)*64] = u;
    red[threadIdx.x] = lva + lvb;
    __syncthreads();
    for (int st = 128; st > 0; st >>= 1){
        if (threadIdx.x < st) red[threadIdx.x] += red[threadIdx.x + st];
        __syncthreads();
    }
    if (threadIdx.x == 0) atomicAdd(&gap[b*64 + c], red[0]);
}

// ---------------- gate MLP (gap holds SUM; fold 1/16384)
__global__ __launch_bounds__(256) void k_gate(const float* __restrict__ gap, const float* __restrict__ w1,
                                              const float* __restrict__ w2, float* __restrict__ gate){
    int b = blockIdx.x;
    __shared__ float hid[48];
    __shared__ float g[64];
    if (threadIdx.x < 64) g[threadIdx.x] = gap[b*64 + threadIdx.x] * (1.0f/16384.0f);
    __syncthreads();
    if (threadIdx.x < 48){
        float s = 0.f;
        for (int c = 0; c < 64; c++) s += g[c] * w1[threadIdx.x*64 + c];
        hid[threadIdx.x] = gelu_f(s);
    }
    __syncthreads();
    if (threadIdx.x < C3){
        float s = 0.f;
        for (int j = 0; j < 48; j++) s += hid[j] * w2[threadIdx.x*48 + j];
        gate[b*C3 + threadIdx.x] = 1.0f / (1.0f + expf(-s));
    }
}

// ---------------- FAT prep: blk<128 -> kcirc, else cvt (weights->bf16, bias table, gap zero)
__global__ __launch_bounds__(256) void k_prep(const float* __restrict__ wr, const float* __restrict__ wi,
    unsigned short* __restrict__ circ,
    const float* __restrict__ wq, const float* __restrict__ wp,
    const float* __restrict__ rel_table, const int* __restrict__ rel_idx, const float* __restrict__ wo,
    const float* __restrict__ wif, const float* __restrict__ wao, const float* __restrict__ pwa,
    unsigned short* __restrict__ wqb, unsigned short* __restrict__ wpb, float* __restrict__ bias6,
    unsigned short* __restrict__ wob, unsigned short* __restrict__ wib,
    unsigned short* __restrict__ waob, unsigned short* __restrict__ pwab, float* __restrict__ gap){
    int tid = threadIdx.x;
    if (blockIdx.x < 128){
        __shared__ float ksl[64];
        int ch = blockIdx.x;
        if (tid < 64){
            int r = tid >> 3, c = tid & 7;
            float s = 0.f;
            for (int u = 0; u < 8; u++){
                for (int v = 0; v < 8; v++){
                    float re, im;
                    if (v <= 4){ re = wr[ch*40 + u*5 + v]; im = wi[ch*40 + u*5 + v]; }
                    else { int u2 = (8-u)&7; int v2 = 8-v; re = wr[ch*40 + u2*5 + v2]; im = -wi[ch*40 + u2*5 + v2]; }
                    float ang = (float)(u*r + v*c) * 0.78539816339744831f;
                    float cs, sn; __sincosf(ang, &sn, &cs);
                    s += re * cs - im * sn;
                }
            }
            ksl[tid] = s * (1.0f/64.0f);
        }
        __syncthreads();
        for (int idx = tid; idx < 4096; idx += 256){
            int o = idx >> 6, i = idx & 63;
            int dr = ((o >> 3) - (i >> 3)) & 7;
            int dc = ((o & 7) - (i & 7)) & 7;
            circ[(size_t)ch*4096 + idx] = f2bf(ksl[dr*8 + dc]);
        }
    } else {
        int idx = (blockIdx.x - 128)*256 + tid;
        if (idx < 576*192) wqb[idx] = f2bf(wq[idx]);
        if (idx < 192*192) wpb[idx] = f2bf(wp[idx]);
        if (idx < 64*128)  wob[idx] = f2bf(wo[idx]);
        if (idx < 256*64)  wib[idx] = f2bf(wif[idx]);
        if (idx < 64*64){  waob[idx] = f2bf(wao[idx]); pwab[idx] = f2bf(pwa[idx]); }
        if (idx < 256)     gap[idx] = 0.f;
        if (idx < 6*64*64){
            int h = idx >> 12; int ij = idx & 4095;
            bias6[idx] = rel_table[rel_idx[ij]*NHEADS + h];
        }
    }
}

// ---------------- FAT kernel: blk < nb*256 -> MHSA (in-place on high); else -> aux path
__global__ __launch_bounds__(256, 3) void k_attn_aux(unsigned short* __restrict__ high,
    const unsigned short* __restrict__ wqb, const unsigned short* __restrict__ wpb,
    const float* __restrict__ bqkv, const float* __restrict__ bproj,
    const float* __restrict__ bias6, const float* __restrict__ lnw, const float* __restrict__ lnb,
    const float* __restrict__ gate, const float* __restrict__ gm_p, const float* __restrict__ gc_p,
    const unsigned short* __restrict__ ll, const float* __restrict__ dw,
    const unsigned short* __restrict__ pwab, const float* __restrict__ ga_p,
    unsigned short* __restrict__ rll, int nb)
{
    __shared__ __align__(16) char smem[52224];
    int tid = threadIdx.x;
    int lane = tid & 63;
    int wv = tid >> 6;
    int lrow = lane & 15;
    int lkg  = lane >> 4;

    if ((int)blockIdx.x < nb*256){
        // ================= ATTN path =================
        unsigned short (*xb)[200] = (unsigned short(*)[200])smem;                // 25600
        unsigned short (*qs)[40]  = (unsigned short(*)[40])(smem + 25600);       // 5120
        unsigned short (*ks2)[40] = (unsigned short(*)[40])(smem + 30720);       // 5120
        unsigned short (*vt)[72]  = (unsigned short(*)[72])(smem + 35840);       // 4608
        unsigned short (*ps)[72]  = (unsigned short(*)[72])(smem + 40448);       // 9216
        float (*st_s)[64]  = (float(*)[64])(smem + 49664);                       // 1024
        float (*st_ss)[64] = (float(*)[64])(smem + 50688);                       // 1024
        float* mu_s = (float*)(smem + 51712);                                    // 256
        float* rs_s = (float*)(smem + 51968);                                    // 256

        int blk = blockIdx.x;
        int b  = blk >> 8;
        size_t wbase = (size_t)blk * 12288;
        const float scale = 0.17677669529663687f;
        float gm = gm_p[0], gc = gc_p[0];

        int t = lane, part = wv;
        float vals[48];
        {
            float s = 0.f, ss = 0.f;
            #pragma unroll
            for (int i = 0; i < 48; i++){
                float v = bf2f(high[wbase + (size_t)(part*48 + i)*64 + t]);
                vals[i] = v; s += v; ss += v*v;
            }
            st_s[part][t] = s; st_ss[part][t] = ss;
        }
        __syncthreads();
        if (tid < 64){
            float s = st_s[0][tid]+st_s[1][tid]+st_s[2][tid]+st_s[3][tid];
            float ss = st_ss[0][tid]+st_ss[1][tid]+st_ss[2][tid]+st_ss[3][tid];
            float mu = s*(1.f/C3);
            float var = ss*(1.f/C3) - mu*mu;
            mu_s[tid] = mu; rs_s[tid] = rsqrtf(var + 1e-6f);
        }
        __syncthreads();
        {
            float mu = mu_s[t], rs = rs_s[t];
            #pragma unroll
            for (int i8 = 0; i8 < 6; i8++){
                bf16x8 pk;
                #pragma unroll
                for (int jj = 0; jj < 8; jj++){
                    int c = part*48 + i8*8 + jj;
                    float nv = (vals[i8*8+jj] - mu) * rs * lnw[c] + lnb[c];
                    pk[jj] = (short)f2bf(nv);
                }
                *(bf16x8*)&xb[t][part*48 + i8*8] = pk;
            }
        }
        __syncthreads();

        f32x4 pacc[3][4];
        #pragma unroll
        for (int mt3 = 0; mt3 < 3; mt3++)
            #pragma unroll
            for (int nt = 0; nt < 4; nt++) pacc[mt3][nt] = (f32x4){0.f,0.f,0.f,0.f};

        for (int h = 0; h < NHEADS; h++){
            f32x4 acc[6];
            #pragma unroll
            for (int nt = 0; nt < 6; nt++) acc[nt] = (f32x4){0.f,0.f,0.f,0.f};
            __builtin_amdgcn_s_setprio(1);
            for (int ksU = 0; ksU < 6; ksU++){
                int c0 = ksU*32 + lkg*8;
                bf16x8 a = *(const bf16x8*)&xb[wv*16 + lrow][c0];
                #pragma unroll
                for (int nt = 0; nt < 6; nt++){
                    int which = nt >> 1;
                    int gr = which*C3 + h*32 + (nt&1)*16 + lrow;
                    bf16x8 bb = *(const bf16x8*)&wqb[(size_t)gr*C3 + c0];
                    acc[nt] = __builtin_amdgcn_mfma_f32_16x16x32_bf16(a, bb, acc[nt], 0, 0, 0);
                }
            }
            __builtin_amdgcn_s_setprio(0);
            #pragma unroll
            for (int nt = 0; nt < 6; nt++){
                int which = nt >> 1;
                int d = (nt&1)*16 + lrow;
                float bias = bqkv[which*C3 + h*32 + d];
                #pragma unroll
                for (int r = 0; r < 4; r++){
                    int row = wv*16 + lkg*4 + r;
                    float v = acc[nt][r] + bias;
                    if (which == 0)      qs[row][d]  = f2bf(v * scale);
                    else if (which == 1) ks2[row][d] = f2bf(v);
                    else                 vt[d][row]  = f2bf(v);
                }
            }
            __syncthreads();

            f32x4 sacc[4];
            {
                bf16x8 a = *(const bf16x8*)&qs[wv*16 + lrow][lkg*8];
                #pragma unroll
                for (int nt = 0; nt < 4; nt++){
                    bf16x8 bb = *(const bf16x8*)&ks2[nt*16 + lrow][lkg*8];
                    f32x4 z = (f32x4){0.f,0.f,0.f,0.f};
                    sacc[nt] = __builtin_amdgcn_mfma_f32_16x16x32_bf16(a, bb, z, 0, 0, 0);
                }
            }
            {
                #pragma unroll
                for (int r = 0; r < 4; r++){
                    int i = wv*16 + lkg*4 + r;
                    float pv[4];
                    float s = 0.f;
                    #pragma unroll
                    for (int nt = 0; nt < 4; nt++){
                        pv[nt] = __expf(sacc[nt][r] + bias6[h*4096 + i*64 + nt*16 + lrow]);
                        s += pv[nt];
                    }
                    s += __shfl_xor(s, 1); s += __shfl_xor(s, 2);
                    s += __shfl_xor(s, 4); s += __shfl_xor(s, 8);
                    float inv = 1.0f / s;
                    #pragma unroll
                    for (int nt = 0; nt < 4; nt++) ps[i][nt*16 + lrow] = f2bf(pv[nt] * inv);
                }
            }
            __syncthreads();

            f32x4 oacc[2];
            #pragma unroll
            for (int nt = 0; nt < 2; nt++) oacc[nt] = (f32x4){0.f,0.f,0.f,0.f};
            #pragma unroll
            for (int kst = 0; kst < 2; kst++){
                bf16x8 a = *(const bf16x8*)&ps[wv*16 + lrow][kst*32 + lkg*8];
                #pragma unroll
                for (int nt = 0; nt < 2; nt++){
                    bf16x8 bb = *(const bf16x8*)&vt[nt*16 + lrow][kst*32 + lkg*8];
                    oacc[nt] = __builtin_amdgcn_mfma_f32_16x16x32_bf16(a, bb, oacc[nt], 0, 0, 0);
                }
            }
            #pragma unroll
            for (int nt = 0; nt < 2; nt++)
                #pragma unroll
                for (int r = 0; r < 4; r++)
                    qs[wv*16 + lkg*4 + r][nt*16 + lrow] = f2bf(oacc[nt][r]);
            __syncthreads();

            __builtin_amdgcn_s_setprio(1);
            #pragma unroll
            for (int mt3 = 0; mt3 < 3; mt3++){
                int o = wv*48 + mt3*16 + lrow;
                bf16x8 a = *(const bf16x8*)&wpb[(size_t)o*C3 + h*32 + lkg*8];
                #pragma unroll
                for (int nt = 0; nt < 4; nt++){
                    bf16x8 bb = *(const bf16x8*)&qs[nt*16 + lrow][lkg*8];
                    pacc[mt3][nt] = __builtin_amdgcn_mfma_f32_16x16x32_bf16(a, bb, pacc[mt3][nt], 0, 0, 0);
                }
            }
            __builtin_amdgcn_s_setprio(0);
            __syncthreads();
        }

        #pragma unroll
        for (int mt3 = 0; mt3 < 3; mt3++){
            #pragma unroll
            for (int r = 0; r < 4; r++){
                int o = wv*48 + mt3*16 + lkg*4 + r;
                float bias = bproj[o];
                float gf = 1.0f + gc * (gate[b*C3 + o] - 0.5f) * 2.0f;
                #pragma unroll
                for (int nt = 0; nt < 4; nt++){
                    int token = nt*16 + lrow;
                    size_t gi = wbase + (size_t)o*64 + token;
                    float orig = bf2f(high[gi]);
                    high[gi] = f2bf((orig + gm*(pacc[mt3][nt][r] + bias)) * gf);
                }
            }
        }
    } else {
        // ================= AUX path =================
        unsigned short (*sll)[3][80] = (unsigned short(*)[3][80])smem;           // 30720
        unsigned short (*tlb)[72]    = (unsigned short(*)[72])(smem + 30720);    // 9216

        int blk = blockIdx.x - nb*256;
        int b   = blk >> 8;
        int row = (blk >> 1) & 127;
        int seg = blk & 1;
        int px0 = seg*64;

        for (int j = tid; j < 1920; j += 256){
            int c = j / 30;
            int rem = j % 30;
            int dy = rem / 10;
            int i8 = rem % 10;
            int gr = row + dy - 1;
            int gp = px0 - 8 + i8*8;
            bf16x8 v = (bf16x8){0,0,0,0,0,0,0,0};
            if (gr >= 0 && gr < 128 && gp >= 0 && gp < 128)
                v = *(const bf16x8*)&ll[(((size_t)b*64 + c) << 14) + gr*128 + gp];
            *(bf16x8*)&sll[c][dy][i8*8] = v;
        }
        __syncthreads();

        int px = tid & 63, cq = tid >> 6;
        for (int ci = cq; ci < 64; ci += 4){
            const float* wd = dw + ci*9;
            float s = 0.f;
            #pragma unroll
            for (int dy = 0; dy < 3; dy++){
                float a0 = bf2f(sll[ci][dy][px+7]);
                float a1 = bf2f(sll[ci][dy][px+8]);
                float a2 = bf2f(sll[ci][dy][px+9]);
                s += wd[dy*3+0]*a0 + wd[dy*3+1]*a1 + wd[dy*3+2]*a2;
            }
            tlb[px][ci] = f2bf(gelu_f(s));
        }
        __syncthreads();

        float ga = ga_p[0];
        f32x4 acc[4];
        #pragma unroll
        for (int nt = 0; nt < 4; nt++) acc[nt] = (f32x4){0.f,0.f,0.f,0.f};
        __builtin_amdgcn_s_setprio(1);
        #pragma unroll
        for (int kst = 0; kst < 2; kst++){
            bf16x8 a = *(const bf16x8*)&pwab[(size_t)(wv*16 + lrow)*64 + kst*32 + lkg*8];
            #pragma unroll
            for (int nt = 0; nt < 4; nt++){
                bf16x8 bb = *(const bf16x8*)&tlb[nt*16 + lrow][kst*32 + lkg*8];
                acc[nt] = __builtin_amdgcn_mfma_f32_16x16x32_bf16(a, bb, acc[nt], 0, 0, 0);
            }
        }
        __builtin_amdgcn_s_setprio(0);
        #pragma unroll
        for (int nt = 0; nt < 4; nt++){
            #pragma unroll
            for (int r = 0; r < 4; r++){
                int o = wv*16 + lkg*4 + r;
                int pxx = nt*16 + lrow;
                float base = bf2f(sll[o][1][pxx + 8]);
                rll[(((size_t)b*64 + o) << 14) + row*128 + px0 + pxx] = f2bf(base + ga * acc[nt][r]);
            }
        }
    }
}

// ---------------- FUSED IWT + proj + residual -> y1b, then LN + conv1x1(64->256) -> h (all MFMA)
__global__ __launch_bounds__(256) void k_iwt_ffn(const unsigned short* __restrict__ rll,
    const unsigned short* __restrict__ high, const float* __restrict__ x,
    const unsigned short* __restrict__ waob,
    const float* __restrict__ lnw, const float* __restrict__ lnb,
    const unsigned short* __restrict__ wib,
    unsigned short* __restrict__ y1b, unsigned short* __restrict__ h, int nb, int b0)
{
    __shared__ __align__(16) char smem[38912];
    float* xt            = (float*)smem;
    unsigned short* ho   = (unsigned short*)smem;
    unsigned short* dbufT= (unsigned short*)(smem + 18432);
    unsigned short* xn   = (unsigned short*)(smem + 27648);
    float* pss           = (float*)(smem + 36864);
    float* psss          = (float*)(smem + 37888);

    int tid = threadIdx.x;
    int blk = blockIdx.x;
    int seg = blk & 3;
    int ph  = (blk >> 2) & 255;
    int b   = blk >> 10;
    int pw0 = seg * 64;
    int h2 = ph >> 1, p = ph & 1;
    size_t xbase = ((size_t)(b0 + b) * DIMC) * 65536;
    int px = tid & 63;
    int ci = tid >> 6;
    int pwv = pw0 + px;
    int w2 = pwv >> 1, q = pwv & 1;
    float shl = q ? 1.f : -1.f;
    float slh = p ? 1.f : -1.f;
    float shh = (p == q) ? 1.f : -1.f;
    int hs = (h2 + SHIFTV) & 127; int wh = hs >> 3; int rr = hs & 7;
    int ws = (w2 + SHIFTV) & 127; int ww = ws >> 3; int cc = ws & 7;
    size_t wbase = ((size_t)(b*256 + wh*16 + ww)) * 12288 + rr*8 + cc;
    for (int i = ci; i < 64; i += 4){
        float llv = bf2f(rll[(((size_t)b*64 + i) << 14) + h2*128 + w2]);
        float hl = bf2f(high[wbase + (size_t)i*64]);
        float lh = bf2f(high[wbase + (size_t)(64 + i)*64]);
        float hh = bf2f(high[wbase + (size_t)(128 + i)*64]);
        float iw = 0.5f * (llv + shl*hl + slh*lh + shh*hh);
        float xv = x[xbase + (size_t)i*65536 + (size_t)ph*256 + pwv];
        xt[i*65 + px] = xv;
        dbufT[px*72 + i] = f2bf(iw - xv);
    }
    __syncthreads();

    int lane = tid & 63;
    int wv = tid >> 6;
    int lrow = lane & 15;
    int lkg  = lane >> 4;
    f32x4 acc[4];
    #pragma unroll
    for (int nt = 0; nt < 4; nt++) acc[nt] = (f32x4){0.f,0.f,0.f,0.f};
    __builtin_amdgcn_s_setprio(1);
    #pragma unroll
    for (int kst = 0; kst < 2; kst++){
        bf16x8 a = *(const bf16x8*)&waob[(size_t)(wv*16 + lrow)*64 + kst*32 + lkg*8];
        #pragma unroll
        for (int nt = 0; nt < 4; nt++){
            bf16x8 bb = *(const bf16x8*)&dbufT[(nt*16 + lrow)*72 + kst*32 + lkg*8];
            acc[nt] = __builtin_amdgcn_mfma_f32_16x16x32_bf16(a, bb, acc[nt], 0, 0, 0);
        }
    }
    __builtin_amdgcn_s_setprio(0);
    float yv[4][4];
    float s4[4], ss4[4];
    #pragma unroll
    for (int nt = 0; nt < 4; nt++){ s4[nt] = 0.f; ss4[nt] = 0.f; }
    #pragma unroll
    for (int nt = 0; nt < 4; nt++){
        int pxx = nt*16 + lrow;
        #pragma unroll
        for (int r = 0; r < 4; r++){
            int o = wv*16 + lkg*4 + r;
            float v = xt[o*65 + pxx] + acc[nt][r];
            yv[nt][r] = v;
            s4[nt] += v; ss4[nt] += v*v;
            y1b[(((size_t)(b*64 + o)) << 16) + (size_t)ph*256 + pw0 + pxx] = f2bf(v);
        }
    }
    #pragma unroll
    for (int nt = 0; nt < 4; nt++){
        s4[nt]  += __shfl_xor(s4[nt], 16);  s4[nt]  += __shfl_xor(s4[nt], 32);
        ss4[nt] += __shfl_xor(ss4[nt], 16); ss4[nt] += __shfl_xor(ss4[nt], 32);
    }
    if (lkg == 0){
        #pragma unroll
        for (int nt = 0; nt < 4; nt++){
            pss[wv*64 + nt*16 + lrow]  = s4[nt];
            psss[wv*64 + nt*16 + lrow] = ss4[nt];
        }
    }
    __syncthreads();
    #pragma unroll
    for (int nt = 0; nt < 4; nt++){
        int pxx = nt*16 + lrow;
        float s  = pss[pxx]  + pss[64 + pxx]  + pss[128 + pxx]  + pss[192 + pxx];
        float ss = psss[pxx] + psss[64 + pxx] + psss[128 + pxx] + psss[192 + pxx];
        float mu = s * (1.f/64.f);
        float var = ss * (1.f/64.f) - mu*mu;
        float rs = rsqrtf(var + 1e-6f);
        #pragma unroll
        for (int r = 0; r < 4; r++){
            int o = wv*16 + lkg*4 + r;
            xn[pxx*72 + o] = f2bf((yv[nt][r] - mu) * rs * lnw[o] + lnb[o]);
        }
    }
    __syncthreads();
    for (int hh = 0; hh < 2; hh++){
        int oc0 = hh*128;
        f32x4 cacc[8];
        #pragma unroll
        for (int nt = 0; nt < 8; nt++) cacc[nt] = (f32x4){0.f,0.f,0.f,0.f};
        __builtin_amdgcn_s_setprio(1);
        #pragma unroll
        for (int kst = 0; kst < 2; kst++){
            bf16x8 a = *(const bf16x8*)&xn[(wv*16 + lrow)*72 + kst*32 + lkg*8];
            #pragma unroll
            for (int nt = 0; nt < 8; nt++){
                bf16x8 bb = *(const bf16x8*)&wib[(size_t)(oc0 + nt*16 + lrow)*64 + kst*32 + lkg*8];
                cacc[nt] = __builtin_amdgcn_mfma_f32_16x16x32_bf16(a, bb, cacc[nt], 0, 0, 0);
            }
        }
        __builtin_amdgcn_s_setprio(0);
        #pragma unroll
        for (int nt = 0; nt < 8; nt++)
            #pragma unroll
            for (int r = 0; r < 4; r++)
                ho[(nt*16 + lrow)*72 + wv*16 + lkg*4 + r] = f2bf(cacc[nt][r]);
        __syncthreads();
        for (int idx = tid; idx < 1024; idx += 256){
            int oc = idx >> 3, p8 = idx & 7;
            bf16x8 v = *(const bf16x8*)&ho[oc*72 + p8*8];
            *(bf16x8*)&h[(size_t)(b*256 + oc0 + oc)*65536 + (size_t)ph*256 + pw0 + p8*8] = v;
        }
        __syncthreads();
    }
}

// ---------------- FUSED FFN-B + spectral conv
#define PMS 68
__global__ __launch_bounds__(256) void k_convb(const unsigned short* __restrict__ h,
    const float* __restrict__ w_dw, const unsigned short* __restrict__ circ,
    unsigned short* __restrict__ mbuf, int nb)
{
    __shared__ __align__(16) unsigned short stage[4][10][272];
    __shared__ __align__(16) unsigned short pm[4][32*PMS];
    int tid = threadIdx.x;
    int lane = tid & 63;
    int wv = tid >> 6;
    int lrow = lane & 15;
    int lkg  = lane >> 4;
    int blk = blockIdx.x;
    int b   = blk >> 9;
    int chg = (blk >> 5) & 15;
    int pc  = blk & 31;
    int r0 = pc*8;

    auto stage_fn = [&](int c16){
        int chA = chg*8 + c16;
        int chs[4] = {chA, chA+128, chA+4, chA+132};
        for (int j = tid; j < 1280; j += 256){
            int pl = j / 320;
            int rem = j - pl*320;
            int row10 = rem >> 5;
            int c0 = (rem & 31) << 3;
            int gr = r0 + row10 - 1;
            bf16x8 v = (bf16x8){0,0,0,0,0,0,0,0};
            if (gr >= 0 && gr < 256)
                v = *(const bf16x8*)&h[((size_t)(b*256 + chs[pl]) << 16) + (size_t)gr*256 + c0];
            *(bf16x8*)&stage[pl][row10][c0] = v;
        }
    };

    stage_fn(0);
    __syncthreads();

    for (int c16 = 0; c16 < 4; c16++){
        {
            int chA = chg*8 + c16;
            int chs[4] = {chA, chA+128, chA+4, chA+132};
            for (int j = tid; j < 1024; j += 256){
                int pl = j >> 8;
                int rem = j & 255;
                int r = rem >> 5;
                int c0 = (rem & 31) << 3;
                const float* wd = w_dw + chs[pl]*9;
                float acc[8] = {0,0,0,0,0,0,0,0};
                #pragma unroll
                for (int dy = 0; dy < 3; dy++){
                    const unsigned short* rp = &stage[pl][r+dy][0];
                    bf16x8 v = *(const bf16x8*)&rp[c0];
                    float vf[8];
                    #pragma unroll
                    for (int jj = 0; jj < 8; jj++) vf[jj] = bf2f((unsigned short)v[jj]);
                    float l  = (c0 > 0)   ? bf2f(rp[c0 - 1]) : 0.f;
                    float rg = (c0 < 248) ? bf2f(rp[c0 + 8]) : 0.f;
                    float w0 = wd[dy*3+0], w1 = wd[dy*3+1], w2 = wd[dy*3+2];
                    acc[0] += w0*l + w1*vf[0] + w2*vf[1];
                    #pragma unroll
                    for (int jj = 1; jj < 7; jj++) acc[jj] += w0*vf[jj-1] + w1*vf[jj] + w2*vf[jj+1];
                    acc[7] += w0*vf[6] + w1*vf[7] + w2*rg;
                }
                bf16x8 o;
                #pragma unroll
                for (int jj = 0; jj < 8; jj++) o[jj] = (short)f2bf(acc[jj]);
                *(bf16x8*)&pm[pl][(c0 >> 3)*PMS + r*8] = o;
            }
        }
        __syncthreads();
        if (c16 < 3) stage_fn(c16 + 1);
        {
            int spl = (wv & 1) * 2;
            int ch = chg*8 + (wv & 1)*4 + c16;
            const unsigned short* Bb = circ + (size_t)ch*4096;
            int plocal = (wv >> 1)*16;
            f32x4 acc4[4];
            #pragma unroll
            for (int nt = 0; nt < 4; nt++) acc4[nt] = (f32x4){0.f,0.f,0.f,0.f};
            __builtin_amdgcn_s_setprio(1);
            #pragma unroll
            for (int kst = 0; kst < 2; kst++){
                bf16x8 a = *(const bf16x8*)&pm[spl][(plocal + lrow)*PMS + kst*32 + lkg*8];
                #pragma unroll
                for (int nt = 0; nt < 4; nt++){
                    bf16x8 bb = *(const bf16x8*)&Bb[(size_t)(nt*16 + lrow)*64 + kst*32 + lkg*8];
                    acc4[nt] = __builtin_amdgcn_mfma_f32_16x16x32_bf16(a, bb, acc4[nt], 0, 0, 0);
                }
            }
            __builtin_amdgcn_s_setprio(0);
            unsigned short* Mb = mbuf + ((size_t)(b*128 + ch) << 16);
            #pragma unroll
            for (int nt = 0; nt < 4; nt++){
                #pragma unroll
                for (int r = 0; r < 4; r++){
                    int pl2 = plocal + lkg*4 + r;
                    int px = nt*16 + lrow;
                    float g = bf2f(pm[spl + 1][pl2*PMS + px]);
                    Mb[(size_t)(pc*32 + pl2)*64 + px] = f2bf(gelu_f(acc4[nt][r]) * g);
                }
            }
        }
        __syncthreads();
    }
}

// ---------------- FFN out-projection via MFMA: out = y1 + m @ w_out.T
__global__ __launch_bounds__(256) void k_out(const unsigned short* __restrict__ y1b,
    const unsigned short* __restrict__ mbuf, const unsigned short* __restrict__ wob,
    float* __restrict__ out, int b0)
{
    __shared__ __align__(16) unsigned short mlds[2][64][136];
    int tid = threadIdx.x;
    int lane = tid & 63;
    int wv = tid >> 6;
    int lrow = lane & 15;
    int lkg  = lane >> 4;
    int blk = blockIdx.x;
    int b  = blk >> 9;
    int pp = blk & 511;

    for (int it = 0; it < 8; it++){
        int chunk = tid + it*256;
        int ch = chunk >> 4;
        int p = (chunk >> 3) & 1;
        int px8 = chunk & 7;
        bf16x8 v = *(const bf16x8*)&mbuf[(((size_t)(b*128 + ch)) << 16) + (size_t)(2*pp + p)*64 + px8*8];
        #pragma unroll
        for (int j = 0; j < 8; j++) mlds[p][px8*8 + j][ch] = (unsigned short)v[j];
    }
    __syncthreads();

    int p = wv >> 1;
    int ochalf = wv & 1;
    f32x4 acc[2][4];
    #pragma unroll
    for (int mt = 0; mt < 2; mt++)
        #pragma unroll
        for (int nt = 0; nt < 4; nt++) acc[mt][nt] = (f32x4){0.f,0.f,0.f,0.f};
    __builtin_amdgcn_s_setprio(1);
    #pragma unroll
    for (int kst = 0; kst < 4; kst++){
        bf16x8 a0 = *(const bf16x8*)&wob[(size_t)(ochalf*32 + 0  + lrow)*128 + kst*32 + lkg*8];
        bf16x8 a1 = *(const bf16x8*)&wob[(size_t)(ochalf*32 + 16 + lrow)*128 + kst*32 + lkg*8];
        #pragma unroll
        for (int nt = 0; nt < 4; nt++){
            bf16x8 bb = *(const bf16x8*)&mlds[p][nt*16 + lrow][kst*32 + lkg*8];
            acc[0][nt] = __builtin_amdgcn_mfma_f32_16x16x32_bf16(a0, bb, acc[0][nt], 0, 0, 0);
            acc[1][nt] = __builtin_amdgcn_mfma_f32_16x16x32_bf16(a1, bb, acc[1][nt], 0, 0, 0);
        }
    }
    __builtin_amdgcn_s_setprio(0);
    int patchIdx = 2*pp + p;
    int Rb = (patchIdx >> 5) * 8, Cb = (patchIdx & 31) * 8;
    #pragma unroll
    for (int mt = 0; mt < 2; mt++){
        #pragma unroll
        for (int nt = 0; nt < 4; nt++){
            #pragma unroll
            for (int r = 0; r < 4; r++){
                int oc = ochalf*32 + mt*16 + lkg*4 + r;
                int px = nt*16 + lrow;
                int R = Rb + (px >> 3), C = Cb + (px & 7);
                size_t li = (((size_t)(b*64 + oc)) << 16) + (size_t)R*256 + C;
                size_t go = (((size_t)((b0 + b)*64 + oc)) << 16) + (size_t)R*256 + C;
                out[go] = bf2f(y1b[li]) + acc[mt][nt][r];
            }
        }
    }
}

extern "C" void kernel_launch(void* const* d_in, const int* in_sizes, int n_in,
                              void* d_out, int out_size, void* d_ws, size_t ws_size,
                              hipStream_t stream){
    const float* x        = (const float*)d_in[0];
    const float* ln_w     = (const float*)d_in[1];
    const float* ln_b     = (const float*)d_in[2];
    const float* lnh_w    = (const float*)d_in[3];
    const float* lnh_b    = (const float*)d_in[4];
    const float* w_qkv    = (const float*)d_in[5];
    const float* b_qkv    = (const float*)d_in[6];
    const float* w_proj   = (const float*)d_in[7];
    const float* b_proj   = (const float*)d_in[8];
    const float* rel_tab  = (const float*)d_in[9];
    const float* g_main   = (const float*)d_in[10];
    const float* g_aux    = (const float*)d_in[11];
    const float* g_cross  = (const float*)d_in[12];
    const float* aux_dw   = (const float*)d_in[13];
    const float* aux_pw   = (const float*)d_in[14];
    const float* cg_w1    = (const float*)d_in[15];
    const float* cg_w2    = (const float*)d_in[16];
    const float* attn_ow  = (const float*)d_in[17];
    const float* ffn_in_w = (const float*)d_in[18];
    const float* ffn_dw   = (const float*)d_in[19];
    const float* ffn_ow   = (const float*)d_in[20];
    const float* wb_re    = (const float*)d_in[21];
    const float* wb_im    = (const float*)d_in[22];
    const int*   rel_idx  = (const int*)d_in[23];
    float* out = (float*)d_out;
    (void)in_sizes; (void)n_in; (void)out_size;

    const size_t MBsz = (size_t)1 << 20;
    auto need = [&](int nb)->size_t { return (size_t)nb*72*MBsz + 2*MBsz; };
    int nbmax = 4;
    while (nbmax > 1 && need(nbmax) > ws_size) nbmax >>= 1;

    for (int b0 = 0; b0 < 4; b0 += nbmax){
        int nb = nbmax;
        char* p = (char*)d_ws;
        char* U = p;                      p += (size_t)nb*72*MBsz;
        float* gap  = (float*)p;          p += 4096;
        float* gate = (float*)p;          p += 4096;
        unsigned short* wqb = (unsigned short*)p; p += 576*192*2;
        unsigned short* wpb = (unsigned short*)p; p += 192*192*2;
        float* bias6 = (float*)p;         p += 6*64*64*4;
        unsigned short* circ = (unsigned short*)p; p += 128*4096*2;
        unsigned short* wob  = (unsigned short*)p; p += 64*128*2;
        unsigned short* wib  = (unsigned short*)p; p += 256*64*2;
        unsigned short* waob = (unsigned short*)p; p += 64*64*2;
        unsigned short* pwab = (unsigned short*)p; p += 64*64*2;

        unsigned short* ll   = (unsigned short*)U;                          // nb*2MB
        unsigned short* highb= (unsigned short*)(U + (size_t)nb*2*MBsz);    // nb*6MB
        unsigned short* rll  = (unsigned short*)(U + (size_t)nb*8*MBsz);    // nb*2MB
        unsigned short* mbuf = (unsigned short*)U;                          // nb*16MB
        unsigned short* h    = (unsigned short*)(U + (size_t)nb*32*MBsz);   // nb*32MB
        unsigned short* y1b  = (unsigned short*)(U + (size_t)nb*64*MBsz);   // nb*8MB

        k_prep<<<560, 256, 0, stream>>>(wb_re, wb_im, circ,
                                        w_qkv, w_proj, rel_tab, rel_idx, ffn_ow, ffn_in_w,
                                        attn_ow, aux_pw,
                                        wqb, wpb, bias6, wob, wib, waob, pwab, gap);
        k_dwt<<<nb*2048, 256, 0, stream>>>(x, ll, highb, gap, nb, b0);
        k_gate<<<nb, 256, 0, stream>>>(gap, cg_w1, cg_w2, gate);
        k_attn_aux<<<nb*512, 256, 0, stream>>>(highb, wqb, wpb, b_qkv, b_proj, bias6,
                                               lnh_w, lnh_b, gate, g_main, g_cross,
                                               ll, aux_dw, pwab, g_aux, rll, nb);
        k_iwt_ffn<<<nb*1024, 256, 0, stream>>>(rll, highb, x, waob, ln_w, ln_b, wib,
                                               y1b, h, nb, b0);
        k_convb<<<nb*512, 256, 0, stream>>>(h, ffn_dw, circ, mbuf, nb);
        k_out<<<nb*512, 256, 0, stream>>>(y1b, mbuf, wob, out, b0);
    }
}

// Round 17
// 466.229 us; speedup vs baseline: 1.8235x; 1.0140x over previous
//
#include <hip/hip_runtime.h>
#include <hip/hip_bf16.h>
#include <math.h>

#define DIMC 64
#define C3 192
#define NHEADS 6
#define DH 32
#define WSZ 8
#define SHIFTV 4
#define HIDC 128
#define FULLR 256
#define HALFR 128

typedef __attribute__((ext_vector_type(8))) short bf16x8;
typedef __attribute__((ext_vector_type(4))) float f32x4;

__device__ __forceinline__ float gelu_f(float x){
    return 0.5f * x * (1.0f + erff(x * 0.70710678118654752440f));
}
__device__ __forceinline__ unsigned short f2bf(float f){
    union { float f; unsigned u; } v; v.f = f;
    unsigned r = (v.u + 0x7FFF + ((v.u >> 16) & 1)) >> 16;
    return (unsigned short)r;
}
__device__ __forceinline__ float bf2f(unsigned short h){
    union { unsigned u; float f; } v; v.u = ((unsigned)h) << 16;
    return v.f;
}

// ---------------- FAT: blocks [0,560) = prep (kcirc + cvt); rest = DWT (+ gap partial sums)
__global__ __launch_bounds__(256) void k_dwt_prep(const float* __restrict__ x,
    unsigned short* __restrict__ ll, unsigned short* __restrict__ high, float* __restrict__ gap,
    const float* __restrict__ wr, const float* __restrict__ wi, unsigned short* __restrict__ circ,
    const float* __restrict__ wq, const float* __restrict__ wp,
    const float* __restrict__ rel_table, const int* __restrict__ rel_idx, const float* __restrict__ wo,
    const float* __restrict__ wif, const float* __restrict__ wao, const float* __restrict__ pwa,
    unsigned short* __restrict__ wqb, unsigned short* __restrict__ wpb, float* __restrict__ bias6,
    unsigned short* __restrict__ wob, unsigned short* __restrict__ wib,
    unsigned short* __restrict__ waob, unsigned short* __restrict__ pwab,
    int nb, int b0)
{
    __shared__ float red[256];
    __shared__ float ksl[64];
    int tid = threadIdx.x;
    if (blockIdx.x < 128){
        int ch = blockIdx.x;
        if (tid < 64){
            int r = tid >> 3, c = tid & 7;
            float s = 0.f;
            for (int u = 0; u < 8; u++){
                for (int v = 0; v < 8; v++){
                    float re, im;
                    if (v <= 4){ re = wr[ch*40 + u*5 + v]; im = wi[ch*40 + u*5 + v]; }
                    else { int u2 = (8-u)&7; int v2 = 8-v; re = wr[ch*40 + u2*5 + v2]; im = -wi[ch*40 + u2*5 + v2]; }
                    float ang = (float)(u*r + v*c) * 0.78539816339744831f;
                    float cs, sn; __sincosf(ang, &sn, &cs);
                    s += re * cs - im * sn;
                }
            }
            ksl[tid] = s * (1.0f/64.0f);
        }
        __syncthreads();
        for (int idx = tid; idx < 4096; idx += 256){
            int o = idx >> 6, i = idx & 63;
            int dr = ((o >> 3) - (i >> 3)) & 7;
            int dc = ((o & 7) - (i & 7)) & 7;
            circ[(size_t)ch*4096 + idx] = f2bf(ksl[dr*8 + dc]);
        }
        return;
    }
    if (blockIdx.x < 560){
        int idx = (blockIdx.x - 128)*256 + tid;
        if (idx < 576*192) wqb[idx] = f2bf(wq[idx]);
        if (idx < 192*192) wpb[idx] = f2bf(wp[idx]);
        if (idx < 64*128)  wob[idx] = f2bf(wo[idx]);
        if (idx < 256*64)  wib[idx] = f2bf(wif[idx]);
        if (idx < 64*64){  waob[idx] = f2bf(wao[idx]); pwab[idx] = f2bf(pwa[idx]); }
        if (idx < 6*64*64){
            int h = idx >> 12; int ij = idx & 4095;
            bias6[idx] = rel_table[rel_idx[ij]*NHEADS + h];
        }
        return;
    }
    int idx = (blockIdx.x - 560) * 256 + tid;
    int total = nb << 19;
    if (idx >= total) return;
    int w4 = idx & 63;
    int h  = (idx >> 6) & 127;
    int c  = (idx >> 13) & 63;
    int b  = idx >> 19;
    const float* xp = x + (((size_t)(b0 + b) * DIMC + c) * FULLR + 2*h) * FULLR + 4*w4;
    float4 r0 = *(const float4*)xp;
    float4 r1 = *(const float4*)(xp + FULLR);
    size_t lbase = (((size_t)b*64 + c) << 14) + h*128 + w4*2;
    float x1a = 0.5f*r0.x, x3a = 0.5f*r0.y, x2a = 0.5f*r1.x, x4a = 0.5f*r1.y;
    float x1b = 0.5f*r0.z, x3b = 0.5f*r0.w, x2b = 0.5f*r1.z, x4b = 0.5f*r1.w;
    float lva = x1a + x2a + x3a + x4a;
    float lvb = x1b + x2b + x3b + x4b;
    *(unsigned*)&ll[lbase] = (unsigned)f2bf(lva) | ((unsigned)f2bf(lvb) << 16);
    int hs = (h + SHIFTV) & 127;  int wh = hs >> 3; int rr = hs & 7;
    int ws = (2*w4 + SHIFTV) & 127; int ww = ws >> 3; int cc = ws & 7;
    size_t wbase = ((size_t)(b*256 + wh*16 + ww)) * 12288 + rr*8 + cc;
    unsigned u;
    u = (unsigned)f2bf(-x1a - x2a + x3a + x4a) | ((unsigned)f2bf(-x1b - x2b + x3b + x4b) << 16);
    *(unsigned*)&high[wbase + (size_t)c*64] = u;
    u = (unsigned)f2bf(-x1a + x2a - x3a + x4a) | ((unsigned)f2bf(-x1b + x2b - x3b + x4b) << 16);
    *(unsigned*)&high[wbase + (size_t)(64 + c)*64] = u;
    u = (unsigned)f2bf( x1a - x2a - x3a + x4a) | ((unsigned)f2bf( x1b - x2b - x3b + x4b) << 16);
    *(unsigned*)&high[wbase + (size_t)(128 + c)*64] = u;
    red[tid] = lva + lvb;
    __syncthreads();
    for (int st = 128; st > 0; st >>= 1){
        if (tid < st) red[tid] += red[tid + st];
        __syncthreads();
    }
    if (tid == 0) atomicAdd(&gap[b*64 + c], red[0]);
}

// ---------------- FAT kernel: blk < nb*256 -> MHSA (inline gate); else -> aux path
__global__ __launch_bounds__(256, 3) void k_attn_aux(unsigned short* __restrict__ high,
    const unsigned short* __restrict__ wqb, const unsigned short* __restrict__ wpb,
    const float* __restrict__ bqkv, const float* __restrict__ bproj,
    const float* __restrict__ bias6, const float* __restrict__ lnw, const float* __restrict__ lnb,
    const float* __restrict__ gap, const float* __restrict__ cgw1, const float* __restrict__ cgw2,
    const float* __restrict__ gm_p, const float* __restrict__ gc_p,
    const unsigned short* __restrict__ ll, const float* __restrict__ dw,
    const unsigned short* __restrict__ pwab, const float* __restrict__ ga_p,
    unsigned short* __restrict__ rll, int nb)
{
    __shared__ __align__(16) char smem[53440];
    int tid = threadIdx.x;
    int lane = tid & 63;
    int wv = tid >> 6;
    int lrow = lane & 15;
    int lkg  = lane >> 4;

    if ((int)blockIdx.x < nb*256){
        // ================= ATTN path =================
        unsigned short (*xb)[200] = (unsigned short(*)[200])smem;                // 25600
        unsigned short (*qs)[40]  = (unsigned short(*)[40])(smem + 25600);       // 5120
        unsigned short (*ks2)[40] = (unsigned short(*)[40])(smem + 30720);       // 5120
        unsigned short (*vt)[72]  = (unsigned short(*)[72])(smem + 35840);       // 4608
        unsigned short (*ps)[72]  = (unsigned short(*)[72])(smem + 40448);       // 9216
        float (*st_s)[64]  = (float(*)[64])(smem + 49664);                       // 1024
        float (*st_ss)[64] = (float(*)[64])(smem + 50688);                       // 1024
        float* mu_s = (float*)(smem + 51712);                                    // 256
        float* rs_s = (float*)(smem + 51968);                                    // 256
        float* gapl = (float*)(smem + 52224);                                    // 256
        float* hid  = (float*)(smem + 52480);                                    // 192
        float* gfl  = (float*)(smem + 52672);                                    // 768

        int blk = blockIdx.x;
        int b  = blk >> 8;
        size_t wbase = (size_t)blk * 12288;
        const float scale = 0.17677669529663687f;
        float gm = gm_p[0], gc = gc_p[0];

        int t = lane, part = wv;
        if (tid < 64) gapl[tid] = gap[b*64 + tid] * (1.0f/16384.0f);
        float vals[48];
        {
            float s = 0.f, ss = 0.f;
            #pragma unroll
            for (int i = 0; i < 48; i++){
                float v = bf2f(high[wbase + (size_t)(part*48 + i)*64 + t]);
                vals[i] = v; s += v; ss += v*v;
            }
            st_s[part][t] = s; st_ss[part][t] = ss;
        }
        __syncthreads();
        if (tid < 64){
            float s = st_s[0][tid]+st_s[1][tid]+st_s[2][tid]+st_s[3][tid];
            float ss = st_ss[0][tid]+st_ss[1][tid]+st_ss[2][tid]+st_ss[3][tid];
            float mu = s*(1.f/C3);
            float var = ss*(1.f/C3) - mu*mu;
            mu_s[tid] = mu; rs_s[tid] = rsqrtf(var + 1e-6f);
        } else if (tid < 112){
            int j = tid - 64;
            float s = 0.f;
            for (int c = 0; c < 64; c++) s += gapl[c] * cgw1[j*64 + c];
            hid[j] = gelu_f(s);
        }
        __syncthreads();
        {
            float mu = mu_s[t], rs = rs_s[t];
            #pragma unroll
            for (int i8 = 0; i8 < 6; i8++){
                bf16x8 pk;
                #pragma unroll
                for (int jj = 0; jj < 8; jj++){
                    int c = part*48 + i8*8 + jj;
                    float nv = (vals[i8*8+jj] - mu) * rs * lnw[c] + lnb[c];
                    pk[jj] = (short)f2bf(nv);
                }
                *(bf16x8*)&xb[t][part*48 + i8*8] = pk;
            }
        }
        if (tid < C3){
            float s = 0.f;
            for (int j = 0; j < 48; j++) s += hid[j] * cgw2[tid*48 + j];
            float gv = 1.0f / (1.0f + expf(-s));
            gfl[tid] = 1.0f + gc * (gv - 0.5f) * 2.0f;
        }
        __syncthreads();

        f32x4 pacc[3][4];
        #pragma unroll
        for (int mt3 = 0; mt3 < 3; mt3++)
            #pragma unroll
            for (int nt = 0; nt < 4; nt++) pacc[mt3][nt] = (f32x4){0.f,0.f,0.f,0.f};

        for (int h = 0; h < NHEADS; h++){
            f32x4 acc[6];
            #pragma unroll
            for (int nt = 0; nt < 6; nt++) acc[nt] = (f32x4){0.f,0.f,0.f,0.f};
            __builtin_amdgcn_s_setprio(1);
            for (int ksU = 0; ksU < 6; ksU++){
                int c0 = ksU*32 + lkg*8;
                bf16x8 a = *(const bf16x8*)&xb[wv*16 + lrow][c0];
                #pragma unroll
                for (int nt = 0; nt < 6; nt++){
                    int which = nt >> 1;
                    int gr = which*C3 + h*32 + (nt&1)*16 + lrow;
                    bf16x8 bb = *(const bf16x8*)&wqb[(size_t)gr*C3 + c0];
                    acc[nt] = __builtin_amdgcn_mfma_f32_16x16x32_bf16(a, bb, acc[nt], 0, 0, 0);
                }
            }
            __builtin_amdgcn_s_setprio(0);
            #pragma unroll
            for (int nt = 0; nt < 6; nt++){
                int which = nt >> 1;
                int d = (nt&1)*16 + lrow;
                float bias = bqkv[which*C3 + h*32 + d];
                #pragma unroll
                for (int r = 0; r < 4; r++){
                    int row = wv*16 + lkg*4 + r;
                    float v = acc[nt][r] + bias;
                    if (which == 0)      qs[row][d]  = f2bf(v * scale);
                    else if (which == 1) ks2[row][d] = f2bf(v);
                    else                 vt[d][row]  = f2bf(v);
                }
            }
            __syncthreads();

            f32x4 sacc[4];
            {
                bf16x8 a = *(const bf16x8*)&qs[wv*16 + lrow][lkg*8];
                #pragma unroll
                for (int nt = 0; nt < 4; nt++){
                    bf16x8 bb = *(const bf16x8*)&ks2[nt*16 + lrow][lkg*8];
                    f32x4 z = (f32x4){0.f,0.f,0.f,0.f};
                    sacc[nt] = __builtin_amdgcn_mfma_f32_16x16x32_bf16(a, bb, z, 0, 0, 0);
                }
            }
            {
                #pragma unroll
                for (int r = 0; r < 4; r++){
                    int i = wv*16 + lkg*4 + r;
                    float pv[4];
                    float s = 0.f;
                    #pragma unroll
                    for (int nt = 0; nt < 4; nt++){
                        pv[nt] = __expf(sacc[nt][r] + bias6[h*4096 + i*64 + nt*16 + lrow]);
                        s += pv[nt];
                    }
                    s += __shfl_xor(s, 1); s += __shfl_xor(s, 2);
                    s += __shfl_xor(s, 4); s += __shfl_xor(s, 8);
                    float inv = 1.0f / s;
                    #pragma unroll
                    for (int nt = 0; nt < 4; nt++) ps[i][nt*16 + lrow] = f2bf(pv[nt] * inv);
                }
            }
            __syncthreads();

            f32x4 oacc[2];
            #pragma unroll
            for (int nt = 0; nt < 2; nt++) oacc[nt] = (f32x4){0.f,0.f,0.f,0.f};
            #pragma unroll
            for (int kst = 0; kst < 2; kst++){
                bf16x8 a = *(const bf16x8*)&ps[wv*16 + lrow][kst*32 + lkg*8];
                #pragma unroll
                for (int nt = 0; nt < 2; nt++){
                    bf16x8 bb = *(const bf16x8*)&vt[nt*16 + lrow][kst*32 + lkg*8];
                    oacc[nt] = __builtin_amdgcn_mfma_f32_16x16x32_bf16(a, bb, oacc[nt], 0, 0, 0);
                }
            }
            #pragma unroll
            for (int nt = 0; nt < 2; nt++)
                #pragma unroll
                for (int r = 0; r < 4; r++)
                    qs[wv*16 + lkg*4 + r][nt*16 + lrow] = f2bf(oacc[nt][r]);
            __syncthreads();

            __builtin_amdgcn_s_setprio(1);
            #pragma unroll
            for (int mt3 = 0; mt3 < 3; mt3++){
                int o = wv*48 + mt3*16 + lrow;
                bf16x8 a = *(const bf16x8*)&wpb[(size_t)o*C3 + h*32 + lkg*8];
                #pragma unroll
                for (int nt = 0; nt < 4; nt++){
                    bf16x8 bb = *(const bf16x8*)&qs[nt*16 + lrow][lkg*8];
                    pacc[mt3][nt] = __builtin_amdgcn_mfma_f32_16x16x32_bf16(a, bb, pacc[mt3][nt], 0, 0, 0);
                }
            }
            __builtin_amdgcn_s_setprio(0);
            __syncthreads();
        }

        #pragma unroll
        for (int mt3 = 0; mt3 < 3; mt3++){
            #pragma unroll
            for (int r = 0; r < 4; r++){
                int o = wv*48 + mt3*16 + lkg*4 + r;
                float bias = bproj[o];
                float gf = gfl[o];
                #pragma unroll
                for (int nt = 0; nt < 4; nt++){
                    int token = nt*16 + lrow;
                    size_t gi = wbase + (size_t)o*64 + token;
                    float orig = bf2f(high[gi]);
                    high[gi] = f2bf((orig + gm*(pacc[mt3][nt][r] + bias)) * gf);
                }
            }
        }
    } else {
        // ================= AUX path =================
        unsigned short (*sll)[3][80] = (unsigned short(*)[3][80])smem;           // 30720
        unsigned short (*tlb)[72]    = (unsigned short(*)[72])(smem + 30720);    // 9216

        int blk = blockIdx.x - nb*256;
        int b   = blk >> 8;
        int row = (blk >> 1) & 127;
        int seg = blk & 1;
        int px0 = seg*64;

        for (int j = tid; j < 1920; j += 256){
            int c = j / 30;
            int rem = j % 30;
            int dy = rem / 10;
            int i8 = rem % 10;
            int gr = row + dy - 1;
            int gp = px0 - 8 + i8*8;
            bf16x8 v = (bf16x8){0,0,0,0,0,0,0,0};
            if (gr >= 0 && gr < 128 && gp >= 0 && gp < 128)
                v = *(const bf16x8*)&ll[(((size_t)b*64 + c) << 14) + gr*128 + gp];
            *(bf16x8*)&sll[c][dy][i8*8] = v;
        }
        __syncthreads();

        int px = tid & 63, cq = tid >> 6;
        for (int ci = cq; ci < 64; ci += 4){
            const float* wd = dw + ci*9;
            float s = 0.f;
            #pragma unroll
            for (int dy = 0; dy < 3; dy++){
                float a0 = bf2f(sll[ci][dy][px+7]);
                float a1 = bf2f(sll[ci][dy][px+8]);
                float a2 = bf2f(sll[ci][dy][px+9]);
                s += wd[dy*3+0]*a0 + wd[dy*3+1]*a1 + wd[dy*3+2]*a2;
            }
            tlb[px][ci] = f2bf(gelu_f(s));
        }
        __syncthreads();

        float ga = ga_p[0];
        f32x4 acc[4];
        #pragma unroll
        for (int nt = 0; nt < 4; nt++) acc[nt] = (f32x4){0.f,0.f,0.f,0.f};
        __builtin_amdgcn_s_setprio(1);
        #pragma unroll
        for (int kst = 0; kst < 2; kst++){
            bf16x8 a = *(const bf16x8*)&pwab[(size_t)(wv*16 + lrow)*64 + kst*32 + lkg*8];
            #pragma unroll
            for (int nt = 0; nt < 4; nt++){
                bf16x8 bb = *(const bf16x8*)&tlb[nt*16 + lrow][kst*32 + lkg*8];
                acc[nt] = __builtin_amdgcn_mfma_f32_16x16x32_bf16(a, bb, acc[nt], 0, 0, 0);
            }
        }
        __builtin_amdgcn_s_setprio(0);
        #pragma unroll
        for (int nt = 0; nt < 4; nt++){
            #pragma unroll
            for (int r = 0; r < 4; r++){
                int o = wv*16 + lkg*4 + r;
                int pxx = nt*16 + lrow;
                float base = bf2f(sll[o][1][pxx + 8]);
                rll[(((size_t)b*64 + o) << 14) + row*128 + px0 + pxx] = f2bf(base + ga * acc[nt][r]);
            }
        }
    }
}

// ---------------- FUSED IWT + proj + residual -> y1b, then LN + conv1x1(64->256) -> h (all MFMA)
__global__ __launch_bounds__(256) void k_iwt_ffn(const unsigned short* __restrict__ rll,
    const unsigned short* __restrict__ high, const float* __restrict__ x,
    const unsigned short* __restrict__ waob,
    const float* __restrict__ lnw, const float* __restrict__ lnb,
    const unsigned short* __restrict__ wib,
    unsigned short* __restrict__ y1b, unsigned short* __restrict__ h, int nb, int b0)
{
    __shared__ __align__(16) char smem[38912];
    float* xt            = (float*)smem;
    unsigned short* ho   = (unsigned short*)smem;
    unsigned short* dbufT= (unsigned short*)(smem + 18432);
    unsigned short* xn   = (unsigned short*)(smem + 27648);
    float* pss           = (float*)(smem + 36864);
    float* psss          = (float*)(smem + 37888);

    int tid = threadIdx.x;
    int blk = blockIdx.x;
    int seg = blk & 3;
    int ph  = (blk >> 2) & 255;
    int b   = blk >> 10;
    int pw0 = seg * 64;
    int h2 = ph >> 1, p = ph & 1;
    size_t xbase = ((size_t)(b0 + b) * DIMC) * 65536;
    int px = tid & 63;
    int ci = tid >> 6;
    int pwv = pw0 + px;
    int w2 = pwv >> 1, q = pwv & 1;
    float shl = q ? 1.f : -1.f;
    float slh = p ? 1.f : -1.f;
    float shh = (p == q) ? 1.f : -1.f;
    int hs = (h2 + SHIFTV) & 127; int wh = hs >> 3; int rr = hs & 7;
    int ws = (w2 + SHIFTV) & 127; int ww = ws >> 3; int cc = ws & 7;
    size_t wbase = ((size_t)(b*256 + wh*16 + ww)) * 12288 + rr*8 + cc;
    for (int i = ci; i < 64; i += 4){
        float llv = bf2f(rll[(((size_t)b*64 + i) << 14) + h2*128 + w2]);
        float hl = bf2f(high[wbase + (size_t)i*64]);
        float lh = bf2f(high[wbase + (size_t)(64 + i)*64]);
        float hh = bf2f(high[wbase + (size_t)(128 + i)*64]);
        float iw = 0.5f * (llv + shl*hl + slh*lh + shh*hh);
        float xv = x[xbase + (size_t)i*65536 + (size_t)ph*256 + pwv];
        xt[i*65 + px] = xv;
        dbufT[px*72 + i] = f2bf(iw - xv);
    }
    __syncthreads();

    int lane = tid & 63;
    int wv = tid >> 6;
    int lrow = lane & 15;
    int lkg  = lane >> 4;
    f32x4 acc[4];
    #pragma unroll
    for (int nt = 0; nt < 4; nt++) acc[nt] = (f32x4){0.f,0.f,0.f,0.f};
    __builtin_amdgcn_s_setprio(1);
    #pragma unroll
    for (int kst = 0; kst < 2; kst++){
        bf16x8 a = *(const bf16x8*)&waob[(size_t)(wv*16 + lrow)*64 + kst*32 + lkg*8];
        #pragma unroll
        for (int nt = 0; nt < 4; nt++){
            bf16x8 bb = *(const bf16x8*)&dbufT[(nt*16 + lrow)*72 + kst*32 + lkg*8];
            acc[nt] = __builtin_amdgcn_mfma_f32_16x16x32_bf16(a, bb, acc[nt], 0, 0, 0);
        }
    }
    __builtin_amdgcn_s_setprio(0);
    float yv[4][4];
    float s4[4], ss4[4];
    #pragma unroll
    for (int nt = 0; nt < 4; nt++){ s4[nt] = 0.f; ss4[nt] = 0.f; }
    #pragma unroll
    for (int nt = 0; nt < 4; nt++){
        int pxx = nt*16 + lrow;
        #pragma unroll
        for (int r = 0; r < 4; r++){
            int o = wv*16 + lkg*4 + r;
            float v = xt[o*65 + pxx] + acc[nt][r];
            yv[nt][r] = v;
            s4[nt] += v; ss4[nt] += v*v;
            y1b[(((size_t)(b*64 + o)) << 16) + (size_t)ph*256 + pw0 + pxx] = f2bf(v);
        }
    }
    #pragma unroll
    for (int nt = 0; nt < 4; nt++){
        s4[nt]  += __shfl_xor(s4[nt], 16);  s4[nt]  += __shfl_xor(s4[nt], 32);
        ss4[nt] += __shfl_xor(ss4[nt], 16); ss4[nt] += __shfl_xor(ss4[nt], 32);
    }
    if (lkg == 0){
        #pragma unroll
        for (int nt = 0; nt < 4; nt++){
            pss[wv*64 + nt*16 + lrow]  = s4[nt];
            psss[wv*64 + nt*16 + lrow] = ss4[nt];
        }
    }
    __syncthreads();
    #pragma unroll
    for (int nt = 0; nt < 4; nt++){
        int pxx = nt*16 + lrow;
        float s  = pss[pxx]  + pss[64 + pxx]  + pss[128 + pxx]  + pss[192 + pxx];
        float ss = psss[pxx] + psss[64 + pxx] + psss[128 + pxx] + psss[192 + pxx];
        float mu = s * (1.f/64.f);
        float var = ss * (1.f/64.f) - mu*mu;
        float rs = rsqrtf(var + 1e-6f);
        #pragma unroll
        for (int r = 0; r < 4; r++){
            int o = wv*16 + lkg*4 + r;
            xn[pxx*72 + o] = f2bf((yv[nt][r] - mu) * rs * lnw[o] + lnb[o]);
        }
    }
    __syncthreads();
    for (int hh = 0; hh < 2; hh++){
        int oc0 = hh*128;
        f32x4 cacc[8];
        #pragma unroll
        for (int nt = 0; nt < 8; nt++) cacc[nt] = (f32x4){0.f,0.f,0.f,0.f};
        __builtin_amdgcn_s_setprio(1);
        #pragma unroll
        for (int kst = 0; kst < 2; kst++){
            bf16x8 a = *(const bf16x8*)&xn[(wv*16 + lrow)*72 + kst*32 + lkg*8];
            #pragma unroll
            for (int nt = 0; nt < 8; nt++){
                bf16x8 bb = *(const bf16x8*)&wib[(size_t)(oc0 + nt*16 + lrow)*64 + kst*32 + lkg*8];
                cacc[nt] = __builtin_amdgcn_mfma_f32_16x16x32_bf16(a, bb, cacc[nt], 0, 0, 0);
            }
        }
        __builtin_amdgcn_s_setprio(0);
        #pragma unroll
        for (int nt = 0; nt < 8; nt++)
            #pragma unroll
            for (int r = 0; r < 4; r++)
                ho[(nt*16 + lrow)*72 + wv*16 + lkg*4 + r] = f2bf(cacc[nt][r]);
        __syncthreads();
        for (int idx = tid; idx < 1024; idx += 256){
            int oc = idx >> 3, p8 = idx & 7;
            bf16x8 v = *(const bf16x8*)&ho[oc*72 + p8*8];
            *(bf16x8*)&h[(size_t)(b*256 + oc0 + oc)*65536 + (size_t)ph*256 + pw0 + p8*8] = v;
        }
        __syncthreads();
    }
}

// ---------------- FUSED FFN-B + spectral conv
#define PMS 68
__global__ __launch_bounds__(256) void k_convb(const unsigned short* __restrict__ h,
    const float* __restrict__ w_dw, const unsigned short* __restrict__ circ,
    unsigned short* __restrict__ mbuf, int nb)
{
    __shared__ __align__(16) unsigned short stage[4][10][272];
    __shared__ __align__(16) unsigned short pm[4][32*PMS];
    int tid = threadIdx.x;
    int lane = tid & 63;
    int wv = tid >> 6;
    int lrow = lane & 15;
    int lkg  = lane >> 4;
    int blk = blockIdx.x;
    int b   = blk >> 9;
    int chg = (blk >> 5) & 15;
    int pc  = blk & 31;
    int r0 = pc*8;

    auto stage_fn = [&](int c16){
        int chA = chg*8 + c16;
        int chs[4] = {chA, chA+128, chA+4, chA+132};
        for (int j = tid; j < 1280; j += 256){
            int pl = j / 320;
            int rem = j - pl*320;
            int row10 = rem >> 5;
            int c0 = (rem & 31) << 3;
            int gr = r0 + row10 - 1;
            bf16x8 v = (bf16x8){0,0,0,0,0,0,0,0};
            if (gr >= 0 && gr < 256)
                v = *(const bf16x8*)&h[((size_t)(b*256 + chs[pl]) << 16) + (size_t)gr*256 + c0];
            *(bf16x8*)&stage[pl][row10][c0] = v;
        }
    };

    stage_fn(0);
    __syncthreads();

    for (int c16 = 0; c16 < 4; c16++){
        {
            int chA = chg*8 + c16;
            int chs[4] = {chA, chA+128, chA+4, chA+132};
            for (int j = tid; j < 1024; j += 256){
                int pl = j >> 8;
                int rem = j & 255;
                int r = rem >> 5;
                int c0 = (rem & 31) << 3;
                const float* wd = w_dw + chs[pl]*9;
                float acc[8] = {0,0,0,0,0,0,0,0};
                #pragma unroll
                for (int dy = 0; dy < 3; dy++){
                    const unsigned short* rp = &stage[pl][r+dy][0];
                    bf16x8 v = *(const bf16x8*)&rp[c0];
                    float vf[8];
                    #pragma unroll
                    for (int jj = 0; jj < 8; jj++) vf[jj] = bf2f((unsigned short)v[jj]);
                    float l  = (c0 > 0)   ? bf2f(rp[c0 - 1]) : 0.f;
                    float rg = (c0 < 248) ? bf2f(rp[c0 + 8]) : 0.f;
                    float w0 = wd[dy*3+0], w1 = wd[dy*3+1], w2 = wd[dy*3+2];
                    acc[0] += w0*l + w1*vf[0] + w2*vf[1];
                    #pragma unroll
                    for (int jj = 1; jj < 7; jj++) acc[jj] += w0*vf[jj-1] + w1*vf[jj] + w2*vf[jj+1];
                    acc[7] += w0*vf[6] + w1*vf[7] + w2*rg;
                }
                bf16x8 o;
                #pragma unroll
                for (int jj = 0; jj < 8; jj++) o[jj] = (short)f2bf(acc[jj]);
                *(bf16x8*)&pm[pl][(c0 >> 3)*PMS + r*8] = o;
            }
        }
        __syncthreads();
        if (c16 < 3) stage_fn(c16 + 1);
        {
            int spl = (wv & 1) * 2;
            int ch = chg*8 + (wv & 1)*4 + c16;
            const unsigned short* Bb = circ + (size_t)ch*4096;
            int plocal = (wv >> 1)*16;
            f32x4 acc4[4];
            #pragma unroll
            for (int nt = 0; nt < 4; nt++) acc4[nt] = (f32x4){0.f,0.f,0.f,0.f};
            __builtin_amdgcn_s_setprio(1);
            #pragma unroll
            for (int kst = 0; kst < 2; kst++){
                bf16x8 a = *(const bf16x8*)&pm[spl][(plocal + lrow)*PMS + kst*32 + lkg*8];
                #pragma unroll
                for (int nt = 0; nt < 4; nt++){
                    bf16x8 bb = *(const bf16x8*)&Bb[(size_t)(nt*16 + lrow)*64 + kst*32 + lkg*8];
                    acc4[nt] = __builtin_amdgcn_mfma_f32_16x16x32_bf16(a, bb, acc4[nt], 0, 0, 0);
                }
            }
            __builtin_amdgcn_s_setprio(0);
            unsigned short* Mb = mbuf + ((size_t)(b*128 + ch) << 16);
            #pragma unroll
            for (int nt = 0; nt < 4; nt++){
                #pragma unroll
                for (int r = 0; r < 4; r++){
                    int pl2 = plocal + lkg*4 + r;
                    int px = nt*16 + lrow;
                    float g = bf2f(pm[spl + 1][pl2*PMS + px]);
                    Mb[(size_t)(pc*32 + pl2)*64 + px] = f2bf(gelu_f(acc4[nt][r]) * g);
                }
            }
        }
        __syncthreads();
    }
}

// ---------------- FFN out-projection via MFMA: out = y1 + m @ w_out.T
__global__ __launch_bounds__(256) void k_out(const unsigned short* __restrict__ y1b,
    const unsigned short* __restrict__ mbuf, const unsigned short* __restrict__ wob,
    float* __restrict__ out, int b0)
{
    __shared__ __align__(16) unsigned short mlds[2][64][136];
    int tid = threadIdx.x;
    int lane = tid & 63;
    int wv = tid >> 6;
    int lrow = lane & 15;
    int lkg  = lane >> 4;
    int blk = blockIdx.x;
    int b  = blk >> 9;
    int pp = blk & 511;

    for (int it = 0; it < 8; it++){
        int chunk = tid + it*256;
        int ch = chunk >> 4;
        int p = (chunk >> 3) & 1;
        int px8 = chunk & 7;
        bf16x8 v = *(const bf16x8*)&mbuf[(((size_t)(b*128 + ch)) << 16) + (size_t)(2*pp + p)*64 + px8*8];
        #pragma unroll
        for (int j = 0; j < 8; j++) mlds[p][px8*8 + j][ch] = (unsigned short)v[j];
    }
    __syncthreads();

    int p = wv >> 1;
    int ochalf = wv & 1;
    f32x4 acc[2][4];
    #pragma unroll
    for (int mt = 0; mt < 2; mt++)
        #pragma unroll
        for (int nt = 0; nt < 4; nt++) acc[mt][nt] = (f32x4){0.f,0.f,0.f,0.f};
    __builtin_amdgcn_s_setprio(1);
    #pragma unroll
    for (int kst = 0; kst < 4; kst++){
        bf16x8 a0 = *(const bf16x8*)&wob[(size_t)(ochalf*32 + 0  + lrow)*128 + kst*32 + lkg*8];
        bf16x8 a1 = *(const bf16x8*)&wob[(size_t)(ochalf*32 + 16 + lrow)*128 + kst*32 + lkg*8];
        #pragma unroll
        for (int nt = 0; nt < 4; nt++){
            bf16x8 bb = *(const bf16x8*)&mlds[p][nt*16 + lrow][kst*32 + lkg*8];
            acc[0][nt] = __builtin_amdgcn_mfma_f32_16x16x32_bf16(a0, bb, acc[0][nt], 0, 0, 0);
            acc[1][nt] = __builtin_amdgcn_mfma_f32_16x16x32_bf16(a1, bb, acc[1][nt], 0, 0, 0);
        }
    }
    __builtin_amdgcn_s_setprio(0);
    int patchIdx = 2*pp + p;
    int Rb = (patchIdx >> 5) * 8, Cb = (patchIdx & 31) * 8;
    #pragma unroll
    for (int mt = 0; mt < 2; mt++){
        #pragma unroll
        for (int nt = 0; nt < 4; nt++){
            #pragma unroll
            for (int r = 0; r < 4; r++){
                int oc = ochalf*32 + mt*16 + lkg*4 + r;
                int px = nt*16 + lrow;
                int R = Rb + (px >> 3), C = Cb + (px & 7);
                size_t li = (((size_t)(b*64 + oc)) << 16) + (size_t)R*256 + C;
                size_t go = (((size_t)((b0 + b)*64 + oc)) << 16) + (size_t)R*256 + C;
                out[go] = bf2f(y1b[li]) + acc[mt][nt][r];
            }
        }
    }
}

extern "C" void kernel_launch(void* const* d_in, const int* in_sizes, int n_in,
                              void* d_out, int out_size, void* d_ws, size_t ws_size,
                              hipStream_t stream){
    const float* x        = (const float*)d_in[0];
    const float* ln_w     = (const float*)d_in[1];
    const float* ln_b     = (const float*)d_in[2];
    const float* lnh_w    = (const float*)d_in[3];
    const float* lnh_b    = (const float*)d_in[4];
    const float* w_qkv    = (const float*)d_in[5];
    const float* b_qkv    = (const float*)d_in[6];
    const float* w_proj   = (const float*)d_in[7];
    const float* b_proj   = (const float*)d_in[8];
    const float* rel_tab  = (const float*)d_in[9];
    const float* g_main   = (const float*)d_in[10];
    const float* g_aux    = (const float*)d_in[11];
    const float* g_cross  = (const float*)d_in[12];
    const float* aux_dw   = (const float*)d_in[13];
    const float* aux_pw   = (const float*)d_in[14];
    const float* cg_w1    = (const float*)d_in[15];
    const float* cg_w2    = (const float*)d_in[16];
    const float* attn_ow  = (const float*)d_in[17];
    const float* ffn_in_w = (const float*)d_in[18];
    const float* ffn_dw   = (const float*)d_in[19];
    const float* ffn_ow   = (const float*)d_in[20];
    const float* wb_re    = (const float*)d_in[21];
    const float* wb_im    = (const float*)d_in[22];
    const int*   rel_idx  = (const int*)d_in[23];
    float* out = (float*)d_out;
    (void)in_sizes; (void)n_in; (void)out_size;

    const size_t MBsz = (size_t)1 << 20;
    auto need = [&](int nb)->size_t { return (size_t)nb*72*MBsz + 2*MBsz; };
    int nbmax = 4;
    while (nbmax > 1 && need(nbmax) > ws_size) nbmax >>= 1;

    for (int b0 = 0; b0 < 4; b0 += nbmax){
        int nb = nbmax;
        char* p = (char*)d_ws;
        char* U = p;                      p += (size_t)nb*72*MBsz;
        float* gap  = (float*)p;          p += 4096;
        unsigned short* wqb = (unsigned short*)p; p += 576*192*2;
        unsigned short* wpb = (unsigned short*)p; p += 192*192*2;
        float* bias6 = (float*)p;         p += 6*64*64*4;
        unsigned short* circ = (unsigned short*)p; p += 128*4096*2;
        unsigned short* wob  = (unsigned short*)p; p += 64*128*2;
        unsigned short* wib  = (unsigned short*)p; p += 256*64*2;
        unsigned short* waob = (unsigned short*)p; p += 64*64*2;
        unsigned short* pwab = (unsigned short*)p; p += 64*64*2;

        unsigned short* ll   = (unsigned short*)U;                          // nb*2MB
        unsigned short* highb= (unsigned short*)(U + (size_t)nb*2*MBsz);    // nb*6MB
        unsigned short* rll  = (unsigned short*)(U + (size_t)nb*8*MBsz);    // nb*2MB
        unsigned short* mbuf = (unsigned short*)U;                          // nb*16MB
        unsigned short* h    = (unsigned short*)(U + (size_t)nb*32*MBsz);   // nb*32MB
        unsigned short* y1b  = (unsigned short*)(U + (size_t)nb*64*MBsz);   // nb*8MB

        hipMemsetAsync(gap, 0, 256*sizeof(float), stream);
        k_dwt_prep<<<560 + nb*2048, 256, 0, stream>>>(x, ll, highb, gap,
                                        wb_re, wb_im, circ,
                                        w_qkv, w_proj, rel_tab, rel_idx, ffn_ow, ffn_in_w,
                                        attn_ow, aux_pw,
                                        wqb, wpb, bias6, wob, wib, waob, pwab, nb, b0);
        k_attn_aux<<<nb*512, 256, 0, stream>>>(highb, wqb, wpb, b_qkv, b_proj, bias6,
                                               lnh_w, lnh_b, gap, cg_w1, cg_w2, g_main, g_cross,
                                               ll, aux_dw, pwab, g_aux, rll, nb);
        k_iwt_ffn<<<nb*1024, 256, 0, stream>>>(rll, highb, x, waob, ln_w, ln_b, wib,
                                               y1b, h, nb, b0);
        k_convb<<<nb*512, 256, 0, stream>>>(h, ffn_dw, circ, mbuf, nb);
        k_out<<<nb*512, 256, 0, stream>>>(y1b, mbuf, wob, out, b0);
    }
}